// Round 7
// baseline (676.156 us; speedup 1.0000x reference)
//
#include <hip/hip_runtime.h>
#include <hip/hip_bf16.h>
#include <math.h>
#include <stdint.h>

#define TT 2080
#define DM 512
#define DI 2048
#define NH 8
#define DH 64
#define NMTOK 16
#define NLAYER 4
#define QKV_N 1536
#define ATT_SCALE 0.125f
#define NCH 4               // attention chunks = waves per block
#define WT_STRIDE 3407872   // shorts per layer's transposed-weight block
#define BDF_HEAD 2196480    // shorts per head of fragment-ordered BD tiles (2145*1024)
#define WRAP_HEAD 33280     // shorts per head of wrap values (TT*16)

typedef short bf16x8 __attribute__((ext_vector_type(8)));
typedef float f32x4 __attribute__((ext_vector_type(4)));
typedef unsigned short ushort_t;

__device__ __forceinline__ ushort_t f2bf(float f) {
  __hip_bfloat16 h = __float2bfloat16(f);
  return *reinterpret_cast<ushort_t*>(&h);
}
__device__ __forceinline__ float bfbits2f(unsigned int hi_bits) {
  return __uint_as_float(hi_bits);
}
__device__ __forceinline__ float bf2f(ushort_t u) {
  return bfbits2f(((unsigned int)u) << 16);
}
__device__ __forceinline__ void unpack8(uint4 v, float* f) {
  f[0] = bfbits2f(v.x << 16); f[1] = bfbits2f(v.x & 0xffff0000u);
  f[2] = bfbits2f(v.y << 16); f[3] = bfbits2f(v.y & 0xffff0000u);
  f[4] = bfbits2f(v.z << 16); f[5] = bfbits2f(v.z & 0xffff0000u);
  f[6] = bfbits2f(v.w << 16); f[7] = bfbits2f(v.w & 0xffff0000u);
}
__device__ __forceinline__ unsigned int pack2(ushort_t lo, ushort_t hi) {
  return (unsigned int)lo | ((unsigned int)hi << 16);
}
// Barrier draining LDS ops only — leaves global (vmcnt) loads in flight.
__device__ __forceinline__ void barrier_lds() {
  asm volatile("s_waitcnt lgkmcnt(0)" ::: "memory");
  __builtin_amdgcn_s_barrier();
}
// global -> LDS direct copy, 16B per lane (FT GEMM staging).
__device__ __forceinline__ void gload16(const ushort_t* g, ushort_t* l) {
  __builtin_amdgcn_global_load_lds(
      (__attribute__((address_space(1))) void*)(uintptr_t)g,
      (__attribute__((address_space(3))) void*)(uintptr_t)l, 16, 0, 0);
}
// ---- fragment-tiled (FT) layout --------------------------------------------
// Matrix X[R][K] (bf16) stored as 1024B blocks of (16 r x 32 k); lane
// = ((k>>3)&3)*16 + (r&15) holds 8 consecutive k-elements = EXACTLY the
// mfma_f32_16x16x32_bf16 A/B fragment order.
__device__ __forceinline__ size_t ft512(int r, int c) {  // K = 512 (KT = 16)
  return (((size_t)(r >> 4) * 16 + (c >> 5)) << 9) + (((c >> 3) & 3) << 7) +
         ((r & 15) << 3) + (c & 7);
}

// ---- fused prep: all 4 layers' weight transposes + build w/pos ------------
__global__ __launch_bounds__(256) void k_prep(
    const float* __restrict__ Wqkv, const float* __restrict__ Wr,
    const float* __restrict__ Wo, const float* __restrict__ W1,
    const float* __restrict__ W2, ushort_t* __restrict__ dstAll,
    const float* __restrict__ we, const float* __restrict__ mem,
    float* __restrict__ w, ushort_t* __restrict__ wbft,
    ushort_t* __restrict__ posft) {
  const int tid = threadIdx.x;
  if (blockIdx.x >= 13312) {  // ---- build ----
    int idx = (blockIdx.x - 13312) * 256 + tid;
    if (idx >= TT * DM) return;
    int t = idx >> 9, d = idx & 511;
    float v;
    if (t < NMTOK) v = mem[t * DM + d];
    else if (t < NMTOK + 2048) v = we[(t - NMTOK) * DM + d];
    else v = mem[(t - (NMTOK + 2048)) * DM + d];
    w[idx] = v;
    wbft[ft512(t, d)] = f2bf(v);
    float p = (float)(TT - 1 - t);
    int i2 = d & 255;
    float freq = __expf(-0.035977892f * (float)i2);
    float ang = p * freq;
    posft[ft512(t, d)] = f2bf((d < 256) ? __sinf(ang) : __cosf(ang));
    return;
  }
  // ---- transpose+cast, layer l ----
  __shared__ float tl[32][33];
  const int l = blockIdx.x / 3328;
  int idx = blockIdx.x % 3328;
  const float* src;
  ushort_t* dst = dstAll + (size_t)l * WT_STRIDE;
  int K, N, local;
  bool isFT = true;
  if (idx < 768)       { src = Wqkv + (size_t)l * 512 * 1536; K = 512;  N = 1536; local = idx; }
  else if (idx < 1024) { src = Wr   + (size_t)l * 512 * 512;  dst += 786432;  K = 512;  N = 512;  local = idx - 768; }
  else if (idx < 1280) { src = Wo   + (size_t)l * 512 * 512;  dst += 1048576; K = 512;  N = 512;  local = idx - 1024; isFT = false; }
  else if (idx < 2304) { src = W1   + (size_t)l * 512 * 2048; dst += 1310720; K = 512;  N = 2048; local = idx - 1280; }
  else                 { src = W2   + (size_t)l * 2048 * 512; dst += 2359296; K = 2048; N = 512;  local = idx - 2304; }
  const int ntiles = N / 32;
  const int n0 = (local % ntiles) * 32, k0 = (local / ntiles) * 32;
#pragma unroll
  for (int p = 0; p < 4; ++p) {
    int row = (tid >> 5) + 8 * p, col = tid & 31;
    tl[row][col] = src[(size_t)(k0 + row) * N + n0 + col];  // tl[k][n]
  }
  __syncthreads();
  if (isFT) {
    if (tid < 128) {
      int b = tid >> 6, l2 = tid & 63;
      int nn = b * 16 + (l2 & 15);
      int kq = (l2 >> 4) * 8;
      ushort_t t8[8];
#pragma unroll
      for (int e = 0; e < 8; ++e) t8[e] = f2bf(tl[kq + e][nn]);
      size_t ad = (((size_t)((n0 >> 4) + b) * (K >> 5) + (k0 >> 5)) << 9) +
                  ((size_t)l2 << 3);
      *(uint4*)&dst[ad] = *(uint4*)t8;
    }
  } else {
#pragma unroll
    for (int p = 0; p < 4; ++p) {
      int n = (tid >> 5) + 8 * p, k = tid & 31;
      dst[(size_t)(n0 + n) * K + k0 + k] = f2bf(tl[k][n]);
    }
  }
}

// -------- bf16 MFMA GEMM body, 32x64 tile, register prefetch (Wo only) ----
__device__ __forceinline__ void gemm32x64_body(const ushort_t* __restrict__ A,
                                               const ushort_t* __restrict__ Bt,
                                               const float* __restrict__ bias,
                                               float* __restrict__ C,
                                               ushort_t* __restrict__ Cb,
                                               int N, int K, int flags,
                                               int m0, int n0) {
  __shared__ short As[32][72];
  __shared__ short Bs[64][72];
  const int tid = threadIdx.x;
  const int lane = tid & 63, wv = tid >> 6;
  const int wm = (wv >> 1) * 16, wn = (wv & 1) * 32;
  const int lm = lane & 15, quad = lane >> 4;
  const int sr = tid >> 3, sc8 = (tid & 7) * 8;

  f32x4 acc[2];
  acc[0] = (f32x4)(0.f); acc[1] = (f32x4)(0.f);

  auto loadA = [&](int k0) -> uint4 {
    return *(const uint4*)&A[(size_t)(m0 + sr) * K + k0 + sc8];
  };
  auto loadB = [&](int row, int k0) -> uint4 {
    return *(const uint4*)&Bt[(size_t)(n0 + row) * K + k0 + sc8];
  };

  uint4 aC = loadA(0), b0C = loadB(sr, 0), b1C = loadB(sr + 32, 0);

  for (int k0 = 0; k0 < K; k0 += 64) {
    const int kn = (k0 + 64 < K) ? k0 + 64 : k0;  // clamped tail reload
    uint4 aN = loadA(kn), b0N = loadB(sr, kn), b1N = loadB(sr + 32, kn);
    barrier_lds();  // prev ds_reads done; vm prefetches stay in flight
    *(uint4*)&As[sr][sc8] = aC;
    *(uint4*)&Bs[sr][sc8] = b0C;
    *(uint4*)&Bs[sr + 32][sc8] = b1C;
    barrier_lds();
#pragma unroll
    for (int kk = 0; kk < 64; kk += 32) {
      bf16x8 a = *(const bf16x8*)&As[wm + lm][kk + quad * 8];
      bf16x8 b0 = *(const bf16x8*)&Bs[wn + lm][kk + quad * 8];
      bf16x8 b1 = *(const bf16x8*)&Bs[wn + 16 + lm][kk + quad * 8];
      acc[0] = __builtin_amdgcn_mfma_f32_16x16x32_bf16(a, b0, acc[0], 0, 0, 0);
      acc[1] = __builtin_amdgcn_mfma_f32_16x16x32_bf16(a, b1, acc[1], 0, 0, 0);
    }
    aC = aN; b0C = b0N; b1C = b1N;
  }
#pragma unroll
  for (int nt = 0; nt < 2; ++nt) {
    int col = n0 + wn + nt * 16 + lm;
    float bv = (flags & 1) ? bias[col] : 0.f;
#pragma unroll
    for (int t = 0; t < 4; ++t) {
      int row = m0 + wm + quad * 4 + t;
      float v = acc[nt][t] + bv;
      if (flags & 2) v = fmaxf(v, 0.f);
      if (flags & 4) Cb[(size_t)row * N + col] = f2bf(v);
      else C[(size_t)row * N + col] = v;
    }
  }
}

__global__ __launch_bounds__(256) void k_gemm_mfma(const ushort_t* __restrict__ A,
                                                   const ushort_t* __restrict__ Bt,
                                                   const float* __restrict__ bias,
                                                   float* __restrict__ C,
                                                   ushort_t* __restrict__ Cb,
                                                   int N, int K, int flags) {
  gemm32x64_body(A, Bt, bias, C, Cb, N, K, flags, blockIdx.y * 32, blockIdx.x * 64);
}

// -------- FT GEMM: 64x128 tile, 4 waves x (32x64), global_load_lds staging,
// conflict-free fragment ds_reads, double-buffered (2 x 24KB LDS).
// flags: 1=+bias, 2=relu. omode: 0=fp32 rm, 1=bf16 rm, 2=FT(cftKT),
// 3=q(qwft=v+rwb FT, qrb=v+rrb rm), 4=k(kft FT, col-512), 5=v(vtft V^T FT).
__device__ __forceinline__ void gemm_ft_body(
    ushort_t* smem, const ushort_t* __restrict__ A, const ushort_t* __restrict__ Bt,
    const float* __restrict__ bias, int N, int K, int kBeg, int kEnd,
    int m0, int n0, int flags, int omode,
    float* __restrict__ Cf, ushort_t* __restrict__ Cb, int cftKT,
    ushort_t* __restrict__ aux, const float* __restrict__ rwb,
    const float* __restrict__ rrb) {
  const int tid = threadIdx.x;
  const int lane = tid & 63, wv = tid >> 6;
  const int wm = (wv >> 1) * 32, wn = (wv & 1) * 64;
  const int lm = lane & 15, quad = lane >> 4;
  const int AKT = K >> 5;                 // global k-tiles per 16-row block
  const int mt0 = m0 >> 4, nt0 = n0 >> 4;
  const int kt0 = kBeg >> 5;

  f32x4 acc[2][4];
#pragma unroll
  for (int i = 0; i < 2; ++i)
#pragma unroll
    for (int j = 0; j < 4; ++j) acc[i][j] = (f32x4)(0.f);

  auto stage = [&](ushort_t* dA, int ktg) {
    ushort_t* dB = dA + 4096;
#pragma unroll
    for (int it = 0; it < 6; ++it) {
      const int c = (it << 8) + tid;
      if (it < 2) {  // A chunks: c in [0,512)
        const int blk = c >> 6, ln = c & 63;
        gload16(A + (((size_t)(mt0 + (blk >> 1)) * AKT + ktg + (blk & 1)) << 9) + (ln << 3),
                dA + (c << 3));
      } else {       // B chunks: cB in [0,1024)
        const int cB = c - 512;
        const int blk = cB >> 6, ln = cB & 63;
        gload16(Bt + (((size_t)(nt0 + (blk >> 1)) * AKT + ktg + (blk & 1)) << 9) + (ln << 3),
                dB + (cB << 3));
      }
    }
  };
  auto compute = [&](const ushort_t* dA) {
    const ushort_t* dB = dA + 4096;
#pragma unroll
    for (int kk = 0; kk < 2; ++kk) {
      bf16x8 a[2], b[4];
#pragma unroll
      for (int i = 0; i < 2; ++i)
        a[i] = *(const bf16x8*)&dA[((((wm >> 4) + i) << 1) + kk) * 512 + (lane << 3)];
#pragma unroll
      for (int j = 0; j < 4; ++j)
        b[j] = *(const bf16x8*)&dB[((((wn >> 4) + j) << 1) + kk) * 512 + (lane << 3)];
#pragma unroll
      for (int i = 0; i < 2; ++i)
#pragma unroll
        for (int j = 0; j < 4; ++j)
          acc[i][j] = __builtin_amdgcn_mfma_f32_16x16x32_bf16(a[i], b[j], acc[i][j], 0, 0, 0);
    }
  };

  const int nIter = (kEnd - kBeg) >> 6;  // always even (8) here
  stage(smem, kt0);
  __syncthreads();
  for (int t = 0; t < nIter; t += 2) {
    if (t + 1 < nIter) stage(smem + 12288, kt0 + (t + 1) * 2);
    compute(smem);
    __syncthreads();
    if (t + 2 < nIter) stage(smem, kt0 + (t + 2) * 2);
    compute(smem + 12288);
    __syncthreads();
  }

#pragma unroll
  for (int i = 0; i < 2; ++i) {
    const int rowb = m0 + wm + i * 16 + quad * 4;
#pragma unroll
    for (int j = 0; j < 4; ++j) {
      const int col = n0 + wn + j * 16 + lm;
      const float bv = (flags & 1) ? bias[col] : 0.f;
#pragma unroll
      for (int t2 = 0; t2 < 4; ++t2) {
        const int row = rowb + t2;
        float v = acc[i][j][t2] + bv;
        if (flags & 2) v = fmaxf(v, 0.f);
        if (omode == 0) {
          Cf[(size_t)row * N + col] = v;
        } else if (omode == 1) {
          Cb[(size_t)row * N + col] = f2bf(v);
        } else if (omode == 2) {
          Cb[(((size_t)(row >> 4) * cftKT + (col >> 5)) << 9) +
             (((col >> 3) & 3) << 7) + ((row & 15) << 3) + (col & 7)] = f2bf(v);
        } else if (omode == 3) {
          Cb[ft512(row, col)] = f2bf(v + rwb[col]);
          aux[(size_t)row * DM + col] = f2bf(v + rrb[col]);
        } else if (omode == 4) {
          Cb[ft512(row, col - 512)] = f2bf(v);
        } else {  // omode 5: V^T FT, r = v-dim, c = token
          const int dv = col - 1024;
          Cb[((size_t)(dv >> 4) * 65 + (row >> 5)) * 512 +
             (((row >> 3) & 3) << 7) + ((dv & 15) << 3) + (row & 7)] = f2bf(v);
        }
      }
    }
  }
}

// merged QKV + Wr GEMMs (FT); q-part -> qwft(+rwb) & qrb(+rrb); k -> kft;
// v -> vtft (V^T FT); Wr -> rbg (rm)
__global__ __launch_bounds__(256) void k_gemm_qkvwr_ft(
    const ushort_t* __restrict__ wbft, const ushort_t* __restrict__ posft,
    const ushort_t* __restrict__ qkvT, const ushort_t* __restrict__ wrT,
    ushort_t* __restrict__ qwft, ushort_t* __restrict__ kft,
    ushort_t* __restrict__ vtft, ushort_t* __restrict__ rbg,
    ushort_t* __restrict__ qrb, const float* __restrict__ rwb,
    const float* __restrict__ rrb) {
  __shared__ ushort_t smem[24576];
  int m0 = blockIdx.y * 64;
  if (m0 + 64 > TT) m0 = TT - 64;  // overlapped last tile (dup writes benign)
  const int bx = blockIdx.x;
  if (bx < 12) {
    const int om = (bx < 4) ? 3 : (bx < 8 ? 4 : 5);
    ushort_t* dst = (om == 3) ? qwft : (om == 4) ? kft : vtft;
    gemm_ft_body(smem, wbft, qkvT, nullptr, QKV_N, DM, 0, DM, m0, bx * 128,
                 0, om, nullptr, dst, 0, qrb, rwb, rrb);
  } else {
    gemm_ft_body(smem, posft, wrT, nullptr, DM, DM, 0, DM, m0, (bx - 12) * 128,
                 0, 1, nullptr, rbg, 0, nullptr, nullptr, nullptr);
  }
}

// FFN1: wbft x w1T -> ff1ft (FT, K_out = DI), bias+relu
__global__ __launch_bounds__(256) void k_ffn1_ft(const ushort_t* __restrict__ wbft,
                                                 const ushort_t* __restrict__ w1T,
                                                 const float* __restrict__ b1l,
                                                 ushort_t* __restrict__ ff1ft) {
  __shared__ ushort_t smem[24576];
  int m0 = blockIdx.y * 64;
  if (m0 + 64 > TT) m0 = TT - 64;
  gemm_ft_body(smem, wbft, w1T, b1l, DI, DM, 0, DM, m0, blockIdx.x * 128,
               1 | 2, 2, nullptr, ff1ft, DI >> 5, nullptr, nullptr, nullptr);
}

// FFN2: ff1ft x w2T -> fp32 partials (split-K=4); bias folded into split 0
__global__ __launch_bounds__(256) void k_ffn2_ft(const ushort_t* __restrict__ ff1ft,
                                                 const ushort_t* __restrict__ w2T,
                                                 const float* __restrict__ b2l,
                                                 float* __restrict__ ff2p) {
  __shared__ ushort_t smem[24576];
  int m0 = blockIdx.y * 64;
  if (m0 + 64 > TT) m0 = TT - 64;
  const int s = blockIdx.z;
  gemm_ft_body(smem, ff1ft, w2T, b2l, DM, DI, s * 512, s * 512 + 512, m0,
               blockIdx.x * 128, (s == 0) ? 1 : 0, 0,
               ff2p + (size_t)s * TT * DM, nullptr, 0, nullptr, nullptr, nullptr);
}

// ---- QR GEMM: QR[h][i][k] = qr_i . r_k ------------------------------------
// Output: BD in per-(qt,jt)-tile C-fragment order (streamable by k_attn) +
// wrap values wrapv[h][row][w<16] (overlaid on dead attnb space).
__global__ __launch_bounds__(256) void k_qr(const ushort_t* __restrict__ qrb,
                                            const ushort_t* __restrict__ rbg,
                                            ushort_t* __restrict__ bdf,
                                            ushort_t* __restrict__ wrapv) {
  const int h = blockIdx.z;
  const int m0 = blockIdx.y * 32, n0 = blockIdx.x * 64;
  if (!(n0 == 0 || n0 + 63 >= TT - 32 - m0)) return;
  __shared__ short As[32][72];
  __shared__ short Bs[64][72];
  const int tid = threadIdx.x;
  const int lane = tid & 63, wv = tid >> 6;
  const int wm = (wv >> 1) * 16, wn = (wv & 1) * 32;
  const int lm = lane & 15, quad = lane >> 4;
  const int sr = tid >> 3, sc8 = (tid & 7) * 8;
  const uint4 zero4 = make_uint4(0, 0, 0, 0);

  *(uint4*)&As[sr][sc8] = *(const uint4*)&qrb[(size_t)(m0 + sr) * DM + h * DH + sc8];
  int br0 = n0 + sr, br1 = n0 + sr + 32;
  *(uint4*)&Bs[sr][sc8] =
      (br0 < TT) ? *(const uint4*)&rbg[(size_t)br0 * DM + h * DH + sc8] : zero4;
  *(uint4*)&Bs[sr + 32][sc8] =
      (br1 < TT) ? *(const uint4*)&rbg[(size_t)br1 * DM + h * DH + sc8] : zero4;
  __syncthreads();

  f32x4 acc[2];
  acc[0] = (f32x4)(0.f); acc[1] = (f32x4)(0.f);
#pragma unroll
  for (int kk = 0; kk < 64; kk += 32) {
    bf16x8 a = *(const bf16x8*)&As[wm + lm][kk + quad * 8];
    bf16x8 b0 = *(const bf16x8*)&Bs[wn + lm][kk + quad * 8];
    bf16x8 b1 = *(const bf16x8*)&Bs[wn + 16 + lm][kk + quad * 8];
    acc[0] = __builtin_amdgcn_mfma_f32_16x16x32_bf16(a, b0, acc[0], 0, 0, 0);
    acc[1] = __builtin_amdgcn_mfma_f32_16x16x32_bf16(a, b1, acc[1], 0, 0, 0);
  }
  const size_t hb = (size_t)h * BDF_HEAD;
  const size_t hw = (size_t)h * WRAP_HEAD;
#pragma unroll
  for (int nt = 0; nt < 2; ++nt) {
    int col = n0 + wn + nt * 16 + lm;
    if (col >= TT) continue;
#pragma unroll
    for (int t = 0; t < 4; ++t) {
      int row = m0 + wm + quad * 4 + t;
      float v = acc[nt][t];
      ushort_t vb = f2bf(v);
      int p = row + col - (TT - 1);  // = causal column j
      if (p >= 0) {
        int qti = row >> 5, jti = p >> 5;
        int ri = row & 31, cj = p & 31;
        size_t tb = hb + (((size_t)(qti * (qti + 1) / 2 + jti)) << 10);
        size_t off = (size_t)((((ri >> 4) * 2 + (cj >> 4)) << 8) +
                              ((((ri & 15) >> 2) * 16 + (cj & 15)) << 2) + (ri & 3));
        bdf[tb + off] = vb;
      }
      if (col < 16) wrapv[hw + row * 16 + col] = vb;  // wrap value QR[row][col]
    }
  }
}

// ------- wave-autonomous MFMA flash attention ------------------------------
// Block = (qt, h); each of its 4 waves owns chunk c = wave-id, processing
// j-tiles jt = c, c+4, ... <= qt with ZERO block barriers. All MFMA operands
// load global->VGPR as FT fragments; softmax is fully in-register; only the
// P transpose round-trips 2KB of wave-private LDS (same-wave DS is in-order;
// fenced per guide rule #18).
__global__ __launch_bounds__(256) void k_attn(const ushort_t* __restrict__ qwft,
                                              const ushort_t* __restrict__ kft,
                                              const ushort_t* __restrict__ vtft,
                                              const ushort_t* __restrict__ bdf,
                                              const ushort_t* __restrict__ wrapv,
                                              float* __restrict__ mlP,
                                              ushort_t* __restrict__ opP) {
  const int h = blockIdx.y;
  const int qt = 64 - blockIdx.x;  // heavy q-tiles dispatch first
  const int tid = threadIdx.x;
  const int wv = tid >> 6;         // wave = chunk id
  if (wv > qt) return;             // wave-level early out (no barriers used)
  const int lane = tid & 63;
  const int lm = lane & 15, quad = lane >> 4;
  const int i0 = qt * 32;

  __shared__ ushort_t pbl[4][1024];  // per-wave P B-fragments (2 x 1KB blocks)

  // Q fragments (loop-invariant), direct global->VGPR
  bf16x8 qf[2][2];
#pragma unroll
  for (int qi = 0; qi < 2; ++qi)
#pragma unroll
    for (int kt = 0; kt < 2; ++kt)
      qf[qi][kt] = *(const bf16x8*)&qwft[(((size_t)((i0 >> 4) + qi) * 16) +
                                         h * 2 + kt) * 512 + (lane << 3)];

  const size_t hbd = (size_t)h * BDF_HEAD + (((size_t)(qt * (qt + 1) / 2)) << 10);
  const size_t hwr = (size_t)h * WRAP_HEAD;

  float mreg[2][4], lreg[2][4];
#pragma unroll
  for (int qi = 0; qi < 2; ++qi)
#pragma unroll
    for (int t = 0; t < 4; ++t) { mreg[qi][t] = -INFINITY; lreg[qi][t] = 0.f; }
  f32x4 o[4][2];  // [dt][iq]: O^T rows d=dt*16+quad*4+tt, cols i=iq*16+lm
#pragma unroll
  for (int dt = 0; dt < 4; ++dt)
#pragma unroll
    for (int iq = 0; iq < 2; ++iq) o[dt][iq] = (f32x4)(0.f);

  for (int jt = wv; jt <= qt; jt += NCH) {
    const int j0 = jt * 32;
    // ---- fragment loads (global->VGPR, compiler-scheduled) ----
    bf16x8 kf[2][2];  // [jq][kt]
#pragma unroll
    for (int jq = 0; jq < 2; ++jq)
#pragma unroll
      for (int kt = 0; kt < 2; ++kt)
        kf[jq][kt] = *(const bf16x8*)&kft[(((size_t)((j0 >> 4) + jq) * 16) +
                                          h * 2 + kt) * 512 + (lane << 3)];
    bf16x8 vf[4];  // [dt]
#pragma unroll
    for (int dt = 0; dt < 4; ++dt)
      vf[dt] = *(const bf16x8*)&vtft[(((size_t)(h * 4 + dt)) * 65 + jt) * 512 +
                                     (lane << 3)];
    uint2 bd[2][2];  // [qi][jq]: 4 bf16 (t=0..3) in C-fragment order
#pragma unroll
    for (int qi = 0; qi < 2; ++qi)
#pragma unroll
      for (int jq = 0; jq < 2; ++jq)
        bd[qi][jq] = *(const uint2*)&bdf[hbd + ((size_t)jt << 10) +
                                         ((qi * 2 + jq) << 8) + (lane << 2)];

    // ---- QK^T: scores in accumulators ----
    f32x4 sA[2][2];
#pragma unroll
    for (int qi = 0; qi < 2; ++qi)
#pragma unroll
      for (int jq = 0; jq < 2; ++jq) {
        f32x4 ac = (f32x4)(0.f);
#pragma unroll
        for (int kt = 0; kt < 2; ++kt)
          ac = __builtin_amdgcn_mfma_f32_16x16x32_bf16(qf[qi][kt], kf[jq][kt], ac, 0, 0, 0);
        sA[qi][jq] = ac;
      }

    // ---- score assembly (in-register) ----
    if (jt < qt) {  // all-causal tile
#pragma unroll
      for (int qi = 0; qi < 2; ++qi)
#pragma unroll
        for (int jq = 0; jq < 2; ++jq) {
          float b0 = bf2f((ushort_t)(bd[qi][jq].x & 0xffffu));
          float b1 = bf2f((ushort_t)(bd[qi][jq].x >> 16));
          float b2 = bf2f((ushort_t)(bd[qi][jq].y & 0xffffu));
          float b3 = bf2f((ushort_t)(bd[qi][jq].y >> 16));
          sA[qi][jq][0] = (sA[qi][jq][0] + b0) * ATT_SCALE;
          sA[qi][jq][1] = (sA[qi][jq][1] + b1) * ATT_SCALE;
          sA[qi][jq][2] = (sA[qi][jq][2] + b2) * ATT_SCALE;
          sA[qi][jq][3] = (sA[qi][jq][3] + b3) * ATT_SCALE;
        }
    } else {  // diagonal tile: mask + mem-corner + wrap
#pragma unroll
      for (int qi = 0; qi < 2; ++qi)
#pragma unroll
        for (int jq = 0; jq < 2; ++jq) {
          float bdv[4];
          bdv[0] = bf2f((ushort_t)(bd[qi][jq].x & 0xffffu));
          bdv[1] = bf2f((ushort_t)(bd[qi][jq].x >> 16));
          bdv[2] = bf2f((ushort_t)(bd[qi][jq].y & 0xffffu));
          bdv[3] = bf2f((ushort_t)(bd[qi][jq].y >> 16));
          const int j = j0 + jq * 16 + lm;
#pragma unroll
          for (int t = 0; t < 4; ++t) {
            const int i = i0 + qi * 16 + quad * 4 + t;
            const float acv = sA[qi][jq][t];
            float s;
            if (j <= i) {
              s = (acv + bdv[t]) * ATT_SCALE;
            } else {
              bool inmem = (i < NMTOK && j < NMTOK) ||
                           (i >= TT - NMTOK && j >= TT - NMTOK);
              if (!inmem) s = -1e30f;
              else if (j == i + 1) s = acv * ATT_SCALE;  // rel_shift zero-pad
              else s = (acv + bf2f(wrapv[hwr + (i + 1) * 16 + (j - i - 2)])) * ATT_SCALE;
            }
            sA[qi][jq][t] = s;
          }
        }
    }

    // ---- online softmax (row = qi*16+quad*4+t; reduce over jq + 16 lanes) --
    float mx[2][4];
#pragma unroll
    for (int qi = 0; qi < 2; ++qi)
#pragma unroll
      for (int t = 0; t < 4; ++t)
        mx[qi][t] = fmaxf(sA[qi][0][t], sA[qi][1][t]);
#pragma unroll
    for (int off = 1; off < 16; off <<= 1)
#pragma unroll
      for (int qi = 0; qi < 2; ++qi)
#pragma unroll
        for (int t = 0; t < 4; ++t)
          mx[qi][t] = fmaxf(mx[qi][t], __shfl_xor(mx[qi][t], off));
    float al[2][4];
#pragma unroll
    for (int qi = 0; qi < 2; ++qi)
#pragma unroll
      for (int t = 0; t < 4; ++t) {
        float mnew = fmaxf(mreg[qi][t], mx[qi][t]);
        al[qi][t] = __expf(mreg[qi][t] - mnew);
        mreg[qi][t] = mnew;
      }
    // p = exp(s - m), row sums
    float ps[2][4];
#pragma unroll
    for (int qi = 0; qi < 2; ++qi)
#pragma unroll
      for (int t = 0; t < 4; ++t) {
        sA[qi][0][t] = __expf(sA[qi][0][t] - mreg[qi][t]);
        sA[qi][1][t] = __expf(sA[qi][1][t] - mreg[qi][t]);
        ps[qi][t] = sA[qi][0][t] + sA[qi][1][t];
      }
#pragma unroll
    for (int off = 1; off < 16; off <<= 1)
#pragma unroll
      for (int qi = 0; qi < 2; ++qi)
#pragma unroll
        for (int t = 0; t < 4; ++t)
          ps[qi][t] += __shfl_xor(ps[qi][t], off);
#pragma unroll
    for (int qi = 0; qi < 2; ++qi)
#pragma unroll
      for (int t = 0; t < 4; ++t)
        lreg[qi][t] = lreg[qi][t] * al[qi][t] + ps[qi][t];

    // ---- alpha broadcast to column layout via shfl ----
    float aw[2];
    {
      const int src = (lm >> 2) << 4;  // lane holding rows (lm>>2)*4+t
      const int t3 = lm & 3;
#pragma unroll
      for (int iq = 0; iq < 2; ++iq) {
        float g0 = __shfl(al[iq][0], src);
        float g1 = __shfl(al[iq][1], src);
        float g2 = __shfl(al[iq][2], src);
        float g3 = __shfl(al[iq][3], src);
        aw[iq] = (t3 == 0) ? g0 : (t3 == 1) ? g1 : (t3 == 2) ? g2 : g3;
      }
    }
#pragma unroll
    for (int dt = 0; dt < 4; ++dt)
#pragma unroll
      for (int iq = 0; iq < 2; ++iq)
#pragma unroll
        for (int tt = 0; tt < 4; ++tt) o[dt][iq][tt] *= aw[iq];

    // ---- P -> wave-private LDS in B-fragment order ----
#pragma unroll
    for (int qi = 0; qi < 2; ++qi)
#pragma unroll
      for (int jq = 0; jq < 2; ++jq)
#pragma unroll
        for (int t = 0; t < 4; ++t)
          pbl[wv][(qi << 9) +
                  (((jq * 2 + (lm >> 3)) * 16 + (quad * 4 + t)) << 3) +
                  (lm & 7)] = f2bf(sA[qi][jq][t]);
    asm volatile("s_waitcnt lgkmcnt(0)" ::: "memory");
    __builtin_amdgcn_sched_barrier(0);
    bf16x8 pf[2];
#pragma unroll
    for (int iq = 0; iq < 2; ++iq)
      pf[iq] = *(const bf16x8*)&pbl[wv][(iq << 9) + (lane << 3)];

    // ---- PV: O^T += V^T * P^T ----
#pragma unroll
    for (int dt = 0; dt < 4; ++dt)
#pragma unroll
      for (int iq = 0; iq < 2; ++iq)
        o[dt][iq] = __builtin_amdgcn_mfma_f32_16x16x32_bf16(vf[dt], pf[iq], o[dt][iq], 0, 0, 0);
  }

  // ---- write partials ----
  const int pidx = (qt * NH + h) * NCH + wv;
  if (lm == 0) {
#pragma unroll
    for (int qi = 0; qi < 2; ++qi)
#pragma unroll
      for (int t = 0; t < 4; ++t) {
        mlP[(size_t)pidx * 64 + qi * 16 + quad * 4 + t] = mreg[qi][t];
        mlP[(size_t)pidx * 64 + 32 + qi * 16 + quad * 4 + t] = lreg[qi][t];
      }
  }
  const size_t ob = (size_t)pidx * 2048;
#pragma unroll
  for (int iq = 0; iq < 2; ++iq)
#pragma unroll
    for (int dt = 0; dt < 4; ++dt) {
      ushort_t o4[4];
#pragma unroll
      for (int tt = 0; tt < 4; ++tt) o4[tt] = f2bf(o[dt][iq][tt]);
      *(uint2*)&opP[ob + (size_t)(iq * 16 + lm) * 64 + dt * 16 + quad * 4] =
          *(uint2*)o4;
    }
}

// -------- combine <=NCH chunk partials -> normalized attn output ----------
__global__ __launch_bounds__(256) void k_attn_combine(const float* __restrict__ mlP,
                                                      const ushort_t* __restrict__ opP,
                                                      ushort_t* __restrict__ attnb) {
  const int qt = blockIdx.x, h = blockIdx.y;
  const int nc = (qt + 1 < NCH) ? qt + 1 : NCH;
  const int tid = threadIdx.x;
  const int i = tid >> 3, d8 = (tid & 7) * 8;
  const size_t base = (size_t)(qt * NH + h) * NCH;
  float m[NCH], l[NCH], wgt[NCH];
  float M = -INFINITY;
  for (int cc = 0; cc < nc; ++cc) {
    m[cc] = mlP[(base + cc) * 64 + i];
    l[cc] = mlP[(base + cc) * 64 + 32 + i];
    M = fmaxf(M, m[cc]);
  }
  float L = 0.f;
  for (int cc = 0; cc < nc; ++cc) { wgt[cc] = __expf(m[cc] - M); L += l[cc] * wgt[cc]; }
  float acc[8] = {0, 0, 0, 0, 0, 0, 0, 0};
  for (int cc = 0; cc < nc; ++cc) {
    uint4 v = *(const uint4*)&opP[(base + cc) * 2048 + (size_t)i * 64 + d8];
    float f[8]; unpack8(v, f);
#pragma unroll
    for (int k = 0; k < 8; ++k) acc[k] += wgt[cc] * f[k];
  }
  const float inv = 1.f / L;
  ushort_t o8[8];
#pragma unroll
  for (int k = 0; k < 8; ++k) o8[k] = f2bf(acc[k] * inv);
  *(uint4*)&attnb[(size_t)(qt * 32 + i) * DM + h * DH + d8] = *(uint4*)o8;
}

// -------- w' = LayerNorm(w + sum(delta parts)) * g + b ---------------------
__global__ __launch_bounds__(256) void k_addln(const float* __restrict__ w,
                                               float* __restrict__ wout,
                                               ushort_t* __restrict__ wbft,
                                               const float* __restrict__ delta,
                                               int nparts,
                                               const float* __restrict__ gamma,
                                               const float* __restrict__ beta) {
  const int row = blockIdx.x;
  const int tid = threadIdx.x;
  __shared__ float red[4], red2[4];
  __shared__ float sm[512];
  size_t base = (size_t)row * DM;
  float x0 = w[base + tid];
  float x1 = w[base + tid + 256];
  for (int p = 0; p < nparts; ++p) {
    x0 += delta[(size_t)p * TT * DM + base + tid];
    x1 += delta[(size_t)p * TT * DM + base + tid + 256];
  }
  float s = x0 + x1;
#pragma unroll
  for (int off = 1; off < 64; off <<= 1) s += __shfl_xor(s, off);
  if ((tid & 63) == 0) red[tid >> 6] = s;
  __syncthreads();
  float mu = (red[0] + red[1] + red[2] + red[3]) * (1.f / 512.f);
  float d0 = x0 - mu, d1 = x1 - mu;
  float v = d0 * d0 + d1 * d1;
#pragma unroll
  for (int off = 1; off < 64; off <<= 1) v += __shfl_xor(v, off);
  if ((tid & 63) == 0) red2[tid >> 6] = v;
  __syncthreads();
  float var = (red2[0] + red2[1] + red2[2] + red2[3]) * (1.f / 512.f);
  float rstd = rsqrtf(var + 1e-5f);
  float o0 = d0 * rstd * gamma[tid] + beta[tid];
  float o1 = d1 * rstd * gamma[tid + 256] + beta[tid + 256];
  wout[base + tid] = o0;
  wout[base + tid + 256] = o1;
  sm[tid] = o0; sm[tid + 256] = o1;
  __syncthreads();
  if (tid < 64) {
    const int d8 = tid << 3;
    ushort_t t8[8];
#pragma unroll
    for (int e = 0; e < 8; ++e) t8[e] = f2bf(sm[d8 + e]);
    *(uint4*)&wbft[ft512(row, d8)] = *(uint4*)t8;
  }
}

extern "C" void kernel_launch(void* const* d_in, const int* in_sizes, int n_in,
                              void* d_out, int out_size, void* d_ws, size_t ws_size,
                              hipStream_t stream) {
  const float* we   = (const float*)d_in[0];
  const float* mem  = (const float*)d_in[1];
  const float* Wqkv = (const float*)d_in[2];
  const float* Wr   = (const float*)d_in[3];
  const float* Wo   = (const float*)d_in[4];
  const float* ln1s = (const float*)d_in[5];
  const float* ln1b = (const float*)d_in[6];
  const float* W1   = (const float*)d_in[7];
  const float* b1   = (const float*)d_in[8];
  const float* W2   = (const float*)d_in[9];
  const float* b2   = (const float*)d_in[10];
  const float* ln2s = (const float*)d_in[11];
  const float* ln2b = (const float*)d_in[12];
  const float* rwb  = (const float*)d_in[13];
  const float* rrb  = (const float*)d_in[14];

  // ---- workspace layout (same footprint as before) ----
  float* w     = (float*)d_ws;                        // TT*DM fp32
  float* proj  = w + (size_t)TT * DM;                 // TT*DM fp32 (Wo out)
  ushort_t* wbft  = (ushort_t*)(proj + (size_t)TT * DM);  // TT*DM bf16 (FT)
  ushort_t* posft = wbft + (size_t)TT * DM;           // TT*DM bf16 (FT)
  ushort_t* attnb = posft + (size_t)TT * DM;          // TT*DM bf16 (rm)
  ushort_t* qkvB  = attnb + (size_t)TT * DM;          // TT*1536 bf16 region
  ushort_t* qwft  = qkvB;                             // TT*DM (Q+rwb, FT)
  ushort_t* kft   = qkvB + (size_t)TT * DM;           // TT*DM (K, FT)
  ushort_t* vtft  = qkvB + (size_t)2 * TT * DM;       // DM*TT (V^T, FT)
  ushort_t* rbg   = qkvB + (size_t)TT * QKV_N;        // TT*DM bf16 (rm)
  ushort_t* WtAll = rbg + (size_t)TT * DM;            // 4 layers x WT_STRIDE shorts
  ushort_t* opP   = WtAll + (size_t)NLAYER * WT_STRIDE;  // partial O region
  float* mlP   = (float*)(opP + (size_t)65 * 8 * 8 * 2048);  // partial m/l region
  ushort_t* qrb  = (ushort_t*)(mlP + (size_t)65 * 8 * 8 * 64);  // TT*DM bf16
  ushort_t* bdf  = qrb + (size_t)TT * DM;             // NH * BDF_HEAD shorts
  ushort_t* wrapv = attnb;           // overlay: wrap values live in dead attnb
  // overlays (time-shared, stream-ordered):
  ushort_t* ff1ft = qkvB;            // FT TT*DI bf16 spans qkv region + rbg
  float* ff2p  = (float*)opP;        // 4 split-K partials, 4*TT*DM f32
  const size_t OFF_QKVT = 0, OFF_WRT = 786432, OFF_WOT = 1048576,
               OFF_W1T = 1310720, OFF_W2T = 2359296;

  // all-layer weight transpose(+FT pack) + build in one dispatch
  k_prep<<<13312 + 4160, 256, 0, stream>>>(Wqkv, Wr, Wo, W1, W2, WtAll,
                                           we, mem, w, wbft, posft);

  dim3 gQW(16, 33);          // merged QKV (12 n-tiles) + Wr (4 n-tiles), 64x128
  dim3 gW1(16, 33);          // FFN1 64x128
  dim3 gW2(4, 33, 4);        // FFN2 64x128, split-K=4
  dim3 gDM32(DM / 64, 65);   // Wo (old 32x64 kernel)
  dim3 gQR(33, 65, NH);
  dim3 gA(65, NH);           // wave-autonomous attention: 4 chunks = 4 waves
  dim3 gC(65, NH);

  for (int l = 0; l < NLAYER; ++l) {
    const ushort_t* Wt = WtAll + (size_t)l * WT_STRIDE;
    k_gemm_qkvwr_ft<<<gQW, 256, 0, stream>>>(wbft, posft, Wt + OFF_QKVT,
                                             Wt + OFF_WRT, qwft, kft, vtft,
                                             rbg, qrb, rwb, rrb);
    k_qr<<<gQR, 256, 0, stream>>>(qrb, rbg, bdf, wrapv);
    k_attn<<<gA, 256, 0, stream>>>(qwft, kft, vtft, bdf, wrapv, mlP, opP);
    k_attn_combine<<<gC, 256, 0, stream>>>(mlP, opP, attnb);
    k_gemm_mfma<<<gDM32, 256, 0, stream>>>(attnb, Wt + OFF_WOT, nullptr, proj, nullptr,
                                           DM, DM, 0);
    k_addln<<<TT, 256, 0, stream>>>(w, w, wbft, proj, 1,
                                    ln1s + (size_t)l * DM, ln1b + (size_t)l * DM);
    k_ffn1_ft<<<gW1, 256, 0, stream>>>(wbft, Wt + OFF_W1T, b1 + (size_t)l * DI, ff1ft);
    k_ffn2_ft<<<gW2, 256, 0, stream>>>(ff1ft, Wt + OFF_W2T, b2 + (size_t)l * DM, ff2p);
    float* wout = (l == NLAYER - 1) ? (float*)d_out : w;
    k_addln<<<TT, 256, 0, stream>>>(w, wout, wbft, ff2p, 4,
                                    ln2s + (size_t)l * DM, ln2b + (size_t)l * DM);
  }
}

// Round 8
// 665.404 us; speedup vs baseline: 1.0162x; 1.0162x over previous
//
#include <hip/hip_runtime.h>
#include <hip/hip_bf16.h>
#include <math.h>
#include <stdint.h>

#define TT 2080
#define DM 512
#define DI 2048
#define NH 8
#define DH 64
#define NMTOK 16
#define NLAYER 4
#define QKV_N 1536
#define ATT_SCALE 0.125f
#define NCHT 8              // total attention chunks per (qt,h)
#define WT_STRIDE 3407872   // shorts per layer's transposed-weight block
#define BDF_HEAD 2196480    // shorts per head of fragment-ordered BD tiles (2145*1024)
#define WRAP_HEAD 33280     // shorts per head of wrap values (TT*16)

typedef short bf16x8 __attribute__((ext_vector_type(8)));
typedef float f32x4 __attribute__((ext_vector_type(4)));
typedef unsigned short ushort_t;

__device__ __forceinline__ ushort_t f2bf(float f) {
  __hip_bfloat16 h = __float2bfloat16(f);
  return *reinterpret_cast<ushort_t*>(&h);
}
__device__ __forceinline__ float bfbits2f(unsigned int hi_bits) {
  return __uint_as_float(hi_bits);
}
__device__ __forceinline__ float bf2f(ushort_t u) {
  return bfbits2f(((unsigned int)u) << 16);
}
__device__ __forceinline__ void unpack8(uint4 v, float* f) {
  f[0] = bfbits2f(v.x << 16); f[1] = bfbits2f(v.x & 0xffff0000u);
  f[2] = bfbits2f(v.y << 16); f[3] = bfbits2f(v.y & 0xffff0000u);
  f[4] = bfbits2f(v.z << 16); f[5] = bfbits2f(v.z & 0xffff0000u);
  f[6] = bfbits2f(v.w << 16); f[7] = bfbits2f(v.w & 0xffff0000u);
}
__device__ __forceinline__ unsigned int pack2(ushort_t lo, ushort_t hi) {
  return (unsigned int)lo | ((unsigned int)hi << 16);
}
// Barrier draining LDS ops only — leaves global (vmcnt) loads in flight.
__device__ __forceinline__ void barrier_lds() {
  asm volatile("s_waitcnt lgkmcnt(0)" ::: "memory");
  __builtin_amdgcn_s_barrier();
}
// global -> LDS direct copy, 16B per lane (FT GEMM staging).
__device__ __forceinline__ void gload16(const ushort_t* g, ushort_t* l) {
  __builtin_amdgcn_global_load_lds(
      (__attribute__((address_space(1))) void*)(uintptr_t)g,
      (__attribute__((address_space(3))) void*)(uintptr_t)l, 16, 0, 0);
}
// ---- fragment-tiled (FT) layout --------------------------------------------
// Matrix X[R][K] (bf16) stored as 1024B blocks of (16 r x 32 k); lane
// = ((k>>3)&3)*16 + (r&15) holds 8 consecutive k-elements = EXACTLY the
// mfma_f32_16x16x32_bf16 A/B fragment order.
__device__ __forceinline__ size_t ft512(int r, int c) {  // K = 512 (KT = 16)
  return (((size_t)(r >> 4) * 16 + (c >> 5)) << 9) + (((c >> 3) & 3) << 7) +
         ((r & 15) << 3) + (c & 7);
}

// ---- fused prep: all 4 layers' weight transposes + build w/pos ------------
__global__ __launch_bounds__(256) void k_prep(
    const float* __restrict__ Wqkv, const float* __restrict__ Wr,
    const float* __restrict__ Wo, const float* __restrict__ W1,
    const float* __restrict__ W2, ushort_t* __restrict__ dstAll,
    const float* __restrict__ we, const float* __restrict__ mem,
    float* __restrict__ w, ushort_t* __restrict__ wbft,
    ushort_t* __restrict__ posft) {
  const int tid = threadIdx.x;
  if (blockIdx.x >= 13312) {  // ---- build ----
    int idx = (blockIdx.x - 13312) * 256 + tid;
    if (idx >= TT * DM) return;
    int t = idx >> 9, d = idx & 511;
    float v;
    if (t < NMTOK) v = mem[t * DM + d];
    else if (t < NMTOK + 2048) v = we[(t - NMTOK) * DM + d];
    else v = mem[(t - (NMTOK + 2048)) * DM + d];
    w[idx] = v;
    wbft[ft512(t, d)] = f2bf(v);
    float p = (float)(TT - 1 - t);
    int i2 = d & 255;
    float freq = __expf(-0.035977892f * (float)i2);
    float ang = p * freq;
    posft[ft512(t, d)] = f2bf((d < 256) ? __sinf(ang) : __cosf(ang));
    return;
  }
  // ---- transpose+cast, layer l ----
  __shared__ float tl[32][33];
  const int l = blockIdx.x / 3328;
  int idx = blockIdx.x % 3328;
  const float* src;
  ushort_t* dst = dstAll + (size_t)l * WT_STRIDE;
  int K, N, local;
  bool isFT = true;
  if (idx < 768)       { src = Wqkv + (size_t)l * 512 * 1536; K = 512;  N = 1536; local = idx; }
  else if (idx < 1024) { src = Wr   + (size_t)l * 512 * 512;  dst += 786432;  K = 512;  N = 512;  local = idx - 768; }
  else if (idx < 1280) { src = Wo   + (size_t)l * 512 * 512;  dst += 1048576; K = 512;  N = 512;  local = idx - 1024; isFT = false; }
  else if (idx < 2304) { src = W1   + (size_t)l * 512 * 2048; dst += 1310720; K = 512;  N = 2048; local = idx - 1280; }
  else                 { src = W2   + (size_t)l * 2048 * 512; dst += 2359296; K = 2048; N = 512;  local = idx - 2304; }
  const int ntiles = N / 32;
  const int n0 = (local % ntiles) * 32, k0 = (local / ntiles) * 32;
#pragma unroll
  for (int p = 0; p < 4; ++p) {
    int row = (tid >> 5) + 8 * p, col = tid & 31;
    tl[row][col] = src[(size_t)(k0 + row) * N + n0 + col];  // tl[k][n]
  }
  __syncthreads();
  if (isFT) {
    if (tid < 128) {
      int b = tid >> 6, l2 = tid & 63;
      int nn = b * 16 + (l2 & 15);
      int kq = (l2 >> 4) * 8;
      ushort_t t8[8];
#pragma unroll
      for (int e = 0; e < 8; ++e) t8[e] = f2bf(tl[kq + e][nn]);
      size_t ad = (((size_t)((n0 >> 4) + b) * (K >> 5) + (k0 >> 5)) << 9) +
                  ((size_t)l2 << 3);
      *(uint4*)&dst[ad] = *(uint4*)t8;
    }
  } else {
#pragma unroll
    for (int p = 0; p < 4; ++p) {
      int n = (tid >> 5) + 8 * p, k = tid & 31;
      dst[(size_t)(n0 + n) * K + k0 + k] = f2bf(tl[k][n]);
    }
  }
}

// -------- bf16 MFMA GEMM body, 32x64 tile, register prefetch (Wo only) ----
__device__ __forceinline__ void gemm32x64_body(const ushort_t* __restrict__ A,
                                               const ushort_t* __restrict__ Bt,
                                               const float* __restrict__ bias,
                                               float* __restrict__ C,
                                               ushort_t* __restrict__ Cb,
                                               int N, int K, int flags,
                                               int m0, int n0) {
  __shared__ short As[32][72];
  __shared__ short Bs[64][72];
  const int tid = threadIdx.x;
  const int lane = tid & 63, wv = tid >> 6;
  const int wm = (wv >> 1) * 16, wn = (wv & 1) * 32;
  const int lm = lane & 15, quad = lane >> 4;
  const int sr = tid >> 3, sc8 = (tid & 7) * 8;

  f32x4 acc[2];
  acc[0] = (f32x4)(0.f); acc[1] = (f32x4)(0.f);

  auto loadA = [&](int k0) -> uint4 {
    return *(const uint4*)&A[(size_t)(m0 + sr) * K + k0 + sc8];
  };
  auto loadB = [&](int row, int k0) -> uint4 {
    return *(const uint4*)&Bt[(size_t)(n0 + row) * K + k0 + sc8];
  };

  uint4 aC = loadA(0), b0C = loadB(sr, 0), b1C = loadB(sr + 32, 0);

  for (int k0 = 0; k0 < K; k0 += 64) {
    const int kn = (k0 + 64 < K) ? k0 + 64 : k0;  // clamped tail reload
    uint4 aN = loadA(kn), b0N = loadB(sr, kn), b1N = loadB(sr + 32, kn);
    barrier_lds();  // prev ds_reads done; vm prefetches stay in flight
    *(uint4*)&As[sr][sc8] = aC;
    *(uint4*)&Bs[sr][sc8] = b0C;
    *(uint4*)&Bs[sr + 32][sc8] = b1C;
    barrier_lds();
#pragma unroll
    for (int kk = 0; kk < 64; kk += 32) {
      bf16x8 a = *(const bf16x8*)&As[wm + lm][kk + quad * 8];
      bf16x8 b0 = *(const bf16x8*)&Bs[wn + lm][kk + quad * 8];
      bf16x8 b1 = *(const bf16x8*)&Bs[wn + 16 + lm][kk + quad * 8];
      acc[0] = __builtin_amdgcn_mfma_f32_16x16x32_bf16(a, b0, acc[0], 0, 0, 0);
      acc[1] = __builtin_amdgcn_mfma_f32_16x16x32_bf16(a, b1, acc[1], 0, 0, 0);
    }
    aC = aN; b0C = b0N; b1C = b1N;
  }
#pragma unroll
  for (int nt = 0; nt < 2; ++nt) {
    int col = n0 + wn + nt * 16 + lm;
    float bv = (flags & 1) ? bias[col] : 0.f;
#pragma unroll
    for (int t = 0; t < 4; ++t) {
      int row = m0 + wm + quad * 4 + t;
      float v = acc[nt][t] + bv;
      if (flags & 2) v = fmaxf(v, 0.f);
      if (flags & 4) Cb[(size_t)row * N + col] = f2bf(v);
      else C[(size_t)row * N + col] = v;
    }
  }
}

__global__ __launch_bounds__(256) void k_gemm_mfma(const ushort_t* __restrict__ A,
                                                   const ushort_t* __restrict__ Bt,
                                                   const float* __restrict__ bias,
                                                   float* __restrict__ C,
                                                   ushort_t* __restrict__ Cb,
                                                   int N, int K, int flags) {
  gemm32x64_body(A, Bt, bias, C, Cb, N, K, flags, blockIdx.y * 32, blockIdx.x * 64);
}

// -------- FT GEMM: 64x128 tile, 4 waves x (32x64), global_load_lds staging,
// conflict-free fragment ds_reads, double-buffered (2 x 24KB LDS).
// flags: 1=+bias, 2=relu. omode: 0=fp32 rm, 1=bf16 rm, 2=FT(cftKT),
// 3=q(qwft=v+rwb FT, qrb=v+rrb rm), 4=k(kft FT, col-512), 5=v(vtft V^T FT).
__device__ __forceinline__ void gemm_ft_body(
    ushort_t* smem, const ushort_t* __restrict__ A, const ushort_t* __restrict__ Bt,
    const float* __restrict__ bias, int N, int K, int kBeg, int kEnd,
    int m0, int n0, int flags, int omode,
    float* __restrict__ Cf, ushort_t* __restrict__ Cb, int cftKT,
    ushort_t* __restrict__ aux, const float* __restrict__ rwb,
    const float* __restrict__ rrb) {
  const int tid = threadIdx.x;
  const int lane = tid & 63, wv = tid >> 6;
  const int wm = (wv >> 1) * 32, wn = (wv & 1) * 64;
  const int lm = lane & 15, quad = lane >> 4;
  const int AKT = K >> 5;                 // global k-tiles per 16-row block
  const int mt0 = m0 >> 4, nt0 = n0 >> 4;
  const int kt0 = kBeg >> 5;

  f32x4 acc[2][4];
#pragma unroll
  for (int i = 0; i < 2; ++i)
#pragma unroll
    for (int j = 0; j < 4; ++j) acc[i][j] = (f32x4)(0.f);

  auto stage = [&](ushort_t* dA, int ktg) {
    ushort_t* dB = dA + 4096;
#pragma unroll
    for (int it = 0; it < 6; ++it) {
      const int c = (it << 8) + tid;
      if (it < 2) {  // A chunks: c in [0,512)
        const int blk = c >> 6, ln = c & 63;
        gload16(A + (((size_t)(mt0 + (blk >> 1)) * AKT + ktg + (blk & 1)) << 9) + (ln << 3),
                dA + (c << 3));
      } else {       // B chunks: cB in [0,1024)
        const int cB = c - 512;
        const int blk = cB >> 6, ln = cB & 63;
        gload16(Bt + (((size_t)(nt0 + (blk >> 1)) * AKT + ktg + (blk & 1)) << 9) + (ln << 3),
                dB + (cB << 3));
      }
    }
  };
  auto compute = [&](const ushort_t* dA) {
    const ushort_t* dB = dA + 4096;
#pragma unroll
    for (int kk = 0; kk < 2; ++kk) {
      bf16x8 a[2], b[4];
#pragma unroll
      for (int i = 0; i < 2; ++i)
        a[i] = *(const bf16x8*)&dA[((((wm >> 4) + i) << 1) + kk) * 512 + (lane << 3)];
#pragma unroll
      for (int j = 0; j < 4; ++j)
        b[j] = *(const bf16x8*)&dB[((((wn >> 4) + j) << 1) + kk) * 512 + (lane << 3)];
#pragma unroll
      for (int i = 0; i < 2; ++i)
#pragma unroll
        for (int j = 0; j < 4; ++j)
          acc[i][j] = __builtin_amdgcn_mfma_f32_16x16x32_bf16(a[i], b[j], acc[i][j], 0, 0, 0);
    }
  };

  const int nIter = (kEnd - kBeg) >> 6;  // always even (8) here
  stage(smem, kt0);
  __syncthreads();
  for (int t = 0; t < nIter; t += 2) {
    if (t + 1 < nIter) stage(smem + 12288, kt0 + (t + 1) * 2);
    compute(smem);
    __syncthreads();
    if (t + 2 < nIter) stage(smem, kt0 + (t + 2) * 2);
    compute(smem + 12288);
    __syncthreads();
  }

#pragma unroll
  for (int i = 0; i < 2; ++i) {
    const int rowb = m0 + wm + i * 16 + quad * 4;
#pragma unroll
    for (int j = 0; j < 4; ++j) {
      const int col = n0 + wn + j * 16 + lm;
      const float bv = (flags & 1) ? bias[col] : 0.f;
#pragma unroll
      for (int t2 = 0; t2 < 4; ++t2) {
        const int row = rowb + t2;
        float v = acc[i][j][t2] + bv;
        if (flags & 2) v = fmaxf(v, 0.f);
        if (omode == 0) {
          Cf[(size_t)row * N + col] = v;
        } else if (omode == 1) {
          Cb[(size_t)row * N + col] = f2bf(v);
        } else if (omode == 2) {
          Cb[(((size_t)(row >> 4) * cftKT + (col >> 5)) << 9) +
             (((col >> 3) & 3) << 7) + ((row & 15) << 3) + (col & 7)] = f2bf(v);
        } else if (omode == 3) {
          Cb[ft512(row, col)] = f2bf(v + rwb[col]);
          aux[(size_t)row * DM + col] = f2bf(v + rrb[col]);
        } else if (omode == 4) {
          Cb[ft512(row, col - 512)] = f2bf(v);
        } else {  // omode 5: V^T FT, r = v-dim, c = token
          const int dv = col - 1024;
          Cb[((size_t)(dv >> 4) * 65 + (row >> 5)) * 512 +
             (((row >> 3) & 3) << 7) + ((dv & 15) << 3) + (row & 7)] = f2bf(v);
        }
      }
    }
  }
}

// merged QKV + Wr GEMMs (FT); q-part -> qwft(+rwb) & qrb(+rrb); k -> kft;
// v -> vtft (V^T FT); Wr -> rbg (rm)
__global__ __launch_bounds__(256) void k_gemm_qkvwr_ft(
    const ushort_t* __restrict__ wbft, const ushort_t* __restrict__ posft,
    const ushort_t* __restrict__ qkvT, const ushort_t* __restrict__ wrT,
    ushort_t* __restrict__ qwft, ushort_t* __restrict__ kft,
    ushort_t* __restrict__ vtft, ushort_t* __restrict__ rbg,
    ushort_t* __restrict__ qrb, const float* __restrict__ rwb,
    const float* __restrict__ rrb) {
  __shared__ ushort_t smem[24576];
  int m0 = blockIdx.y * 64;
  if (m0 + 64 > TT) m0 = TT - 64;  // overlapped last tile (dup writes benign)
  const int bx = blockIdx.x;
  if (bx < 12) {
    const int om = (bx < 4) ? 3 : (bx < 8 ? 4 : 5);
    ushort_t* dst = (om == 3) ? qwft : (om == 4) ? kft : vtft;
    gemm_ft_body(smem, wbft, qkvT, nullptr, QKV_N, DM, 0, DM, m0, bx * 128,
                 0, om, nullptr, dst, 0, qrb, rwb, rrb);
  } else {
    gemm_ft_body(smem, posft, wrT, nullptr, DM, DM, 0, DM, m0, (bx - 12) * 128,
                 0, 1, nullptr, rbg, 0, nullptr, nullptr, nullptr);
  }
}

// FFN1: wbft x w1T -> ff1ft (FT, K_out = DI), bias+relu
__global__ __launch_bounds__(256) void k_ffn1_ft(const ushort_t* __restrict__ wbft,
                                                 const ushort_t* __restrict__ w1T,
                                                 const float* __restrict__ b1l,
                                                 ushort_t* __restrict__ ff1ft) {
  __shared__ ushort_t smem[24576];
  int m0 = blockIdx.y * 64;
  if (m0 + 64 > TT) m0 = TT - 64;
  gemm_ft_body(smem, wbft, w1T, b1l, DI, DM, 0, DM, m0, blockIdx.x * 128,
               1 | 2, 2, nullptr, ff1ft, DI >> 5, nullptr, nullptr, nullptr);
}

// FFN2: ff1ft x w2T -> fp32 partials (split-K=4); bias folded into split 0
__global__ __launch_bounds__(256) void k_ffn2_ft(const ushort_t* __restrict__ ff1ft,
                                                 const ushort_t* __restrict__ w2T,
                                                 const float* __restrict__ b2l,
                                                 float* __restrict__ ff2p) {
  __shared__ ushort_t smem[24576];
  int m0 = blockIdx.y * 64;
  if (m0 + 64 > TT) m0 = TT - 64;
  const int s = blockIdx.z;
  gemm_ft_body(smem, ff1ft, w2T, b2l, DM, DI, s * 512, s * 512 + 512, m0,
               blockIdx.x * 128, (s == 0) ? 1 : 0, 0,
               ff2p + (size_t)s * TT * DM, nullptr, 0, nullptr, nullptr, nullptr);
}

// ---- QR GEMM: QR[h][i][k] = qr_i . r_k ------------------------------------
// Output: BD in per-(qt,jt)-tile C-fragment order (streamable by k_attn) +
// wrap values wrapv[h][row][w<16] (overlaid on dead attnb space).
__global__ __launch_bounds__(256) void k_qr(const ushort_t* __restrict__ qrb,
                                            const ushort_t* __restrict__ rbg,
                                            ushort_t* __restrict__ bdf,
                                            ushort_t* __restrict__ wrapv) {
  const int h = blockIdx.z;
  const int m0 = blockIdx.y * 32, n0 = blockIdx.x * 64;
  if (!(n0 == 0 || n0 + 63 >= TT - 32 - m0)) return;
  __shared__ short As[32][72];
  __shared__ short Bs[64][72];
  const int tid = threadIdx.x;
  const int lane = tid & 63, wv = tid >> 6;
  const int wm = (wv >> 1) * 16, wn = (wv & 1) * 32;
  const int lm = lane & 15, quad = lane >> 4;
  const int sr = tid >> 3, sc8 = (tid & 7) * 8;
  const uint4 zero4 = make_uint4(0, 0, 0, 0);

  *(uint4*)&As[sr][sc8] = *(const uint4*)&qrb[(size_t)(m0 + sr) * DM + h * DH + sc8];
  int br0 = n0 + sr, br1 = n0 + sr + 32;
  *(uint4*)&Bs[sr][sc8] =
      (br0 < TT) ? *(const uint4*)&rbg[(size_t)br0 * DM + h * DH + sc8] : zero4;
  *(uint4*)&Bs[sr + 32][sc8] =
      (br1 < TT) ? *(const uint4*)&rbg[(size_t)br1 * DM + h * DH + sc8] : zero4;
  __syncthreads();

  f32x4 acc[2];
  acc[0] = (f32x4)(0.f); acc[1] = (f32x4)(0.f);
#pragma unroll
  for (int kk = 0; kk < 64; kk += 32) {
    bf16x8 a = *(const bf16x8*)&As[wm + lm][kk + quad * 8];
    bf16x8 b0 = *(const bf16x8*)&Bs[wn + lm][kk + quad * 8];
    bf16x8 b1 = *(const bf16x8*)&Bs[wn + 16 + lm][kk + quad * 8];
    acc[0] = __builtin_amdgcn_mfma_f32_16x16x32_bf16(a, b0, acc[0], 0, 0, 0);
    acc[1] = __builtin_amdgcn_mfma_f32_16x16x32_bf16(a, b1, acc[1], 0, 0, 0);
  }
  const size_t hb = (size_t)h * BDF_HEAD;
  const size_t hw = (size_t)h * WRAP_HEAD;
#pragma unroll
  for (int nt = 0; nt < 2; ++nt) {
    int col = n0 + wn + nt * 16 + lm;
    if (col >= TT) continue;
#pragma unroll
    for (int t = 0; t < 4; ++t) {
      int row = m0 + wm + quad * 4 + t;
      float v = acc[nt][t];
      ushort_t vb = f2bf(v);
      int p = row + col - (TT - 1);  // = causal column j
      if (p >= 0) {
        int qti = row >> 5, jti = p >> 5;
        int ri = row & 31, cj = p & 31;
        size_t tb = hb + (((size_t)(qti * (qti + 1) / 2 + jti)) << 10);
        size_t off = (size_t)((((ri >> 4) * 2 + (cj >> 4)) << 8) +
                              ((((ri & 15) >> 2) * 16 + (cj & 15)) << 2) + (ri & 3));
        bdf[tb + off] = vb;
      }
      if (col < 16) wrapv[hw + row * 16 + col] = vb;  // wrap value QR[row][col]
    }
  }
}

// ------- wave-autonomous MFMA flash attention (8 chunks, prefetched) -------
// Grid (65, NH, 2); each block's 4 waves own chunk cid = z*4 + wv of 8,
// processing j-tiles jt = cid, cid+8, ... <= qt with ZERO block barriers.
// K/BD fragments for tile t+1 are issued BEFORE tile t's softmax/fence (they
// stay in flight across the sched_barrier); V for tile t loads at the top of
// its own iteration (hidden under QK^T+softmax).
__global__ __launch_bounds__(256) void k_attn(const ushort_t* __restrict__ qwft,
                                              const ushort_t* __restrict__ kft,
                                              const ushort_t* __restrict__ vtft,
                                              const ushort_t* __restrict__ bdf,
                                              const ushort_t* __restrict__ wrapv,
                                              float* __restrict__ mlP,
                                              ushort_t* __restrict__ opP) {
  const int h = blockIdx.y;
  const int qt = 64 - blockIdx.x;  // heavy q-tiles dispatch first
  const int tid = threadIdx.x;
  const int wv = tid >> 6;
  const int cid = blockIdx.z * 4 + wv;  // chunk id 0..7
  if (cid > qt) return;                 // wave-level early out (no barriers)
  const int lane = tid & 63;
  const int lm = lane & 15, quad = lane >> 4;
  const int i0 = qt * 32;

  __shared__ ushort_t pbl[4][1024];  // per-wave P B-fragments (2 x 1KB blocks)

  // Q fragments (loop-invariant), direct global->VGPR
  bf16x8 qf[2][2];
#pragma unroll
  for (int qi = 0; qi < 2; ++qi)
#pragma unroll
    for (int kt = 0; kt < 2; ++kt)
      qf[qi][kt] = *(const bf16x8*)&qwft[(((size_t)((i0 >> 4) + qi) * 16) +
                                         h * 2 + kt) * 512 + (lane << 3)];

  const size_t hbd = (size_t)h * BDF_HEAD + (((size_t)(qt * (qt + 1) / 2)) << 10);
  const size_t hwr = (size_t)h * WRAP_HEAD;

  auto loadKB = [&](int jt, bf16x8 (&kf)[2][2], uint2 (&bd)[2][2]) {
    const int j0 = jt * 32;
#pragma unroll
    for (int jq = 0; jq < 2; ++jq)
#pragma unroll
      for (int kt = 0; kt < 2; ++kt)
        kf[jq][kt] = *(const bf16x8*)&kft[(((size_t)((j0 >> 4) + jq) * 16) +
                                          h * 2 + kt) * 512 + (lane << 3)];
#pragma unroll
    for (int qi = 0; qi < 2; ++qi)
#pragma unroll
      for (int jq = 0; jq < 2; ++jq)
        bd[qi][jq] = *(const uint2*)&bdf[hbd + ((size_t)jt << 10) +
                                         ((qi * 2 + jq) << 8) + (lane << 2)];
  };

  float mreg[2][4], lreg[2][4];
#pragma unroll
  for (int qi = 0; qi < 2; ++qi)
#pragma unroll
    for (int t = 0; t < 4; ++t) { mreg[qi][t] = -INFINITY; lreg[qi][t] = 0.f; }
  f32x4 o[4][2];  // [dt][iq]: O^T rows d=dt*16+quad*4+tt, cols i=iq*16+lm
#pragma unroll
  for (int dt = 0; dt < 4; ++dt)
#pragma unroll
    for (int iq = 0; iq < 2; ++iq) o[dt][iq] = (f32x4)(0.f);

  // prologue: first tile's K + BD fragments
  bf16x8 kf[2][2];
  uint2 bd[2][2];
  loadKB(cid, kf, bd);

  for (int jt = cid; jt <= qt; jt += NCHT) {
    const int j0 = jt * 32;
    // ---- current V fragments (used only at PV; latency hides under QK+SM) --
    bf16x8 vf[4];
#pragma unroll
    for (int dt = 0; dt < 4; ++dt)
      vf[dt] = *(const bf16x8*)&vtft[(((size_t)(h * 4 + dt)) * 65 + jt) * 512 +
                                     (lane << 3)];

    // ---- QK^T: scores in accumulators ----
    f32x4 sA[2][2];
#pragma unroll
    for (int qi = 0; qi < 2; ++qi)
#pragma unroll
      for (int jq = 0; jq < 2; ++jq) {
        f32x4 ac = (f32x4)(0.f);
#pragma unroll
        for (int kt = 0; kt < 2; ++kt)
          ac = __builtin_amdgcn_mfma_f32_16x16x32_bf16(qf[qi][kt], kf[jq][kt], ac, 0, 0, 0);
        sA[qi][jq] = ac;
      }

    // ---- prefetch next tile's K + BD (in flight across the fence) ----
    const int jn = (jt + NCHT <= qt) ? jt + NCHT : jt;  // clamped reload
    bf16x8 kn[2][2];
    uint2 bdn[2][2];
    loadKB(jn, kn, bdn);

    // ---- score assembly (in-register) ----
    if (jt < qt) {  // all-causal tile
#pragma unroll
      for (int qi = 0; qi < 2; ++qi)
#pragma unroll
        for (int jq = 0; jq < 2; ++jq) {
          float b0 = bf2f((ushort_t)(bd[qi][jq].x & 0xffffu));
          float b1 = bf2f((ushort_t)(bd[qi][jq].x >> 16));
          float b2 = bf2f((ushort_t)(bd[qi][jq].y & 0xffffu));
          float b3 = bf2f((ushort_t)(bd[qi][jq].y >> 16));
          sA[qi][jq][0] = (sA[qi][jq][0] + b0) * ATT_SCALE;
          sA[qi][jq][1] = (sA[qi][jq][1] + b1) * ATT_SCALE;
          sA[qi][jq][2] = (sA[qi][jq][2] + b2) * ATT_SCALE;
          sA[qi][jq][3] = (sA[qi][jq][3] + b3) * ATT_SCALE;
        }
    } else {  // diagonal tile: mask + mem-corner + wrap
#pragma unroll
      for (int qi = 0; qi < 2; ++qi)
#pragma unroll
        for (int jq = 0; jq < 2; ++jq) {
          float bdv[4];
          bdv[0] = bf2f((ushort_t)(bd[qi][jq].x & 0xffffu));
          bdv[1] = bf2f((ushort_t)(bd[qi][jq].x >> 16));
          bdv[2] = bf2f((ushort_t)(bd[qi][jq].y & 0xffffu));
          bdv[3] = bf2f((ushort_t)(bd[qi][jq].y >> 16));
          const int j = j0 + jq * 16 + lm;
#pragma unroll
          for (int t = 0; t < 4; ++t) {
            const int i = i0 + qi * 16 + quad * 4 + t;
            const float acv = sA[qi][jq][t];
            float s;
            if (j <= i) {
              s = (acv + bdv[t]) * ATT_SCALE;
            } else {
              bool inmem = (i < NMTOK && j < NMTOK) ||
                           (i >= TT - NMTOK && j >= TT - NMTOK);
              if (!inmem) s = -1e30f;
              else if (j == i + 1) s = acv * ATT_SCALE;  // rel_shift zero-pad
              else s = (acv + bf2f(wrapv[hwr + (i + 1) * 16 + (j - i - 2)])) * ATT_SCALE;
            }
            sA[qi][jq][t] = s;
          }
        }
    }

    // ---- online softmax (row = qi*16+quad*4+t; reduce over jq + 16 lanes) --
    float mx[2][4];
#pragma unroll
    for (int qi = 0; qi < 2; ++qi)
#pragma unroll
      for (int t = 0; t < 4; ++t)
        mx[qi][t] = fmaxf(sA[qi][0][t], sA[qi][1][t]);
#pragma unroll
    for (int off = 1; off < 16; off <<= 1)
#pragma unroll
      for (int qi = 0; qi < 2; ++qi)
#pragma unroll
        for (int t = 0; t < 4; ++t)
          mx[qi][t] = fmaxf(mx[qi][t], __shfl_xor(mx[qi][t], off));
    float al[2][4];
#pragma unroll
    for (int qi = 0; qi < 2; ++qi)
#pragma unroll
      for (int t = 0; t < 4; ++t) {
        float mnew = fmaxf(mreg[qi][t], mx[qi][t]);
        al[qi][t] = __expf(mreg[qi][t] - mnew);
        mreg[qi][t] = mnew;
      }
    // p = exp(s - m), row sums
    float ps[2][4];
#pragma unroll
    for (int qi = 0; qi < 2; ++qi)
#pragma unroll
      for (int t = 0; t < 4; ++t) {
        sA[qi][0][t] = __expf(sA[qi][0][t] - mreg[qi][t]);
        sA[qi][1][t] = __expf(sA[qi][1][t] - mreg[qi][t]);
        ps[qi][t] = sA[qi][0][t] + sA[qi][1][t];
      }
#pragma unroll
    for (int off = 1; off < 16; off <<= 1)
#pragma unroll
      for (int qi = 0; qi < 2; ++qi)
#pragma unroll
        for (int t = 0; t < 4; ++t)
          ps[qi][t] += __shfl_xor(ps[qi][t], off);
#pragma unroll
    for (int qi = 0; qi < 2; ++qi)
#pragma unroll
      for (int t = 0; t < 4; ++t)
        lreg[qi][t] = lreg[qi][t] * al[qi][t] + ps[qi][t];

    // ---- alpha broadcast to column layout via shfl ----
    float aw[2];
    {
      const int src = (lm >> 2) << 4;  // lane holding rows (lm>>2)*4+t
      const int t3 = lm & 3;
#pragma unroll
      for (int iq = 0; iq < 2; ++iq) {
        float g0 = __shfl(al[iq][0], src);
        float g1 = __shfl(al[iq][1], src);
        float g2 = __shfl(al[iq][2], src);
        float g3 = __shfl(al[iq][3], src);
        aw[iq] = (t3 == 0) ? g0 : (t3 == 1) ? g1 : (t3 == 2) ? g2 : g3;
      }
    }
#pragma unroll
    for (int dt = 0; dt < 4; ++dt)
#pragma unroll
      for (int iq = 0; iq < 2; ++iq)
#pragma unroll
        for (int tt = 0; tt < 4; ++tt) o[dt][iq][tt] *= aw[iq];

    // ---- P -> wave-private LDS in B-fragment order ----
#pragma unroll
    for (int qi = 0; qi < 2; ++qi)
#pragma unroll
      for (int jq = 0; jq < 2; ++jq)
#pragma unroll
        for (int t = 0; t < 4; ++t)
          pbl[wv][(qi << 9) +
                  (((jq * 2 + (lm >> 3)) * 16 + (quad * 4 + t)) << 3) +
                  (lm & 7)] = f2bf(sA[qi][jq][t]);
    asm volatile("s_waitcnt lgkmcnt(0)" ::: "memory");
    __builtin_amdgcn_sched_barrier(0);
    bf16x8 pf[2];
#pragma unroll
    for (int iq = 0; iq < 2; ++iq)
      pf[iq] = *(const bf16x8*)&pbl[wv][(iq << 9) + (lane << 3)];

    // ---- PV: O^T += V^T * P^T ----
#pragma unroll
    for (int dt = 0; dt < 4; ++dt)
#pragma unroll
      for (int iq = 0; iq < 2; ++iq)
        o[dt][iq] = __builtin_amdgcn_mfma_f32_16x16x32_bf16(vf[dt], pf[iq], o[dt][iq], 0, 0, 0);

    // rotate prefetched K/BD into place
#pragma unroll
    for (int jq = 0; jq < 2; ++jq)
#pragma unroll
      for (int kt = 0; kt < 2; ++kt) kf[jq][kt] = kn[jq][kt];
#pragma unroll
    for (int qi = 0; qi < 2; ++qi)
#pragma unroll
      for (int jq = 0; jq < 2; ++jq) bd[qi][jq] = bdn[qi][jq];
  }

  // ---- write partials ----
  const int pidx = (qt * NH + h) * NCHT + cid;
  if (lm == 0) {
#pragma unroll
    for (int qi = 0; qi < 2; ++qi)
#pragma unroll
      for (int t = 0; t < 4; ++t) {
        mlP[(size_t)pidx * 64 + qi * 16 + quad * 4 + t] = mreg[qi][t];
        mlP[(size_t)pidx * 64 + 32 + qi * 16 + quad * 4 + t] = lreg[qi][t];
      }
  }
  const size_t ob = (size_t)pidx * 2048;
#pragma unroll
  for (int iq = 0; iq < 2; ++iq)
#pragma unroll
    for (int dt = 0; dt < 4; ++dt) {
      ushort_t o4[4];
#pragma unroll
      for (int tt = 0; tt < 4; ++tt) o4[tt] = f2bf(o[dt][iq][tt]);
      *(uint2*)&opP[ob + (size_t)(iq * 16 + lm) * 64 + dt * 16 + quad * 4] =
          *(uint2*)o4;
    }
}

// -------- combine <=NCHT chunk partials -> normalized attn output ---------
__global__ __launch_bounds__(256) void k_attn_combine(const float* __restrict__ mlP,
                                                      const ushort_t* __restrict__ opP,
                                                      ushort_t* __restrict__ attnb) {
  const int qt = blockIdx.x, h = blockIdx.y;
  const int nc = (qt + 1 < NCHT) ? qt + 1 : NCHT;
  const int tid = threadIdx.x;
  const int i = tid >> 3, d8 = (tid & 7) * 8;
  const size_t base = (size_t)(qt * NH + h) * NCHT;
  float m[NCHT], l[NCHT], wgt[NCHT];
  float M = -INFINITY;
  for (int cc = 0; cc < nc; ++cc) {
    m[cc] = mlP[(base + cc) * 64 + i];
    l[cc] = mlP[(base + cc) * 64 + 32 + i];
    M = fmaxf(M, m[cc]);
  }
  float L = 0.f;
  for (int cc = 0; cc < nc; ++cc) { wgt[cc] = __expf(m[cc] - M); L += l[cc] * wgt[cc]; }
  float acc[8] = {0, 0, 0, 0, 0, 0, 0, 0};
  for (int cc = 0; cc < nc; ++cc) {
    uint4 v = *(const uint4*)&opP[(base + cc) * 2048 + (size_t)i * 64 + d8];
    float f[8]; unpack8(v, f);
#pragma unroll
    for (int k = 0; k < 8; ++k) acc[k] += wgt[cc] * f[k];
  }
  const float inv = 1.f / L;
  ushort_t o8[8];
#pragma unroll
  for (int k = 0; k < 8; ++k) o8[k] = f2bf(acc[k] * inv);
  *(uint4*)&attnb[(size_t)(qt * 32 + i) * DM + h * DH + d8] = *(uint4*)o8;
}

// -------- w' = LayerNorm(w + sum(delta parts)) * g + b ---------------------
__global__ __launch_bounds__(256) void k_addln(const float* __restrict__ w,
                                               float* __restrict__ wout,
                                               ushort_t* __restrict__ wbft,
                                               const float* __restrict__ delta,
                                               int nparts,
                                               const float* __restrict__ gamma,
                                               const float* __restrict__ beta) {
  const int row = blockIdx.x;
  const int tid = threadIdx.x;
  __shared__ float red[4], red2[4];
  __shared__ float sm[512];
  size_t base = (size_t)row * DM;
  float x0 = w[base + tid];
  float x1 = w[base + tid + 256];
  for (int p = 0; p < nparts; ++p) {
    x0 += delta[(size_t)p * TT * DM + base + tid];
    x1 += delta[(size_t)p * TT * DM + base + tid + 256];
  }
  float s = x0 + x1;
#pragma unroll
  for (int off = 1; off < 64; off <<= 1) s += __shfl_xor(s, off);
  if ((tid & 63) == 0) red[tid >> 6] = s;
  __syncthreads();
  float mu = (red[0] + red[1] + red[2] + red[3]) * (1.f / 512.f);
  float d0 = x0 - mu, d1 = x1 - mu;
  float v = d0 * d0 + d1 * d1;
#pragma unroll
  for (int off = 1; off < 64; off <<= 1) v += __shfl_xor(v, off);
  if ((tid & 63) == 0) red2[tid >> 6] = v;
  __syncthreads();
  float var = (red2[0] + red2[1] + red2[2] + red2[3]) * (1.f / 512.f);
  float rstd = rsqrtf(var + 1e-5f);
  float o0 = d0 * rstd * gamma[tid] + beta[tid];
  float o1 = d1 * rstd * gamma[tid + 256] + beta[tid + 256];
  wout[base + tid] = o0;
  wout[base + tid + 256] = o1;
  sm[tid] = o0; sm[tid + 256] = o1;
  __syncthreads();
  if (tid < 64) {
    const int d8 = tid << 3;
    ushort_t t8[8];
#pragma unroll
    for (int e = 0; e < 8; ++e) t8[e] = f2bf(sm[d8 + e]);
    *(uint4*)&wbft[ft512(row, d8)] = *(uint4*)t8;
  }
}

extern "C" void kernel_launch(void* const* d_in, const int* in_sizes, int n_in,
                              void* d_out, int out_size, void* d_ws, size_t ws_size,
                              hipStream_t stream) {
  const float* we   = (const float*)d_in[0];
  const float* mem  = (const float*)d_in[1];
  const float* Wqkv = (const float*)d_in[2];
  const float* Wr   = (const float*)d_in[3];
  const float* Wo   = (const float*)d_in[4];
  const float* ln1s = (const float*)d_in[5];
  const float* ln1b = (const float*)d_in[6];
  const float* W1   = (const float*)d_in[7];
  const float* b1   = (const float*)d_in[8];
  const float* W2   = (const float*)d_in[9];
  const float* b2   = (const float*)d_in[10];
  const float* ln2s = (const float*)d_in[11];
  const float* ln2b = (const float*)d_in[12];
  const float* rwb  = (const float*)d_in[13];
  const float* rrb  = (const float*)d_in[14];

  // ---- workspace layout (same footprint as before) ----
  float* w     = (float*)d_ws;                        // TT*DM fp32
  float* proj  = w + (size_t)TT * DM;                 // TT*DM fp32 (Wo out)
  ushort_t* wbft  = (ushort_t*)(proj + (size_t)TT * DM);  // TT*DM bf16 (FT)
  ushort_t* posft = wbft + (size_t)TT * DM;           // TT*DM bf16 (FT)
  ushort_t* attnb = posft + (size_t)TT * DM;          // TT*DM bf16 (rm)
  ushort_t* qkvB  = attnb + (size_t)TT * DM;          // TT*1536 bf16 region
  ushort_t* qwft  = qkvB;                             // TT*DM (Q+rwb, FT)
  ushort_t* kft   = qkvB + (size_t)TT * DM;           // TT*DM (K, FT)
  ushort_t* vtft  = qkvB + (size_t)2 * TT * DM;       // DM*TT (V^T, FT)
  ushort_t* rbg   = qkvB + (size_t)TT * QKV_N;        // TT*DM bf16 (rm)
  ushort_t* WtAll = rbg + (size_t)TT * DM;            // 4 layers x WT_STRIDE shorts
  ushort_t* opP   = WtAll + (size_t)NLAYER * WT_STRIDE;  // partial O region
  float* mlP   = (float*)(opP + (size_t)65 * 8 * 8 * 2048);  // partial m/l region
  ushort_t* qrb  = (ushort_t*)(mlP + (size_t)65 * 8 * 8 * 64);  // TT*DM bf16
  ushort_t* bdf  = qrb + (size_t)TT * DM;             // NH * BDF_HEAD shorts
  ushort_t* wrapv = attnb;           // overlay: wrap values live in dead attnb
  // overlays (time-shared, stream-ordered):
  ushort_t* ff1ft = qkvB;            // FT TT*DI bf16 spans qkv region + rbg
  float* ff2p  = (float*)opP;        // 4 split-K partials, 4*TT*DM f32
  const size_t OFF_QKVT = 0, OFF_WRT = 786432, OFF_WOT = 1048576,
               OFF_W1T = 1310720, OFF_W2T = 2359296;

  // all-layer weight transpose(+FT pack) + build in one dispatch
  k_prep<<<13312 + 4160, 256, 0, stream>>>(Wqkv, Wr, Wo, W1, W2, WtAll,
                                           we, mem, w, wbft, posft);

  dim3 gQW(16, 33);          // merged QKV (12 n-tiles) + Wr (4 n-tiles), 64x128
  dim3 gW1(16, 33);          // FFN1 64x128
  dim3 gW2(4, 33, 4);        // FFN2 64x128, split-K=4
  dim3 gDM32(DM / 64, 65);   // Wo (old 32x64 kernel)
  dim3 gQR(33, 65, NH);
  dim3 gA(65, NH, 2);        // wave-autonomous attention: 8 chunks = 2z x 4 waves
  dim3 gC(65, NH);

  for (int l = 0; l < NLAYER; ++l) {
    const ushort_t* Wt = WtAll + (size_t)l * WT_STRIDE;
    k_gemm_qkvwr_ft<<<gQW, 256, 0, stream>>>(wbft, posft, Wt + OFF_QKVT,
                                             Wt + OFF_WRT, qwft, kft, vtft,
                                             rbg, qrb, rwb, rrb);
    k_qr<<<gQR, 256, 0, stream>>>(qrb, rbg, bdf, wrapv);
    k_attn<<<gA, 256, 0, stream>>>(qwft, kft, vtft, bdf, wrapv, mlP, opP);
    k_attn_combine<<<gC, 256, 0, stream>>>(mlP, opP, attnb);
    k_gemm_mfma<<<gDM32, 256, 0, stream>>>(attnb, Wt + OFF_WOT, nullptr, proj, nullptr,
                                           DM, DM, 0);
    k_addln<<<TT, 256, 0, stream>>>(w, w, wbft, proj, 1,
                                    ln1s + (size_t)l * DM, ln1b + (size_t)l * DM);
    k_ffn1_ft<<<gW1, 256, 0, stream>>>(wbft, Wt + OFF_W1T, b1 + (size_t)l * DI, ff1ft);
    k_ffn2_ft<<<gW2, 256, 0, stream>>>(ff1ft, Wt + OFF_W2T, b2 + (size_t)l * DM, ff2p);
    float* wout = (l == NLAYER - 1) ? (float*)d_out : w;
    k_addln<<<TT, 256, 0, stream>>>(w, wout, wbft, ff2p, 4,
                                    ln2s + (size_t)l * DM, ln2b + (size_t)l * DM);
  }
}

// Round 10
// 607.024 us; speedup vs baseline: 1.1139x; 1.0962x over previous
//
#include <hip/hip_runtime.h>
#include <hip/hip_bf16.h>
#include <math.h>
#include <stdint.h>

#define TT 2080
#define DM 512
#define DI 2048
#define NH 8
#define DH 64
#define NMTOK 16
#define NLAYER 4
#define QKV_N 1536
#define ATT_SCALE 0.125f
#define SPLIT 8
#define WT_STRIDE 3407872   // shorts per layer's transposed-weight block
#define RSFT_ROWS 2112      // shifted-r FT rows (132 blocks of 16)

typedef short bf16x8 __attribute__((ext_vector_type(8)));
typedef float f32x4 __attribute__((ext_vector_type(4)));
typedef unsigned short ushort_t;

__device__ __forceinline__ ushort_t f2bf(float f) {
  __hip_bfloat16 h = __float2bfloat16(f);
  return *reinterpret_cast<ushort_t*>(&h);
}
__device__ __forceinline__ float bfbits2f(unsigned int hi_bits) {
  return __uint_as_float(hi_bits);
}
__device__ __forceinline__ float bf2f(ushort_t u) {
  return bfbits2f(((unsigned int)u) << 16);
}
__device__ __forceinline__ void unpack8(uint4 v, float* f) {
  f[0] = bfbits2f(v.x << 16); f[1] = bfbits2f(v.x & 0xffff0000u);
  f[2] = bfbits2f(v.y << 16); f[3] = bfbits2f(v.y & 0xffff0000u);
  f[4] = bfbits2f(v.z << 16); f[5] = bfbits2f(v.z & 0xffff0000u);
  f[6] = bfbits2f(v.w << 16); f[7] = bfbits2f(v.w & 0xffff0000u);
}
__device__ __forceinline__ unsigned int pack2(ushort_t lo, ushort_t hi) {
  return (unsigned int)lo | ((unsigned int)hi << 16);
}
// Barrier draining LDS ops only — leaves global (vmcnt) loads in flight.
__device__ __forceinline__ void barrier_lds() {
  asm volatile("s_waitcnt lgkmcnt(0)" ::: "memory");
  __builtin_amdgcn_s_barrier();
}
// Barrier draining everything (used to retire global_load_lds prefetches).
__device__ __forceinline__ void barrier_all() {
  asm volatile("s_waitcnt vmcnt(0) lgkmcnt(0)" ::: "memory");
  __builtin_amdgcn_s_barrier();
}
// global -> LDS direct copy, 16B per lane. LDS dest must be wave-uniform
// base + lane*16 (contract of global_load_lds).
__device__ __forceinline__ void gload16(const ushort_t* g, ushort_t* l) {
  __builtin_amdgcn_global_load_lds(
      (__attribute__((address_space(1))) void*)(uintptr_t)g,
      (__attribute__((address_space(3))) void*)(uintptr_t)l, 16, 0, 0);
}
// ---- fragment-tiled (FT) layout --------------------------------------------
// Matrix X[R][K] (bf16) stored as 1024B blocks of (16 r x 32 k); lane
// = ((k>>3)&3)*16 + (r&15) holds 8 consecutive k-elements = EXACTLY the
// mfma_f32_16x16x32_bf16 A/B fragment order.
__device__ __forceinline__ size_t ft512(int r, int c) {  // K = 512 (KT = 16)
  return (((size_t)(r >> 4) * 16 + (c >> 5)) << 9) + (((c >> 3) & 3) << 7) +
         ((r & 15) << 3) + (c & 7);
}

// ---- fused prep: all 4 layers' weight transposes + build w/pos ------------
__global__ __launch_bounds__(256) void k_prep(
    const float* __restrict__ Wqkv, const float* __restrict__ Wr,
    const float* __restrict__ Wo, const float* __restrict__ W1,
    const float* __restrict__ W2, ushort_t* __restrict__ dstAll,
    const float* __restrict__ we, const float* __restrict__ mem,
    float* __restrict__ w, ushort_t* __restrict__ wbft,
    ushort_t* __restrict__ posft) {
  const int tid = threadIdx.x;
  if (blockIdx.x >= 13312) {  // ---- build ----
    int idx = (blockIdx.x - 13312) * 256 + tid;
    if (idx >= TT * DM) return;
    int t = idx >> 9, d = idx & 511;
    float v;
    if (t < NMTOK) v = mem[t * DM + d];
    else if (t < NMTOK + 2048) v = we[(t - NMTOK) * DM + d];
    else v = mem[(t - (NMTOK + 2048)) * DM + d];
    w[idx] = v;
    wbft[ft512(t, d)] = f2bf(v);
    float p = (float)(TT - 1 - t);
    int i2 = d & 255;
    float freq = __expf(-0.035977892f * (float)i2);
    float ang = p * freq;
    posft[ft512(t, d)] = f2bf((d < 256) ? __sinf(ang) : __cosf(ang));
    return;
  }
  // ---- transpose+cast, layer l ----
  __shared__ float tl[32][33];
  const int l = blockIdx.x / 3328;
  int idx = blockIdx.x % 3328;
  const float* src;
  ushort_t* dst = dstAll + (size_t)l * WT_STRIDE;
  int K, N, local;
  bool isFT = true;
  if (idx < 768)       { src = Wqkv + (size_t)l * 512 * 1536; K = 512;  N = 1536; local = idx; }
  else if (idx < 1024) { src = Wr   + (size_t)l * 512 * 512;  dst += 786432;  K = 512;  N = 512;  local = idx - 768; }
  else if (idx < 1280) { src = Wo   + (size_t)l * 512 * 512;  dst += 1048576; K = 512;  N = 512;  local = idx - 1024; isFT = false; }
  else if (idx < 2304) { src = W1   + (size_t)l * 512 * 2048; dst += 1310720; K = 512;  N = 2048; local = idx - 1280; }
  else                 { src = W2   + (size_t)l * 2048 * 512; dst += 2359296; K = 2048; N = 512;  local = idx - 2304; }
  const int ntiles = N / 32;
  const int n0 = (local % ntiles) * 32, k0 = (local / ntiles) * 32;
#pragma unroll
  for (int p = 0; p < 4; ++p) {
    int row = (tid >> 5) + 8 * p, col = tid & 31;
    tl[row][col] = src[(size_t)(k0 + row) * N + n0 + col];  // tl[k][n]
  }
  __syncthreads();
  if (isFT) {
    if (tid < 128) {
      int b = tid >> 6, l2 = tid & 63;
      int nn = b * 16 + (l2 & 15);
      int kq = (l2 >> 4) * 8;
      ushort_t t8[8];
#pragma unroll
      for (int e = 0; e < 8; ++e) t8[e] = f2bf(tl[kq + e][nn]);
      size_t ad = (((size_t)((n0 >> 4) + b) * (K >> 5) + (k0 >> 5)) << 9) +
                  ((size_t)l2 << 3);
      *(uint4*)&dst[ad] = *(uint4*)t8;
    }
  } else {
#pragma unroll
    for (int p = 0; p < 4; ++p) {
      int n = (tid >> 5) + 8 * p, k = tid & 31;
      dst[(size_t)(n0 + n) * K + k0 + k] = f2bf(tl[k][n]);
    }
  }
}

// -------- bf16 MFMA GEMM body, 32x64 tile, register prefetch (Wo only) ----
__device__ __forceinline__ void gemm32x64_body(const ushort_t* __restrict__ A,
                                               const ushort_t* __restrict__ Bt,
                                               const float* __restrict__ bias,
                                               float* __restrict__ C,
                                               ushort_t* __restrict__ Cb,
                                               int N, int K, int flags,
                                               int m0, int n0) {
  __shared__ short As[32][72];
  __shared__ short Bs[64][72];
  const int tid = threadIdx.x;
  const int lane = tid & 63, wv = tid >> 6;
  const int wm = (wv >> 1) * 16, wn = (wv & 1) * 32;
  const int lm = lane & 15, quad = lane >> 4;
  const int sr = tid >> 3, sc8 = (tid & 7) * 8;

  f32x4 acc[2];
  acc[0] = (f32x4)(0.f); acc[1] = (f32x4)(0.f);

  auto loadA = [&](int k0) -> uint4 {
    return *(const uint4*)&A[(size_t)(m0 + sr) * K + k0 + sc8];
  };
  auto loadB = [&](int row, int k0) -> uint4 {
    return *(const uint4*)&Bt[(size_t)(n0 + row) * K + k0 + sc8];
  };

  uint4 aC = loadA(0), b0C = loadB(sr, 0), b1C = loadB(sr + 32, 0);

  for (int k0 = 0; k0 < K; k0 += 64) {
    const int kn = (k0 + 64 < K) ? k0 + 64 : k0;  // clamped tail reload
    uint4 aN = loadA(kn), b0N = loadB(sr, kn), b1N = loadB(sr + 32, kn);
    barrier_lds();  // prev ds_reads done; vm prefetches stay in flight
    *(uint4*)&As[sr][sc8] = aC;
    *(uint4*)&Bs[sr][sc8] = b0C;
    *(uint4*)&Bs[sr + 32][sc8] = b1C;
    barrier_lds();
#pragma unroll
    for (int kk = 0; kk < 64; kk += 32) {
      bf16x8 a = *(const bf16x8*)&As[wm + lm][kk + quad * 8];
      bf16x8 b0 = *(const bf16x8*)&Bs[wn + lm][kk + quad * 8];
      bf16x8 b1 = *(const bf16x8*)&Bs[wn + 16 + lm][kk + quad * 8];
      acc[0] = __builtin_amdgcn_mfma_f32_16x16x32_bf16(a, b0, acc[0], 0, 0, 0);
      acc[1] = __builtin_amdgcn_mfma_f32_16x16x32_bf16(a, b1, acc[1], 0, 0, 0);
    }
    aC = aN; b0C = b0N; b1C = b1N;
  }
#pragma unroll
  for (int nt = 0; nt < 2; ++nt) {
    int col = n0 + wn + nt * 16 + lm;
    float bv = (flags & 1) ? bias[col] : 0.f;
#pragma unroll
    for (int t = 0; t < 4; ++t) {
      int row = m0 + wm + quad * 4 + t;
      float v = acc[nt][t] + bv;
      if (flags & 2) v = fmaxf(v, 0.f);
      if (flags & 4) Cb[(size_t)row * N + col] = f2bf(v);
      else C[(size_t)row * N + col] = v;
    }
  }
}

__global__ __launch_bounds__(256) void k_gemm_mfma(const ushort_t* __restrict__ A,
                                                   const ushort_t* __restrict__ Bt,
                                                   const float* __restrict__ bias,
                                                   float* __restrict__ C,
                                                   ushort_t* __restrict__ Cb,
                                                   int N, int K, int flags) {
  gemm32x64_body(A, Bt, bias, C, Cb, N, K, flags, blockIdx.y * 32, blockIdx.x * 64);
}

// -------- FT GEMM: 64x128 tile, 4 waves x (32x64), global_load_lds staging,
// conflict-free fragment ds_reads, double-buffered (2 x 24KB LDS).
// flags: 1=+bias, 2=relu. omode: 0=fp32 rm, 1=bf16 rm, 2=FT(cftKT),
// 3=q(qwft=v+rwb FT; aux=qrft=v+rrb FT), 4=k(kft FT, col-512),
// 5=v(vtft V^T FT), 6=r(rsft FT shifted +1 row; aux=r16 rm for row<16).
__device__ __forceinline__ void gemm_ft_body(
    ushort_t* smem, const ushort_t* __restrict__ A, const ushort_t* __restrict__ Bt,
    const float* __restrict__ bias, int N, int K, int kBeg, int kEnd,
    int m0, int n0, int flags, int omode,
    float* __restrict__ Cf, ushort_t* __restrict__ Cb, int cftKT,
    ushort_t* __restrict__ aux, const float* __restrict__ rwb,
    const float* __restrict__ rrb) {
  const int tid = threadIdx.x;
  const int lane = tid & 63, wv = tid >> 6;
  const int wm = (wv >> 1) * 32, wn = (wv & 1) * 64;
  const int lm = lane & 15, quad = lane >> 4;
  const int AKT = K >> 5;                 // global k-tiles per 16-row block
  const int mt0 = m0 >> 4, nt0 = n0 >> 4;
  const int kt0 = kBeg >> 5;

  f32x4 acc[2][4];
#pragma unroll
  for (int i = 0; i < 2; ++i)
#pragma unroll
    for (int j = 0; j < 4; ++j) acc[i][j] = (f32x4)(0.f);

  auto stage = [&](ushort_t* dA, int ktg) {
    ushort_t* dB = dA + 4096;
#pragma unroll
    for (int it = 0; it < 6; ++it) {
      const int c = (it << 8) + tid;
      if (it < 2) {  // A chunks: c in [0,512)
        const int blk = c >> 6, ln = c & 63;
        gload16(A + (((size_t)(mt0 + (blk >> 1)) * AKT + ktg + (blk & 1)) << 9) + (ln << 3),
                dA + (c << 3));
      } else {       // B chunks: cB in [0,1024)
        const int cB = c - 512;
        const int blk = cB >> 6, ln = cB & 63;
        gload16(Bt + (((size_t)(nt0 + (blk >> 1)) * AKT + ktg + (blk & 1)) << 9) + (ln << 3),
                dB + (cB << 3));
      }
    }
  };
  auto compute = [&](const ushort_t* dA) {
    const ushort_t* dB = dA + 4096;
#pragma unroll
    for (int kk = 0; kk < 2; ++kk) {
      bf16x8 a[2], b[4];
#pragma unroll
      for (int i = 0; i < 2; ++i)
        a[i] = *(const bf16x8*)&dA[((((wm >> 4) + i) << 1) + kk) * 512 + (lane << 3)];
#pragma unroll
      for (int j = 0; j < 4; ++j)
        b[j] = *(const bf16x8*)&dB[((((wn >> 4) + j) << 1) + kk) * 512 + (lane << 3)];
#pragma unroll
      for (int i = 0; i < 2; ++i)
#pragma unroll
        for (int j = 0; j < 4; ++j)
          acc[i][j] = __builtin_amdgcn_mfma_f32_16x16x32_bf16(a[i], b[j], acc[i][j], 0, 0, 0);
    }
  };

  const int nIter = (kEnd - kBeg) >> 6;  // always even (8) here
  stage(smem, kt0);
  __syncthreads();
  for (int t = 0; t < nIter; t += 2) {
    if (t + 1 < nIter) stage(smem + 12288, kt0 + (t + 1) * 2);
    compute(smem);
    __syncthreads();
    if (t + 2 < nIter) stage(smem, kt0 + (t + 2) * 2);
    compute(smem + 12288);
    __syncthreads();
  }

#pragma unroll
  for (int i = 0; i < 2; ++i) {
    const int rowb = m0 + wm + i * 16 + quad * 4;
#pragma unroll
    for (int j = 0; j < 4; ++j) {
      const int col = n0 + wn + j * 16 + lm;
      const float bv = (flags & 1) ? bias[col] : 0.f;
#pragma unroll
      for (int t2 = 0; t2 < 4; ++t2) {
        const int row = rowb + t2;
        float v = acc[i][j][t2] + bv;
        if (flags & 2) v = fmaxf(v, 0.f);
        if (omode == 0) {
          Cf[(size_t)row * N + col] = v;
        } else if (omode == 1) {
          Cb[(size_t)row * N + col] = f2bf(v);
        } else if (omode == 2) {
          Cb[(((size_t)(row >> 4) * cftKT + (col >> 5)) << 9) +
             (((col >> 3) & 3) << 7) + ((row & 15) << 3) + (col & 7)] = f2bf(v);
        } else if (omode == 3) {
          Cb[ft512(row, col)] = f2bf(v + rwb[col]);
          aux[ft512(row, col)] = f2bf(v + rrb[col]);
        } else if (omode == 4) {
          Cb[ft512(row, col - 512)] = f2bf(v);
        } else if (omode == 5) {  // V^T FT, r = v-dim, c = token
          const int dv = col - 1024;
          Cb[((size_t)(dv >> 4) * 65 + (row >> 5)) * 512 +
             (((row >> 3) & 3) << 7) + ((dv & 15) << 3) + (row & 7)] = f2bf(v);
        } else {  // omode 6: shifted r (rsft[k] = r[k-1]) + r16 head rows
          Cb[ft512(row + 1, col)] = f2bf(v);
          if (row < 16) aux[(size_t)row * 512 + col] = f2bf(v);
        }
      }
    }
  }
}

// merged QKV + Wr GEMMs (FT); q -> qwft(+rwb) & qrft(+rrb); k -> kft;
// v -> vtft (V^T FT); Wr -> rsft (shifted FT) + r16
__global__ __launch_bounds__(256) void k_gemm_qkvwr_ft(
    const ushort_t* __restrict__ wbft, const ushort_t* __restrict__ posft,
    const ushort_t* __restrict__ qkvT, const ushort_t* __restrict__ wrT,
    ushort_t* __restrict__ qwft, ushort_t* __restrict__ kft,
    ushort_t* __restrict__ vtft, ushort_t* __restrict__ rsft,
    ushort_t* __restrict__ r16, ushort_t* __restrict__ qrft,
    const float* __restrict__ rwb, const float* __restrict__ rrb) {
  __shared__ ushort_t smem[24576];
  int m0 = blockIdx.y * 64;
  if (m0 + 64 > TT) m0 = TT - 64;  // overlapped last tile (dup writes benign)
  const int bx = blockIdx.x;
  if (bx < 12) {
    const int om = (bx < 4) ? 3 : (bx < 8 ? 4 : 5);
    ushort_t* dst = (om == 3) ? qwft : (om == 4) ? kft : vtft;
    gemm_ft_body(smem, wbft, qkvT, nullptr, QKV_N, DM, 0, DM, m0, bx * 128,
                 0, om, nullptr, dst, 0, (om == 3) ? qrft : nullptr, rwb, rrb);
  } else {
    gemm_ft_body(smem, posft, wrT, nullptr, DM, DM, 0, DM, m0, (bx - 12) * 128,
                 0, 6, nullptr, rsft, 0, r16, nullptr, nullptr);
  }
}

// FFN1: wbft x w1T -> ff1ft (FT, K_out = DI), bias+relu
__global__ __launch_bounds__(256) void k_ffn1_ft(const ushort_t* __restrict__ wbft,
                                                 const ushort_t* __restrict__ w1T,
                                                 const float* __restrict__ b1l,
                                                 ushort_t* __restrict__ ff1ft) {
  __shared__ ushort_t smem[24576];
  int m0 = blockIdx.y * 64;
  if (m0 + 64 > TT) m0 = TT - 64;
  gemm_ft_body(smem, wbft, w1T, b1l, DI, DM, 0, DM, m0, blockIdx.x * 128,
               1 | 2, 2, nullptr, ff1ft, DI >> 5, nullptr, nullptr, nullptr);
}

// FFN2: ff1ft x w2T -> fp32 partials (split-K=4); bias folded into split 0
__global__ __launch_bounds__(256) void k_ffn2_ft(const ushort_t* __restrict__ ff1ft,
                                                 const ushort_t* __restrict__ w2T,
                                                 const float* __restrict__ b2l,
                                                 float* __restrict__ ff2p) {
  __shared__ ushort_t smem[24576];
  int m0 = blockIdx.y * 64;
  if (m0 + 64 > TT) m0 = TT - 64;
  const int s = blockIdx.z;
  gemm_ft_body(smem, ff1ft, w2T, b2l, DM, DI, s * 512, s * 512 + 512, m0,
               blockIdx.x * 128, (s == 0) ? 1 : 0, 0,
               ff2p + (size_t)s * TT * DM, nullptr, 0, nullptr, nullptr, nullptr);
}

// ---- wrap values: wrapv[h][row][w<16] = qr_row(h) . r_w(h) ---------------
// (rel_shift wrap entries; read only on diagonal-tile mem corners)
__global__ __launch_bounds__(256) void k_wrap(const ushort_t* __restrict__ qrft,
                                              const ushort_t* __restrict__ r16,
                                              ushort_t* __restrict__ wrapv) {
  const int h = blockIdx.y;
  const int row = blockIdx.x * 32 + (threadIdx.x >> 3);
  const int w = threadIdx.x & 7;
  float a0 = 0.f, a1 = 0.f;
#pragma unroll
  for (int d8 = 0; d8 < 64; d8 += 8) {
    bf16x8 qv = *(const bf16x8*)&qrft[ft512(row, h * DH + d8)];
    bf16x8 r0 = *(const bf16x8*)&r16[(size_t)w * 512 + h * DH + d8];
    bf16x8 r1 = *(const bf16x8*)&r16[(size_t)(w + 8) * 512 + h * DH + d8];
#pragma unroll
    for (int e = 0; e < 8; ++e) {
      float q = bf2f((ushort_t)qv[e]);
      a0 += q * bf2f((ushort_t)r0[e]);
      a1 += q * bf2f((ushort_t)r1[e]);
    }
  }
  const size_t b = (size_t)h * TT * 16 + (size_t)row * 16;
  wrapv[b + w] = f2bf(a0);
  wrapv[b + w + 8] = f2bf(a1);
}

// ------- MFMA flash attention, KVBLK=32, split-j, FT-staged Q/K/V^T -------
// Round-6 structure (27KB LDS, barriers identical) + in-kernel banded BD:
// QRb = qr x rS-window via MFMA (L2-resident), shfl-aligned into st = AC+BD.
// The 39MB/dispatch qrp HBM stream and k_qr are gone.
__global__ __launch_bounds__(256) void k_attn(const ushort_t* __restrict__ qwft,
                                              const ushort_t* __restrict__ qrft,
                                              const ushort_t* __restrict__ kft,
                                              const ushort_t* __restrict__ vtft,
                                              const ushort_t* __restrict__ rsft,
                                              const ushort_t* __restrict__ wrapv,
                                              float* __restrict__ mlP,
                                              ushort_t* __restrict__ opP) {
  const int h = blockIdx.y;
  const int qt = 64 - blockIdx.x;  // heavy q-tiles dispatch first
  const int c = blockIdx.z;
  if (c > qt) return;  // empty chunk
  const int i0 = qt * 32;
  const int tid = threadIdx.x;
  const int lane = tid & 63, wv = tid >> 6;
  const int lm = lane & 15, quad = lane >> 4;

  __shared__ ushort_t qwl[2048];     // (q+rwb) 4 FT blocks [it][kt]
  __shared__ ushort_t kl[2][2048];   // K dbuf, 4 FT blocks [jt][kt]
  __shared__ ushort_t vtl[2][2048];  // V^T dbuf, 4 FT blocks [dt]
  __shared__ ushort_t pbl[1024];     // P bf16, 2 FT blocks [it]
  __shared__ float st[32][34];       // AC+BD fp32 [i][j] (+2 pad)
  __shared__ float m_s[32], l_s[32], alpha_s[32];

  const int ii = tid >> 3, g = tid & 7, jjb = g * 4;
  const int i = i0 + ii;
  const size_t hwr = (size_t)h * TT * 16;

  const int sblk = tid >> 6, sln = tid & 63;
  auto stageKV = [&](int j0, int buf) {
    gload16(kft + (((size_t)((j0 >> 4) + (sblk >> 1)) * 16) + h * 2 + (sblk & 1)) * 512 +
                (sln << 3),
            kl[buf] + (tid << 3));
    gload16(vtft + (((size_t)(h * 4 + sblk)) * 65 + (j0 >> 5)) * 512 + (sln << 3),
            vtl[buf] + (tid << 3));
  };

  // per-wave quadrant + its banded-QR column pair
  const int acit = wv >> 1, acjt = wv & 1;
  const int cqlo = 1 + acjt - acit;  // needed QRb col-blocks {cqlo, cqlo+1}
  auto loadRS = [&](int jt2, bf16x8 (&rs)[2][2]) {
    const int wbp4 = 128 - 2 * (qt - jt2);  // rS window base block
#pragma unroll
    for (int f = 0; f < 2; ++f)
#pragma unroll
      for (int kt = 0; kt < 2; ++kt)
        rs[f][kt] = *(const bf16x8*)&rsft[(((size_t)(wbp4 + cqlo + f) * 16) +
                                          h * 2 + kt) * 512 + (lane << 3)];
  };

  // prologue: Q tile + first K/V tile direct-to-LDS; first rS to VGPR
  gload16(qwft + (((size_t)((i0 >> 4) + (sblk >> 1)) * 16) + h * 2 + (sblk & 1)) * 512 +
              (sln << 3),
          qwl + (tid << 3));
  stageKV(c * 32, 0);
  bf16x8 rsc[2][2];
  loadRS(c, rsc);
  if (tid < 32) { m_s[tid] = -INFINITY; l_s[tid] = 0.f; }
  barrier_all();

  // loop-invariant A fragments: q+rwb (from LDS) and q+rrb (direct global)
  bf16x8 aQ[2], aQR[2];
#pragma unroll
  for (int kt = 0; kt < 2; ++kt) {
    aQ[kt] = *(const bf16x8*)&qwl[(acit * 2 + kt) * 512 + (lane << 3)];
    aQR[kt] = *(const bf16x8*)&qrft[(((size_t)((i0 >> 4) + acit) * 16) +
                                    h * 2 + kt) * 512 + (lane << 3)];
  }

  f32x4 oA = (f32x4)(0.f);  // O^T accum, d-tile=wv, i = i0+lm
  f32x4 oB = (f32x4)(0.f);  // i = i0+16+lm

  int cur = 0;
  for (int jt = c; jt <= qt; jt += SPLIT) {
    const int j0 = jt * 32;
    if (jt + SPLIT <= qt) stageKV((jt + SPLIT) * 32, cur ^ 1);
    const int jn = (jt + SPLIT <= qt) ? jt + SPLIT : jt;
    bf16x8 rsn[2][2];
    loadRS(jn, rsn);

    {  // ---- phase B: AC + banded-QR MFMAs -> st = AC + BD ----
      f32x4 ac = (f32x4)(0.f), qa = (f32x4)(0.f), qb = (f32x4)(0.f);
#pragma unroll
      for (int kt = 0; kt < 2; ++kt) {
        bf16x8 b = *(const bf16x8*)&kl[cur][(acjt * 2 + kt) * 512 + (lane << 3)];
        ac = __builtin_amdgcn_mfma_f32_16x16x32_bf16(aQ[kt], b, ac, 0, 0, 0);
        qa = __builtin_amdgcn_mfma_f32_16x16x32_bf16(aQR[kt], rsc[0][kt], qa, 0, 0, 0);
        qb = __builtin_amdgcn_mfma_f32_16x16x32_bf16(aQR[kt], rsc[1][kt], qb, 0, 0, 0);
      }
      const bool diag = (jt == qt);
      const int thr = 16 * (1 + acit - acjt);
#pragma unroll
      for (int t = 0; t < 4; ++t) {
        // element (row quad*4+t, col lm) needs band index cw = col-row+32;
        // within this wave's pair: idx = cw - cqlo*16 = lm - (quad*4+t) + 16
        const int idx = lm - (quad * 4 + t) + 16;
        const int src = quad * 16 + (idx & 15);
        const float av = __shfl(qa[t], src);
        const float bv2 = __shfl(qb[t], src);
        float bd = (idx < 16) ? av : bv2;
        if (diag && idx > thr) bd = 0.f;  // j > i: BD replaced by mask/wrap
        st[acit * 16 + quad * 4 + t][acjt * 16 + lm] = ac[t] + bd;
      }
    }
    barrier_lds();

    {  // ---- phase C: score masking + online softmax ----
      float sreg[4];
      if (jt < qt) {  // fast path: all-causal tile, BD already in st
#pragma unroll
        for (int u = 0; u < 4; ++u) sreg[u] = st[ii][jjb + u] * ATT_SCALE;
      } else {  // diagonal tile: mask + mem-corner + wrap handling
#pragma unroll
        for (int u = 0; u < 4; ++u) {
          int j = j0 + jjb + u;
          float stv = st[ii][jjb + u];
          float s;
          if (j <= i) {
            s = stv * ATT_SCALE;
          } else {
            bool inmem = (i < NMTOK && j < NMTOK) ||
                         (i >= TT - NMTOK && j >= TT - NMTOK);
            if (!inmem) s = -1e30f;
            else if (j == i + 1) s = stv * ATT_SCALE;  // rel_shift zero-pad
            else s = (stv + bf2f(wrapv[hwr + (size_t)(i + 1) * 16 + (j - i - 2)])) *
                     ATT_SCALE;
          }
          sreg[u] = s;
        }
      }
      float tmax = fmaxf(fmaxf(sreg[0], sreg[1]), fmaxf(sreg[2], sreg[3]));
#pragma unroll
      for (int off = 1; off < 8; off <<= 1) tmax = fmaxf(tmax, __shfl_xor(tmax, off));
      const float mold = m_s[ii];
      const float mnew = fmaxf(mold, tmax);
      const float alpha = __expf(mold - mnew);
      float p[4], psum = 0.f;
#pragma unroll
      for (int u = 0; u < 4; ++u) { p[u] = __expf(sreg[u] - mnew); psum += p[u]; }
#pragma unroll
      for (int off = 1; off < 8; off <<= 1) psum += __shfl_xor(psum, off);
      uint2 pk;
      pk.x = pack2(f2bf(p[0]), f2bf(p[1]));
      pk.y = pack2(f2bf(p[2]), f2bf(p[3]));
      *(uint2*)&pbl[(size_t)(ii >> 4) * 512 + (g >> 1) * 128 + (ii & 15) * 8 +
                    (g & 1) * 4] = pk;
      if (g == 0) {
        m_s[ii] = mnew;
        l_s[ii] = l_s[ii] * alpha + psum;
        alpha_s[ii] = alpha;
      }
    }
    barrier_lds();

    {  // ---- phase D: O^T = O^T*alpha + V^T P^T ----
      float a0 = alpha_s[lm], a1 = alpha_s[16 + lm];
      bf16x8 av = *(const bf16x8*)&vtl[cur][wv * 512 + (lane << 3)];
      bf16x8 p0 = *(const bf16x8*)&pbl[(lane << 3)];
      bf16x8 p1 = *(const bf16x8*)&pbl[512 + (lane << 3)];
#pragma unroll
      for (int t = 0; t < 4; ++t) { oA[t] *= a0; oB[t] *= a1; }
      oA = __builtin_amdgcn_mfma_f32_16x16x32_bf16(av, p0, oA, 0, 0, 0);
      oB = __builtin_amdgcn_mfma_f32_16x16x32_bf16(av, p1, oB, 0, 0, 0);
    }
    barrier_all();  // retire prefetch + recycle buffers
    cur ^= 1;
#pragma unroll
    for (int f = 0; f < 2; ++f)
#pragma unroll
      for (int kt = 0; kt < 2; ++kt) rsc[f][kt] = rsn[f][kt];
  }

  {  // write partials: m, l (fp32) and un-normalized O (bf16, [i][d] layout)
    const int pidx = (qt * NH + h) * SPLIT + c;
    if (tid < 32) {
      mlP[(size_t)pidx * 64 + tid] = m_s[tid];
      mlP[(size_t)pidx * 64 + 32 + tid] = l_s[tid];
    }
    ushort_t o0[4], o1[4];
#pragma unroll
    for (int t = 0; t < 4; ++t) { o0[t] = f2bf(oA[t]); o1[t] = f2bf(oB[t]); }
    size_t ob = (size_t)pidx * 2048;
    *(uint2*)&opP[ob + (size_t)lm * 64 + wv * 16 + quad * 4] = *(uint2*)o0;
    *(uint2*)&opP[ob + (size_t)(16 + lm) * 64 + wv * 16 + quad * 4] = *(uint2*)o1;
  }
}

// -------- combine <=SPLIT chunk partials -> normalized attn output --------
__global__ __launch_bounds__(256) void k_attn_combine(const float* __restrict__ mlP,
                                                      const ushort_t* __restrict__ opP,
                                                      ushort_t* __restrict__ attnb) {
  const int qt = blockIdx.x, h = blockIdx.y;
  const int nc = (qt + 1 < SPLIT) ? qt + 1 : SPLIT;
  const int tid = threadIdx.x;
  const int i = tid >> 3, d8 = (tid & 7) * 8;
  const size_t base = (size_t)(qt * NH + h) * SPLIT;
  float m[SPLIT], l[SPLIT], wgt[SPLIT];
  float M = -INFINITY;
  for (int cc = 0; cc < nc; ++cc) {
    m[cc] = mlP[(base + cc) * 64 + i];
    l[cc] = mlP[(base + cc) * 64 + 32 + i];
    M = fmaxf(M, m[cc]);
  }
  float L = 0.f;
  for (int cc = 0; cc < nc; ++cc) { wgt[cc] = __expf(m[cc] - M); L += l[cc] * wgt[cc]; }
  float acc[8] = {0, 0, 0, 0, 0, 0, 0, 0};
  for (int cc = 0; cc < nc; ++cc) {
    uint4 v = *(const uint4*)&opP[(base + cc) * 2048 + (size_t)i * 64 + d8];
    float f[8]; unpack8(v, f);
#pragma unroll
    for (int k = 0; k < 8; ++k) acc[k] += wgt[cc] * f[k];
  }
  const float inv = 1.f / L;
  ushort_t o8[8];
#pragma unroll
  for (int k = 0; k < 8; ++k) o8[k] = f2bf(acc[k] * inv);
  *(uint4*)&attnb[(size_t)(qt * 32 + i) * DM + h * DH + d8] = *(uint4*)o8;
}

// -------- w' = LayerNorm(w + sum(delta parts)) * g + b ---------------------
__global__ __launch_bounds__(256) void k_addln(const float* __restrict__ w,
                                               float* __restrict__ wout,
                                               ushort_t* __restrict__ wbft,
                                               const float* __restrict__ delta,
                                               int nparts,
                                               const float* __restrict__ gamma,
                                               const float* __restrict__ beta) {
  const int row = blockIdx.x;
  const int tid = threadIdx.x;
  __shared__ float red[4], red2[4];
  __shared__ float sm[512];
  size_t base = (size_t)row * DM;
  float x0 = w[base + tid];
  float x1 = w[base + tid + 256];
  for (int p = 0; p < nparts; ++p) {
    x0 += delta[(size_t)p * TT * DM + base + tid];
    x1 += delta[(size_t)p * TT * DM + base + tid + 256];
  }
  float s = x0 + x1;
#pragma unroll
  for (int off = 1; off < 64; off <<= 1) s += __shfl_xor(s, off);
  if ((tid & 63) == 0) red[tid >> 6] = s;
  __syncthreads();
  float mu = (red[0] + red[1] + red[2] + red[3]) * (1.f / 512.f);
  float d0 = x0 - mu, d1 = x1 - mu;
  float v = d0 * d0 + d1 * d1;
#pragma unroll
  for (int off = 1; off < 64; off <<= 1) v += __shfl_xor(v, off);
  if ((tid & 63) == 0) red2[tid >> 6] = v;
  __syncthreads();
  float var = (red2[0] + red2[1] + red2[2] + red2[3]) * (1.f / 512.f);
  float rstd = rsqrtf(var + 1e-5f);
  float o0 = d0 * rstd * gamma[tid] + beta[tid];
  float o1 = d1 * rstd * gamma[tid + 256] + beta[tid + 256];
  wout[base + tid] = o0;
  wout[base + tid + 256] = o1;
  sm[tid] = o0; sm[tid + 256] = o1;
  __syncthreads();
  if (tid < 64) {
    const int d8 = tid << 3;
    ushort_t t8[8];
#pragma unroll
    for (int e = 0; e < 8; ++e) t8[e] = f2bf(sm[d8 + e]);
    *(uint4*)&wbft[ft512(row, d8)] = *(uint4*)t8;
  }
}

extern "C" void kernel_launch(void* const* d_in, const int* in_sizes, int n_in,
                              void* d_out, int out_size, void* d_ws, size_t ws_size,
                              hipStream_t stream) {
  const float* we   = (const float*)d_in[0];
  const float* mem  = (const float*)d_in[1];
  const float* Wqkv = (const float*)d_in[2];
  const float* Wr   = (const float*)d_in[3];
  const float* Wo   = (const float*)d_in[4];
  const float* ln1s = (const float*)d_in[5];
  const float* ln1b = (const float*)d_in[6];
  const float* W1   = (const float*)d_in[7];
  const float* b1   = (const float*)d_in[8];
  const float* W2   = (const float*)d_in[9];
  const float* b2   = (const float*)d_in[10];
  const float* ln2s = (const float*)d_in[11];
  const float* ln2b = (const float*)d_in[12];
  const float* rwb  = (const float*)d_in[13];
  const float* rrb  = (const float*)d_in[14];

  // ---- workspace layout ----
  float* w     = (float*)d_ws;                        // TT*DM fp32
  float* proj  = w + (size_t)TT * DM;                 // TT*DM fp32 (Wo out)
  ushort_t* wbft  = (ushort_t*)(proj + (size_t)TT * DM);  // TT*DM bf16 (FT)
  ushort_t* posft = wbft + (size_t)TT * DM;           // TT*DM bf16 (FT)
  ushort_t* attnb = posft + (size_t)TT * DM;          // TT*DM bf16 (rm)
  ushort_t* qkvB  = attnb + (size_t)TT * DM;          // q/k/v FT region
  ushort_t* qwft  = qkvB;                             // TT*DM (Q+rwb, FT)
  ushort_t* kft   = qkvB + (size_t)TT * DM;           // TT*DM (K, FT)
  ushort_t* vtft  = qkvB + (size_t)2 * TT * DM;       // DM*TT (V^T, FT)
  // + TT*DM reserved gap (ff1ft overlay tail)
  ushort_t* WtAll = qkvB + (size_t)TT * QKV_N + (size_t)TT * DM;
  ushort_t* opP   = WtAll + (size_t)NLAYER * WT_STRIDE;  // 65*8*SPLIT*2048
  float* mlP   = (float*)(opP + (size_t)65 * 8 * SPLIT * 2048);  // 65*8*SPLIT*64 f32
  ushort_t* qrft  = (ushort_t*)(mlP + (size_t)65 * 8 * SPLIT * 64);  // TT*DM (FT)
  ushort_t* rsft  = qrft + (size_t)TT * DM;           // RSFT_ROWS/16 * 16*512 shorts
  ushort_t* wrapv = rsft + (size_t)(RSFT_ROWS / 16) * 16 * 512;  // NH*TT*16
  ushort_t* r16   = wrapv + (size_t)NH * TT * 16;     // 16*512
  // overlays (time-shared, stream-ordered):
  ushort_t* ff1ft = qkvB;            // FT TT*DI bf16 spans qkv region + gap
  float* ff2p  = (float*)opP;        // 4 split-K partials, 4*TT*DM f32
  const size_t OFF_QKVT = 0, OFF_WRT = 786432, OFF_WOT = 1048576,
               OFF_W1T = 1310720, OFF_W2T = 2359296;

  // all-layer weight transpose(+FT pack) + build in one dispatch
  k_prep<<<13312 + 4160, 256, 0, stream>>>(Wqkv, Wr, Wo, W1, W2, WtAll,
                                           we, mem, w, wbft, posft);

  dim3 gQW(16, 33);          // merged QKV (12 n-tiles) + Wr (4 n-tiles), 64x128
  dim3 gW1(16, 33);          // FFN1 64x128
  dim3 gW2(4, 33, 4);        // FFN2 64x128, split-K=4
  dim3 gDM32(DM / 64, 65);   // Wo (old 32x64 kernel)
  dim3 gWr(65, NH);          // wrap-value micro-kernel
  dim3 gA(65, NH, SPLIT);
  dim3 gC(65, NH);

  for (int l = 0; l < NLAYER; ++l) {
    const ushort_t* Wt = WtAll + (size_t)l * WT_STRIDE;
    k_gemm_qkvwr_ft<<<gQW, 256, 0, stream>>>(wbft, posft, Wt + OFF_QKVT,
                                             Wt + OFF_WRT, qwft, kft, vtft,
                                             rsft, r16, qrft, rwb, rrb);
    k_wrap<<<gWr, 256, 0, stream>>>(qrft, r16, wrapv);
    k_attn<<<gA, 256, 0, stream>>>(qwft, qrft, kft, vtft, rsft, wrapv, mlP, opP);
    k_attn_combine<<<gC, 256, 0, stream>>>(mlP, opP, attnb);
    k_gemm_mfma<<<gDM32, 256, 0, stream>>>(attnb, Wt + OFF_WOT, nullptr, proj, nullptr,
                                           DM, DM, 0);
    k_addln<<<TT, 256, 0, stream>>>(w, w, wbft, proj, 1,
                                    ln1s + (size_t)l * DM, ln1b + (size_t)l * DM);
    k_ffn1_ft<<<gW1, 256, 0, stream>>>(wbft, Wt + OFF_W1T, b1 + (size_t)l * DI, ff1ft);
    k_ffn2_ft<<<gW2, 256, 0, stream>>>(ff1ft, Wt + OFF_W2T, b2 + (size_t)l * DM, ff2p);
    float* wout = (l == NLAYER - 1) ? (float*)d_out : w;
    k_addln<<<TT, 256, 0, stream>>>(w, wout, wbft, ff2p, 4,
                                    ln2s + (size_t)l * DM, ln2b + (size_t)l * DM);
  }
}

// Round 11
// 600.862 us; speedup vs baseline: 1.1253x; 1.0103x over previous
//
#include <hip/hip_runtime.h>
#include <hip/hip_bf16.h>
#include <math.h>
#include <stdint.h>

#define TT 2080
#define DM 512
#define DI 2048
#define NH 8
#define DH 64
#define NMTOK 16
#define NLAYER 4
#define QKV_N 1536
#define ATT_SCALE 0.125f
#define SPLIT 8
#define WT_STRIDE 3407872   // shorts per layer's transposed-weight block
#define RSFT_ROWS 2112      // shifted-r FT rows (132 blocks of 16)

typedef short bf16x8 __attribute__((ext_vector_type(8)));
typedef float f32x4 __attribute__((ext_vector_type(4)));
typedef unsigned short ushort_t;

__device__ __forceinline__ ushort_t f2bf(float f) {
  __hip_bfloat16 h = __float2bfloat16(f);
  return *reinterpret_cast<ushort_t*>(&h);
}
__device__ __forceinline__ float bfbits2f(unsigned int hi_bits) {
  return __uint_as_float(hi_bits);
}
__device__ __forceinline__ float bf2f(ushort_t u) {
  return bfbits2f(((unsigned int)u) << 16);
}
__device__ __forceinline__ void unpack8(uint4 v, float* f) {
  f[0] = bfbits2f(v.x << 16); f[1] = bfbits2f(v.x & 0xffff0000u);
  f[2] = bfbits2f(v.y << 16); f[3] = bfbits2f(v.y & 0xffff0000u);
  f[4] = bfbits2f(v.z << 16); f[5] = bfbits2f(v.z & 0xffff0000u);
  f[6] = bfbits2f(v.w << 16); f[7] = bfbits2f(v.w & 0xffff0000u);
}
__device__ __forceinline__ unsigned int pack2(ushort_t lo, ushort_t hi) {
  return (unsigned int)lo | ((unsigned int)hi << 16);
}
// Barrier draining LDS ops only — leaves global (vmcnt) loads in flight.
__device__ __forceinline__ void barrier_lds() {
  asm volatile("s_waitcnt lgkmcnt(0)" ::: "memory");
  __builtin_amdgcn_s_barrier();
}
// Barrier draining everything (used to retire global_load_lds prefetches).
__device__ __forceinline__ void barrier_all() {
  asm volatile("s_waitcnt vmcnt(0) lgkmcnt(0)" ::: "memory");
  __builtin_amdgcn_s_barrier();
}
// global -> LDS direct copy, 16B per lane. LDS dest must be wave-uniform
// base + lane*16 (contract of global_load_lds).
__device__ __forceinline__ void gload16(const ushort_t* g, ushort_t* l) {
  __builtin_amdgcn_global_load_lds(
      (__attribute__((address_space(1))) void*)(uintptr_t)g,
      (__attribute__((address_space(3))) void*)(uintptr_t)l, 16, 0, 0);
}
// ---- fragment-tiled (FT) layout --------------------------------------------
// Matrix X[R][K] (bf16) stored as 1024B blocks of (16 r x 32 k); lane
// = ((k>>3)&3)*16 + (r&15) holds 8 consecutive k-elements = EXACTLY the
// mfma_f32_16x16x32_bf16 A/B fragment order.
__device__ __forceinline__ size_t ft512(int r, int c) {  // K = 512 (KT = 16)
  return (((size_t)(r >> 4) * 16 + (c >> 5)) << 9) + (((c >> 3) & 3) << 7) +
         ((r & 15) << 3) + (c & 7);
}

// ---- fused prep: all 4 layers' weight transposes + build w/pos ------------
__global__ __launch_bounds__(256) void k_prep(
    const float* __restrict__ Wqkv, const float* __restrict__ Wr,
    const float* __restrict__ Wo, const float* __restrict__ W1,
    const float* __restrict__ W2, ushort_t* __restrict__ dstAll,
    const float* __restrict__ we, const float* __restrict__ mem,
    float* __restrict__ w, ushort_t* __restrict__ wbft,
    ushort_t* __restrict__ posft) {
  const int tid = threadIdx.x;
  if (blockIdx.x >= 13312) {  // ---- build ----
    int idx = (blockIdx.x - 13312) * 256 + tid;
    if (idx >= TT * DM) return;
    int t = idx >> 9, d = idx & 511;
    float v;
    if (t < NMTOK) v = mem[t * DM + d];
    else if (t < NMTOK + 2048) v = we[(t - NMTOK) * DM + d];
    else v = mem[(t - (NMTOK + 2048)) * DM + d];
    w[idx] = v;
    wbft[ft512(t, d)] = f2bf(v);
    float p = (float)(TT - 1 - t);
    int i2 = d & 255;
    float freq = __expf(-0.035977892f * (float)i2);
    float ang = p * freq;
    posft[ft512(t, d)] = f2bf((d < 256) ? __sinf(ang) : __cosf(ang));
    return;
  }
  // ---- transpose+cast, layer l ----
  __shared__ float tl[32][33];
  const int l = blockIdx.x / 3328;
  int idx = blockIdx.x % 3328;
  const float* src;
  ushort_t* dst = dstAll + (size_t)l * WT_STRIDE;
  int K, N, local;
  bool isFT = true;
  if (idx < 768)       { src = Wqkv + (size_t)l * 512 * 1536; K = 512;  N = 1536; local = idx; }
  else if (idx < 1024) { src = Wr   + (size_t)l * 512 * 512;  dst += 786432;  K = 512;  N = 512;  local = idx - 768; }
  else if (idx < 1280) { src = Wo   + (size_t)l * 512 * 512;  dst += 1048576; K = 512;  N = 512;  local = idx - 1024; isFT = false; }
  else if (idx < 2304) { src = W1   + (size_t)l * 512 * 2048; dst += 1310720; K = 512;  N = 2048; local = idx - 1280; }
  else                 { src = W2   + (size_t)l * 2048 * 512; dst += 2359296; K = 2048; N = 512;  local = idx - 2304; }
  const int ntiles = N / 32;
  const int n0 = (local % ntiles) * 32, k0 = (local / ntiles) * 32;
#pragma unroll
  for (int p = 0; p < 4; ++p) {
    int row = (tid >> 5) + 8 * p, col = tid & 31;
    tl[row][col] = src[(size_t)(k0 + row) * N + n0 + col];  // tl[k][n]
  }
  __syncthreads();
  if (isFT) {
    if (tid < 128) {
      int b = tid >> 6, l2 = tid & 63;
      int nn = b * 16 + (l2 & 15);
      int kq = (l2 >> 4) * 8;
      ushort_t t8[8];
#pragma unroll
      for (int e = 0; e < 8; ++e) t8[e] = f2bf(tl[kq + e][nn]);
      size_t ad = (((size_t)((n0 >> 4) + b) * (K >> 5) + (k0 >> 5)) << 9) +
                  ((size_t)l2 << 3);
      *(uint4*)&dst[ad] = *(uint4*)t8;
    }
  } else {
#pragma unroll
    for (int p = 0; p < 4; ++p) {
      int n = (tid >> 5) + 8 * p, k = tid & 31;
      dst[(size_t)(n0 + n) * K + k0 + k] = f2bf(tl[k][n]);
    }
  }
}

// -------- bf16 MFMA GEMM body, 32x64 tile, register prefetch (Wo only) ----
__device__ __forceinline__ void gemm32x64_body(const ushort_t* __restrict__ A,
                                               const ushort_t* __restrict__ Bt,
                                               const float* __restrict__ bias,
                                               float* __restrict__ C,
                                               ushort_t* __restrict__ Cb,
                                               int N, int K, int flags,
                                               int m0, int n0) {
  __shared__ short As[32][72];
  __shared__ short Bs[64][72];
  const int tid = threadIdx.x;
  const int lane = tid & 63, wv = tid >> 6;
  const int wm = (wv >> 1) * 16, wn = (wv & 1) * 32;
  const int lm = lane & 15, quad = lane >> 4;
  const int sr = tid >> 3, sc8 = (tid & 7) * 8;

  f32x4 acc[2];
  acc[0] = (f32x4)(0.f); acc[1] = (f32x4)(0.f);

  auto loadA = [&](int k0) -> uint4 {
    return *(const uint4*)&A[(size_t)(m0 + sr) * K + k0 + sc8];
  };
  auto loadB = [&](int row, int k0) -> uint4 {
    return *(const uint4*)&Bt[(size_t)(n0 + row) * K + k0 + sc8];
  };

  uint4 aC = loadA(0), b0C = loadB(sr, 0), b1C = loadB(sr + 32, 0);

  for (int k0 = 0; k0 < K; k0 += 64) {
    const int kn = (k0 + 64 < K) ? k0 + 64 : k0;  // clamped tail reload
    uint4 aN = loadA(kn), b0N = loadB(sr, kn), b1N = loadB(sr + 32, kn);
    barrier_lds();  // prev ds_reads done; vm prefetches stay in flight
    *(uint4*)&As[sr][sc8] = aC;
    *(uint4*)&Bs[sr][sc8] = b0C;
    *(uint4*)&Bs[sr + 32][sc8] = b1C;
    barrier_lds();
#pragma unroll
    for (int kk = 0; kk < 64; kk += 32) {
      bf16x8 a = *(const bf16x8*)&As[wm + lm][kk + quad * 8];
      bf16x8 b0 = *(const bf16x8*)&Bs[wn + lm][kk + quad * 8];
      bf16x8 b1 = *(const bf16x8*)&Bs[wn + 16 + lm][kk + quad * 8];
      acc[0] = __builtin_amdgcn_mfma_f32_16x16x32_bf16(a, b0, acc[0], 0, 0, 0);
      acc[1] = __builtin_amdgcn_mfma_f32_16x16x32_bf16(a, b1, acc[1], 0, 0, 0);
    }
    aC = aN; b0C = b0N; b1C = b1N;
  }
#pragma unroll
  for (int nt = 0; nt < 2; ++nt) {
    int col = n0 + wn + nt * 16 + lm;
    float bv = (flags & 1) ? bias[col] : 0.f;
#pragma unroll
    for (int t = 0; t < 4; ++t) {
      int row = m0 + wm + quad * 4 + t;
      float v = acc[nt][t] + bv;
      if (flags & 2) v = fmaxf(v, 0.f);
      if (flags & 4) Cb[(size_t)row * N + col] = f2bf(v);
      else C[(size_t)row * N + col] = v;
    }
  }
}

__global__ __launch_bounds__(256) void k_gemm_mfma(const ushort_t* __restrict__ A,
                                                   const ushort_t* __restrict__ Bt,
                                                   const float* __restrict__ bias,
                                                   float* __restrict__ C,
                                                   ushort_t* __restrict__ Cb,
                                                   int N, int K, int flags) {
  gemm32x64_body(A, Bt, bias, C, Cb, N, K, flags, blockIdx.y * 32, blockIdx.x * 64);
}

// -------- FT GEMM: 64x128 tile, 4 waves x (32x64), global_load_lds staging,
// conflict-free fragment ds_reads, double-buffered (2 x 24KB LDS).
// flags: 1=+bias, 2=relu. omode: 0=fp32 rm, 1=bf16 rm, 2=FT(cftKT),
// 3=q(qwft=v+rwb FT; aux=qrft=v+rrb FT), 4=k(kft FT, col-512),
// 5=v(vtft V^T FT), 6=r(rsft FT shifted +1 row; aux=r16 rm for row<16).
__device__ __forceinline__ void gemm_ft_body(
    ushort_t* smem, const ushort_t* __restrict__ A, const ushort_t* __restrict__ Bt,
    const float* __restrict__ bias, int N, int K, int kBeg, int kEnd,
    int m0, int n0, int flags, int omode,
    float* __restrict__ Cf, ushort_t* __restrict__ Cb, int cftKT,
    ushort_t* __restrict__ aux, const float* __restrict__ rwb,
    const float* __restrict__ rrb) {
  const int tid = threadIdx.x;
  const int lane = tid & 63, wv = tid >> 6;
  const int wm = (wv >> 1) * 32, wn = (wv & 1) * 64;
  const int lm = lane & 15, quad = lane >> 4;
  const int AKT = K >> 5;                 // global k-tiles per 16-row block
  const int mt0 = m0 >> 4, nt0 = n0 >> 4;
  const int kt0 = kBeg >> 5;

  f32x4 acc[2][4];
#pragma unroll
  for (int i = 0; i < 2; ++i)
#pragma unroll
    for (int j = 0; j < 4; ++j) acc[i][j] = (f32x4)(0.f);

  auto stage = [&](ushort_t* dA, int ktg) {
    ushort_t* dB = dA + 4096;
#pragma unroll
    for (int it = 0; it < 6; ++it) {
      const int c = (it << 8) + tid;
      if (it < 2) {  // A chunks: c in [0,512)
        const int blk = c >> 6, ln = c & 63;
        gload16(A + (((size_t)(mt0 + (blk >> 1)) * AKT + ktg + (blk & 1)) << 9) + (ln << 3),
                dA + (c << 3));
      } else {       // B chunks: cB in [0,1024)
        const int cB = c - 512;
        const int blk = cB >> 6, ln = cB & 63;
        gload16(Bt + (((size_t)(nt0 + (blk >> 1)) * AKT + ktg + (blk & 1)) << 9) + (ln << 3),
                dB + (cB << 3));
      }
    }
  };
  auto compute = [&](const ushort_t* dA) {
    const ushort_t* dB = dA + 4096;
#pragma unroll
    for (int kk = 0; kk < 2; ++kk) {
      bf16x8 a[2], b[4];
#pragma unroll
      for (int i = 0; i < 2; ++i)
        a[i] = *(const bf16x8*)&dA[((((wm >> 4) + i) << 1) + kk) * 512 + (lane << 3)];
#pragma unroll
      for (int j = 0; j < 4; ++j)
        b[j] = *(const bf16x8*)&dB[((((wn >> 4) + j) << 1) + kk) * 512 + (lane << 3)];
#pragma unroll
      for (int i = 0; i < 2; ++i)
#pragma unroll
        for (int j = 0; j < 4; ++j)
          acc[i][j] = __builtin_amdgcn_mfma_f32_16x16x32_bf16(a[i], b[j], acc[i][j], 0, 0, 0);
    }
  };

  const int nIter = (kEnd - kBeg) >> 6;  // always even (8) here
  stage(smem, kt0);
  __syncthreads();
  for (int t = 0; t < nIter; t += 2) {
    if (t + 1 < nIter) stage(smem + 12288, kt0 + (t + 1) * 2);
    compute(smem);
    __syncthreads();
    if (t + 2 < nIter) stage(smem, kt0 + (t + 2) * 2);
    compute(smem + 12288);
    __syncthreads();
  }

#pragma unroll
  for (int i = 0; i < 2; ++i) {
    const int rowb = m0 + wm + i * 16 + quad * 4;
#pragma unroll
    for (int j = 0; j < 4; ++j) {
      const int col = n0 + wn + j * 16 + lm;
      const float bv = (flags & 1) ? bias[col] : 0.f;
#pragma unroll
      for (int t2 = 0; t2 < 4; ++t2) {
        const int row = rowb + t2;
        float v = acc[i][j][t2] + bv;
        if (flags & 2) v = fmaxf(v, 0.f);
        if (omode == 0) {
          Cf[(size_t)row * N + col] = v;
        } else if (omode == 1) {
          Cb[(size_t)row * N + col] = f2bf(v);
        } else if (omode == 2) {
          Cb[(((size_t)(row >> 4) * cftKT + (col >> 5)) << 9) +
             (((col >> 3) & 3) << 7) + ((row & 15) << 3) + (col & 7)] = f2bf(v);
        } else if (omode == 3) {
          Cb[ft512(row, col)] = f2bf(v + rwb[col]);
          aux[ft512(row, col)] = f2bf(v + rrb[col]);
        } else if (omode == 4) {
          Cb[ft512(row, col - 512)] = f2bf(v);
        } else if (omode == 5) {  // V^T FT, r = v-dim, c = token
          const int dv = col - 1024;
          Cb[((size_t)(dv >> 4) * 65 + (row >> 5)) * 512 +
             (((row >> 3) & 3) << 7) + ((dv & 15) << 3) + (row & 7)] = f2bf(v);
        } else {  // omode 6: shifted r (rsft[k] = r[k-1]) + r16 head rows
          Cb[ft512(row + 1, col)] = f2bf(v);
          if (row < 16) aux[(size_t)row * 512 + col] = f2bf(v);
        }
      }
    }
  }
}

// merged QKV + Wr GEMMs (FT); q -> qwft(+rwb) & qrft(+rrb); k -> kft;
// v -> vtft (V^T FT); Wr -> rsft (shifted FT) + r16
__global__ __launch_bounds__(256) void k_gemm_qkvwr_ft(
    const ushort_t* __restrict__ wbft, const ushort_t* __restrict__ posft,
    const ushort_t* __restrict__ qkvT, const ushort_t* __restrict__ wrT,
    ushort_t* __restrict__ qwft, ushort_t* __restrict__ kft,
    ushort_t* __restrict__ vtft, ushort_t* __restrict__ rsft,
    ushort_t* __restrict__ r16, ushort_t* __restrict__ qrft,
    const float* __restrict__ rwb, const float* __restrict__ rrb) {
  __shared__ ushort_t smem[24576];
  int m0 = blockIdx.y * 64;
  if (m0 + 64 > TT) m0 = TT - 64;  // overlapped last tile (dup writes benign)
  const int bx = blockIdx.x;
  if (bx < 12) {
    const int om = (bx < 4) ? 3 : (bx < 8 ? 4 : 5);
    ushort_t* dst = (om == 3) ? qwft : (om == 4) ? kft : vtft;
    gemm_ft_body(smem, wbft, qkvT, nullptr, QKV_N, DM, 0, DM, m0, bx * 128,
                 0, om, nullptr, dst, 0, (om == 3) ? qrft : nullptr, rwb, rrb);
  } else {
    gemm_ft_body(smem, posft, wrT, nullptr, DM, DM, 0, DM, m0, (bx - 12) * 128,
                 0, 6, nullptr, rsft, 0, r16, nullptr, nullptr);
  }
}

// FFN1: wbft x w1T -> ff1ft (FT, K_out = DI), bias+relu
__global__ __launch_bounds__(256) void k_ffn1_ft(const ushort_t* __restrict__ wbft,
                                                 const ushort_t* __restrict__ w1T,
                                                 const float* __restrict__ b1l,
                                                 ushort_t* __restrict__ ff1ft) {
  __shared__ ushort_t smem[24576];
  int m0 = blockIdx.y * 64;
  if (m0 + 64 > TT) m0 = TT - 64;
  gemm_ft_body(smem, wbft, w1T, b1l, DI, DM, 0, DM, m0, blockIdx.x * 128,
               1 | 2, 2, nullptr, ff1ft, DI >> 5, nullptr, nullptr, nullptr);
}

// FFN2: ff1ft x w2T -> fp32 partials (split-K=4); bias folded into split 0
__global__ __launch_bounds__(256) void k_ffn2_ft(const ushort_t* __restrict__ ff1ft,
                                                 const ushort_t* __restrict__ w2T,
                                                 const float* __restrict__ b2l,
                                                 float* __restrict__ ff2p) {
  __shared__ ushort_t smem[24576];
  int m0 = blockIdx.y * 64;
  if (m0 + 64 > TT) m0 = TT - 64;
  const int s = blockIdx.z;
  gemm_ft_body(smem, ff1ft, w2T, b2l, DM, DI, s * 512, s * 512 + 512, m0,
               blockIdx.x * 128, (s == 0) ? 1 : 0, 0,
               ff2p + (size_t)s * TT * DM, nullptr, 0, nullptr, nullptr, nullptr);
}

// ---- wrap values: wrapv[h][row][w<16] = qr_row(h) . r_w(h) ---------------
// 1D grid, h = bid & 7 -> head h lands on XCD h (L2 affinity).
__global__ __launch_bounds__(256) void k_wrap(const ushort_t* __restrict__ qrft,
                                              const ushort_t* __restrict__ r16,
                                              ushort_t* __restrict__ wrapv) {
  const int bid = blockIdx.x;
  const int h = bid & 7;
  const int row = (bid >> 3) * 32 + (threadIdx.x >> 3);
  const int w = threadIdx.x & 7;
  float a0 = 0.f, a1 = 0.f;
#pragma unroll
  for (int d8 = 0; d8 < 64; d8 += 8) {
    bf16x8 qv = *(const bf16x8*)&qrft[ft512(row, h * DH + d8)];
    bf16x8 r0 = *(const bf16x8*)&r16[(size_t)w * 512 + h * DH + d8];
    bf16x8 r1 = *(const bf16x8*)&r16[(size_t)(w + 8) * 512 + h * DH + d8];
#pragma unroll
    for (int e = 0; e < 8; ++e) {
      float q = bf2f((ushort_t)qv[e]);
      a0 += q * bf2f((ushort_t)r0[e]);
      a1 += q * bf2f((ushort_t)r1[e]);
    }
  }
  const size_t b = (size_t)h * TT * 16 + (size_t)row * 16;
  wrapv[b + w] = f2bf(a0);
  wrapv[b + w + 8] = f2bf(a1);
}

// ------- MFMA flash attention, KVBLK=32, split-j, FT-staged Q/K/V^T -------
// Round-10 structure + head->XCD affinity: 1D grid with h = bid & 7, so all
// blocks of head h share one XCD's L2 (per-head working set ~1.4MB resident;
// kills the 8x cross-XCD duplication behind the 26.7MB FETCH/dispatch).
__global__ __launch_bounds__(256) void k_attn(const ushort_t* __restrict__ qwft,
                                              const ushort_t* __restrict__ qrft,
                                              const ushort_t* __restrict__ kft,
                                              const ushort_t* __restrict__ vtft,
                                              const ushort_t* __restrict__ rsft,
                                              const ushort_t* __restrict__ wrapv,
                                              float* __restrict__ mlP,
                                              ushort_t* __restrict__ opP) {
  const int bid = blockIdx.x;
  const int h = bid & 7;            // head == XCD (bid % 8 round-robin)
  const int rest = bid >> 3;
  const int qt = 64 - rest % 65;    // heavy q-tiles dispatch first
  const int c = rest / 65;
  if (c > qt) return;  // empty chunk
  const int i0 = qt * 32;
  const int tid = threadIdx.x;
  const int lane = tid & 63, wv = tid >> 6;
  const int lm = lane & 15, quad = lane >> 4;

  __shared__ ushort_t qwl[2048];     // (q+rwb) 4 FT blocks [it][kt]
  __shared__ ushort_t kl[2][2048];   // K dbuf, 4 FT blocks [jt][kt]
  __shared__ ushort_t vtl[2][2048];  // V^T dbuf, 4 FT blocks [dt]
  __shared__ ushort_t pbl[1024];     // P bf16, 2 FT blocks [it]
  __shared__ float st[32][34];       // AC+BD fp32 [i][j] (+2 pad)
  __shared__ float m_s[32], l_s[32], alpha_s[32];

  const int ii = tid >> 3, g = tid & 7, jjb = g * 4;
  const int i = i0 + ii;
  const size_t hwr = (size_t)h * TT * 16;

  const int sblk = tid >> 6, sln = tid & 63;
  auto stageKV = [&](int j0, int buf) {
    gload16(kft + (((size_t)((j0 >> 4) + (sblk >> 1)) * 16) + h * 2 + (sblk & 1)) * 512 +
                (sln << 3),
            kl[buf] + (tid << 3));
    gload16(vtft + (((size_t)(h * 4 + sblk)) * 65 + (j0 >> 5)) * 512 + (sln << 3),
            vtl[buf] + (tid << 3));
  };

  // per-wave quadrant + its banded-QR column pair
  const int acit = wv >> 1, acjt = wv & 1;
  const int cqlo = 1 + acjt - acit;  // needed QRb col-blocks {cqlo, cqlo+1}
  auto loadRS = [&](int jt2, bf16x8 (&rs)[2][2]) {
    const int wbp4 = 128 - 2 * (qt - jt2);  // rS window base block
#pragma unroll
    for (int f = 0; f < 2; ++f)
#pragma unroll
      for (int kt = 0; kt < 2; ++kt)
        rs[f][kt] = *(const bf16x8*)&rsft[(((size_t)(wbp4 + cqlo + f) * 16) +
                                          h * 2 + kt) * 512 + (lane << 3)];
  };

  // prologue: Q tile + first K/V tile direct-to-LDS; first rS to VGPR
  gload16(qwft + (((size_t)((i0 >> 4) + (sblk >> 1)) * 16) + h * 2 + (sblk & 1)) * 512 +
              (sln << 3),
          qwl + (tid << 3));
  stageKV(c * 32, 0);
  bf16x8 rsc[2][2];
  loadRS(c, rsc);
  if (tid < 32) { m_s[tid] = -INFINITY; l_s[tid] = 0.f; }
  barrier_all();

  // loop-invariant A fragments: q+rwb (from LDS) and q+rrb (direct global)
  bf16x8 aQ[2], aQR[2];
#pragma unroll
  for (int kt = 0; kt < 2; ++kt) {
    aQ[kt] = *(const bf16x8*)&qwl[(acit * 2 + kt) * 512 + (lane << 3)];
    aQR[kt] = *(const bf16x8*)&qrft[(((size_t)((i0 >> 4) + acit) * 16) +
                                    h * 2 + kt) * 512 + (lane << 3)];
  }

  f32x4 oA = (f32x4)(0.f);  // O^T accum, d-tile=wv, i = i0+lm
  f32x4 oB = (f32x4)(0.f);  // i = i0+16+lm

  int cur = 0;
  for (int jt = c; jt <= qt; jt += SPLIT) {
    const int j0 = jt * 32;
    if (jt + SPLIT <= qt) stageKV((jt + SPLIT) * 32, cur ^ 1);
    const int jn = (jt + SPLIT <= qt) ? jt + SPLIT : jt;
    bf16x8 rsn[2][2];
    loadRS(jn, rsn);

    {  // ---- phase B: AC + banded-QR MFMAs -> st = AC + BD ----
      f32x4 ac = (f32x4)(0.f), qa = (f32x4)(0.f), qb = (f32x4)(0.f);
#pragma unroll
      for (int kt = 0; kt < 2; ++kt) {
        bf16x8 b = *(const bf16x8*)&kl[cur][(acjt * 2 + kt) * 512 + (lane << 3)];
        ac = __builtin_amdgcn_mfma_f32_16x16x32_bf16(aQ[kt], b, ac, 0, 0, 0);
        qa = __builtin_amdgcn_mfma_f32_16x16x32_bf16(aQR[kt], rsc[0][kt], qa, 0, 0, 0);
        qb = __builtin_amdgcn_mfma_f32_16x16x32_bf16(aQR[kt], rsc[1][kt], qb, 0, 0, 0);
      }
      const bool diag = (jt == qt);
      const int thr = 16 * (1 + acit - acjt);
#pragma unroll
      for (int t = 0; t < 4; ++t) {
        // element (row quad*4+t, col lm) needs band index cw = col-row+32;
        // within this wave's pair: idx = cw - cqlo*16 = lm - (quad*4+t) + 16
        const int idx = lm - (quad * 4 + t) + 16;
        const int src = quad * 16 + (idx & 15);
        const float av = __shfl(qa[t], src);
        const float bv2 = __shfl(qb[t], src);
        float bd = (idx < 16) ? av : bv2;
        if (diag && idx > thr) bd = 0.f;  // j > i: BD replaced by mask/wrap
        st[acit * 16 + quad * 4 + t][acjt * 16 + lm] = ac[t] + bd;
      }
    }
    barrier_lds();

    {  // ---- phase C: score masking + online softmax ----
      float sreg[4];
      if (jt < qt) {  // fast path: all-causal tile, BD already in st
#pragma unroll
        for (int u = 0; u < 4; ++u) sreg[u] = st[ii][jjb + u] * ATT_SCALE;
      } else {  // diagonal tile: mask + mem-corner + wrap handling
#pragma unroll
        for (int u = 0; u < 4; ++u) {
          int j = j0 + jjb + u;
          float stv = st[ii][jjb + u];
          float s;
          if (j <= i) {
            s = stv * ATT_SCALE;
          } else {
            bool inmem = (i < NMTOK && j < NMTOK) ||
                         (i >= TT - NMTOK && j >= TT - NMTOK);
            if (!inmem) s = -1e30f;
            else if (j == i + 1) s = stv * ATT_SCALE;  // rel_shift zero-pad
            else s = (stv + bf2f(wrapv[hwr + (size_t)(i + 1) * 16 + (j - i - 2)])) *
                     ATT_SCALE;
          }
          sreg[u] = s;
        }
      }
      float tmax = fmaxf(fmaxf(sreg[0], sreg[1]), fmaxf(sreg[2], sreg[3]));
#pragma unroll
      for (int off = 1; off < 8; off <<= 1) tmax = fmaxf(tmax, __shfl_xor(tmax, off));
      const float mold = m_s[ii];
      const float mnew = fmaxf(mold, tmax);
      const float alpha = __expf(mold - mnew);
      float p[4], psum = 0.f;
#pragma unroll
      for (int u = 0; u < 4; ++u) { p[u] = __expf(sreg[u] - mnew); psum += p[u]; }
#pragma unroll
      for (int off = 1; off < 8; off <<= 1) psum += __shfl_xor(psum, off);
      uint2 pk;
      pk.x = pack2(f2bf(p[0]), f2bf(p[1]));
      pk.y = pack2(f2bf(p[2]), f2bf(p[3]));
      *(uint2*)&pbl[(size_t)(ii >> 4) * 512 + (g >> 1) * 128 + (ii & 15) * 8 +
                    (g & 1) * 4] = pk;
      if (g == 0) {
        m_s[ii] = mnew;
        l_s[ii] = l_s[ii] * alpha + psum;
        alpha_s[ii] = alpha;
      }
    }
    barrier_lds();

    {  // ---- phase D: O^T = O^T*alpha + V^T P^T ----
      float a0 = alpha_s[lm], a1 = alpha_s[16 + lm];
      bf16x8 av = *(const bf16x8*)&vtl[cur][wv * 512 + (lane << 3)];
      bf16x8 p0 = *(const bf16x8*)&pbl[(lane << 3)];
      bf16x8 p1 = *(const bf16x8*)&pbl[512 + (lane << 3)];
#pragma unroll
      for (int t = 0; t < 4; ++t) { oA[t] *= a0; oB[t] *= a1; }
      oA = __builtin_amdgcn_mfma_f32_16x16x32_bf16(av, p0, oA, 0, 0, 0);
      oB = __builtin_amdgcn_mfma_f32_16x16x32_bf16(av, p1, oB, 0, 0, 0);
    }
    barrier_all();  // retire prefetch + recycle buffers
    cur ^= 1;
#pragma unroll
    for (int f = 0; f < 2; ++f)
#pragma unroll
      for (int kt = 0; kt < 2; ++kt) rsc[f][kt] = rsn[f][kt];
  }

  {  // write partials: m, l (fp32) and un-normalized O (bf16, [i][d] layout)
    const int pidx = (qt * NH + h) * SPLIT + c;
    if (tid < 32) {
      mlP[(size_t)pidx * 64 + tid] = m_s[tid];
      mlP[(size_t)pidx * 64 + 32 + tid] = l_s[tid];
    }
    ushort_t o0[4], o1[4];
#pragma unroll
    for (int t = 0; t < 4; ++t) { o0[t] = f2bf(oA[t]); o1[t] = f2bf(oB[t]); }
    size_t ob = (size_t)pidx * 2048;
    *(uint2*)&opP[ob + (size_t)lm * 64 + wv * 16 + quad * 4] = *(uint2*)o0;
    *(uint2*)&opP[ob + (size_t)(16 + lm) * 64 + wv * 16 + quad * 4] = *(uint2*)o1;
  }
}

// -------- combine <=SPLIT chunk partials -> normalized attn output --------
// 1D grid with h = bid & 7: partials are read on the XCD that wrote them.
__global__ __launch_bounds__(256) void k_attn_combine(const float* __restrict__ mlP,
                                                      const ushort_t* __restrict__ opP,
                                                      ushort_t* __restrict__ attnb) {
  const int bid = blockIdx.x;
  const int h = bid & 7, qt = bid >> 3;
  const int nc = (qt + 1 < SPLIT) ? qt + 1 : SPLIT;
  const int tid = threadIdx.x;
  const int i = tid >> 3, d8 = (tid & 7) * 8;
  const size_t base = (size_t)(qt * NH + h) * SPLIT;
  float m[SPLIT], l[SPLIT], wgt[SPLIT];
  float M = -INFINITY;
  for (int cc = 0; cc < nc; ++cc) {
    m[cc] = mlP[(base + cc) * 64 + i];
    l[cc] = mlP[(base + cc) * 64 + 32 + i];
    M = fmaxf(M, m[cc]);
  }
  float L = 0.f;
  for (int cc = 0; cc < nc; ++cc) { wgt[cc] = __expf(m[cc] - M); L += l[cc] * wgt[cc]; }
  float acc[8] = {0, 0, 0, 0, 0, 0, 0, 0};
  for (int cc = 0; cc < nc; ++cc) {
    uint4 v = *(const uint4*)&opP[(base + cc) * 2048 + (size_t)i * 64 + d8];
    float f[8]; unpack8(v, f);
#pragma unroll
    for (int k = 0; k < 8; ++k) acc[k] += wgt[cc] * f[k];
  }
  const float inv = 1.f / L;
  ushort_t o8[8];
#pragma unroll
  for (int k = 0; k < 8; ++k) o8[k] = f2bf(acc[k] * inv);
  *(uint4*)&attnb[(size_t)(qt * 32 + i) * DM + h * DH + d8] = *(uint4*)o8;
}

// -------- w' = LayerNorm(w + sum(delta parts)) * g + b ---------------------
__global__ __launch_bounds__(256) void k_addln(const float* __restrict__ w,
                                               float* __restrict__ wout,
                                               ushort_t* __restrict__ wbft,
                                               const float* __restrict__ delta,
                                               int nparts,
                                               const float* __restrict__ gamma,
                                               const float* __restrict__ beta) {
  const int row = blockIdx.x;
  const int tid = threadIdx.x;
  __shared__ float red[4], red2[4];
  __shared__ float sm[512];
  size_t base = (size_t)row * DM;
  float x0 = w[base + tid];
  float x1 = w[base + tid + 256];
  for (int p = 0; p < nparts; ++p) {
    x0 += delta[(size_t)p * TT * DM + base + tid];
    x1 += delta[(size_t)p * TT * DM + base + tid + 256];
  }
  float s = x0 + x1;
#pragma unroll
  for (int off = 1; off < 64; off <<= 1) s += __shfl_xor(s, off);
  if ((tid & 63) == 0) red[tid >> 6] = s;
  __syncthreads();
  float mu = (red[0] + red[1] + red[2] + red[3]) * (1.f / 512.f);
  float d0 = x0 - mu, d1 = x1 - mu;
  float v = d0 * d0 + d1 * d1;
#pragma unroll
  for (int off = 1; off < 64; off <<= 1) v += __shfl_xor(v, off);
  if ((tid & 63) == 0) red2[tid >> 6] = v;
  __syncthreads();
  float var = (red2[0] + red2[1] + red2[2] + red2[3]) * (1.f / 512.f);
  float rstd = rsqrtf(var + 1e-5f);
  float o0 = d0 * rstd * gamma[tid] + beta[tid];
  float o1 = d1 * rstd * gamma[tid + 256] + beta[tid + 256];
  wout[base + tid] = o0;
  wout[base + tid + 256] = o1;
  sm[tid] = o0; sm[tid + 256] = o1;
  __syncthreads();
  if (tid < 64) {
    const int d8 = tid << 3;
    ushort_t t8[8];
#pragma unroll
    for (int e = 0; e < 8; ++e) t8[e] = f2bf(sm[d8 + e]);
    *(uint4*)&wbft[ft512(row, d8)] = *(uint4*)t8;
  }
}

extern "C" void kernel_launch(void* const* d_in, const int* in_sizes, int n_in,
                              void* d_out, int out_size, void* d_ws, size_t ws_size,
                              hipStream_t stream) {
  const float* we   = (const float*)d_in[0];
  const float* mem  = (const float*)d_in[1];
  const float* Wqkv = (const float*)d_in[2];
  const float* Wr   = (const float*)d_in[3];
  const float* Wo   = (const float*)d_in[4];
  const float* ln1s = (const float*)d_in[5];
  const float* ln1b = (const float*)d_in[6];
  const float* W1   = (const float*)d_in[7];
  const float* b1   = (const float*)d_in[8];
  const float* W2   = (const float*)d_in[9];
  const float* b2   = (const float*)d_in[10];
  const float* ln2s = (const float*)d_in[11];
  const float* ln2b = (const float*)d_in[12];
  const float* rwb  = (const float*)d_in[13];
  const float* rrb  = (const float*)d_in[14];

  // ---- workspace layout ----
  float* w     = (float*)d_ws;                        // TT*DM fp32
  float* proj  = w + (size_t)TT * DM;                 // TT*DM fp32 (Wo out)
  ushort_t* wbft  = (ushort_t*)(proj + (size_t)TT * DM);  // TT*DM bf16 (FT)
  ushort_t* posft = wbft + (size_t)TT * DM;           // TT*DM bf16 (FT)
  ushort_t* attnb = posft + (size_t)TT * DM;          // TT*DM bf16 (rm)
  ushort_t* qkvB  = attnb + (size_t)TT * DM;          // q/k/v FT region
  ushort_t* qwft  = qkvB;                             // TT*DM (Q+rwb, FT)
  ushort_t* kft   = qkvB + (size_t)TT * DM;           // TT*DM (K, FT)
  ushort_t* vtft  = qkvB + (size_t)2 * TT * DM;       // DM*TT (V^T, FT)
  // + TT*DM reserved gap (ff1ft overlay tail)
  ushort_t* WtAll = qkvB + (size_t)TT * QKV_N + (size_t)TT * DM;
  ushort_t* opP   = WtAll + (size_t)NLAYER * WT_STRIDE;  // 65*8*SPLIT*2048
  float* mlP   = (float*)(opP + (size_t)65 * 8 * SPLIT * 2048);  // 65*8*SPLIT*64 f32
  ushort_t* qrft  = (ushort_t*)(mlP + (size_t)65 * 8 * SPLIT * 64);  // TT*DM (FT)
  ushort_t* rsft  = qrft + (size_t)TT * DM;           // RSFT_ROWS/16 * 16*512 shorts
  ushort_t* wrapv = rsft + (size_t)(RSFT_ROWS / 16) * 16 * 512;  // NH*TT*16
  ushort_t* r16   = wrapv + (size_t)NH * TT * 16;     // 16*512
  // overlays (time-shared, stream-ordered):
  ushort_t* ff1ft = qkvB;            // FT TT*DI bf16 spans qkv region + gap
  float* ff2p  = (float*)opP;        // 4 split-K partials, 4*TT*DM f32
  const size_t OFF_QKVT = 0, OFF_WRT = 786432, OFF_WOT = 1048576,
               OFF_W1T = 1310720, OFF_W2T = 2359296;

  // all-layer weight transpose(+FT pack) + build in one dispatch
  k_prep<<<13312 + 4160, 256, 0, stream>>>(Wqkv, Wr, Wo, W1, W2, WtAll,
                                           we, mem, w, wbft, posft);

  dim3 gQW(16, 33);          // merged QKV (12 n-tiles) + Wr (4 n-tiles), 64x128
  dim3 gW1(16, 33);          // FFN1 64x128
  dim3 gW2(4, 33, 4);        // FFN2 64x128, split-K=4
  dim3 gDM32(DM / 64, 65);   // Wo (old 32x64 kernel)

  for (int l = 0; l < NLAYER; ++l) {
    const ushort_t* Wt = WtAll + (size_t)l * WT_STRIDE;
    k_gemm_qkvwr_ft<<<gQW, 256, 0, stream>>>(wbft, posft, Wt + OFF_QKVT,
                                             Wt + OFF_WRT, qwft, kft, vtft,
                                             rsft, r16, qrft, rwb, rrb);
    k_wrap<<<65 * NH, 256, 0, stream>>>(qrft, r16, wrapv);
    k_attn<<<65 * NH * SPLIT, 256, 0, stream>>>(qwft, qrft, kft, vtft, rsft,
                                                wrapv, mlP, opP);
    k_attn_combine<<<65 * NH, 256, 0, stream>>>(mlP, opP, attnb);
    k_gemm_mfma<<<gDM32, 256, 0, stream>>>(attnb, Wt + OFF_WOT, nullptr, proj, nullptr,
                                           DM, DM, 0);
    k_addln<<<TT, 256, 0, stream>>>(w, w, wbft, proj, 1,
                                    ln1s + (size_t)l * DM, ln1b + (size_t)l * DM);
    k_ffn1_ft<<<gW1, 256, 0, stream>>>(wbft, Wt + OFF_W1T, b1 + (size_t)l * DI, ff1ft);
    k_ffn2_ft<<<gW2, 256, 0, stream>>>(ff1ft, Wt + OFF_W2T, b2 + (size_t)l * DM, ff2p);
    float* wout = (l == NLAYER - 1) ? (float*)d_out : w;
    k_addln<<<TT, 256, 0, stream>>>(w, wout, wbft, ff2p, 4,
                                    ln2s + (size_t)l * DM, ln2b + (size_t)l * DM);
  }
}

// Round 12
// 597.626 us; speedup vs baseline: 1.1314x; 1.0054x over previous
//
#include <hip/hip_runtime.h>
#include <hip/hip_bf16.h>
#include <math.h>
#include <stdint.h>

#define TT 2080
#define DM 512
#define DI 2048
#define NH 8
#define DH 64
#define NMTOK 16
#define NLAYER 4
#define QKV_N 1536
#define ATT_SCALE 0.125f
#define SPLIT 8
#define WT_STRIDE 3407872   // shorts per layer's transposed-weight block
#define RSFT_ROWS 2112      // shifted-r FT rows (132 blocks of 16)

typedef short bf16x8 __attribute__((ext_vector_type(8)));
typedef float f32x4 __attribute__((ext_vector_type(4)));
typedef unsigned short ushort_t;

__device__ __forceinline__ ushort_t f2bf(float f) {
  __hip_bfloat16 h = __float2bfloat16(f);
  return *reinterpret_cast<ushort_t*>(&h);
}
__device__ __forceinline__ float bfbits2f(unsigned int hi_bits) {
  return __uint_as_float(hi_bits);
}
__device__ __forceinline__ float bf2f(ushort_t u) {
  return bfbits2f(((unsigned int)u) << 16);
}
__device__ __forceinline__ void unpack8(uint4 v, float* f) {
  f[0] = bfbits2f(v.x << 16); f[1] = bfbits2f(v.x & 0xffff0000u);
  f[2] = bfbits2f(v.y << 16); f[3] = bfbits2f(v.y & 0xffff0000u);
  f[4] = bfbits2f(v.z << 16); f[5] = bfbits2f(v.z & 0xffff0000u);
  f[6] = bfbits2f(v.w << 16); f[7] = bfbits2f(v.w & 0xffff0000u);
}
__device__ __forceinline__ unsigned int pack2(ushort_t lo, ushort_t hi) {
  return (unsigned int)lo | ((unsigned int)hi << 16);
}
// Barrier draining LDS ops only — leaves global (vmcnt) loads in flight.
__device__ __forceinline__ void barrier_lds() {
  asm volatile("s_waitcnt lgkmcnt(0)" ::: "memory");
  __builtin_amdgcn_s_barrier();
}
// Barrier draining everything (used to retire global_load_lds prefetches).
__device__ __forceinline__ void barrier_all() {
  asm volatile("s_waitcnt vmcnt(0) lgkmcnt(0)" ::: "memory");
  __builtin_amdgcn_s_barrier();
}
// Counted drain: waits the OLDEST outstanding vmem ops down to 4 — retires
// the 2 stageKV gload_lds (issued first in the iteration) while leaving the
// 4 rs prefetch loads (issued after, needed only next iteration) in flight.
__device__ __forceinline__ void barrier_vm4() {
  asm volatile("s_waitcnt vmcnt(4) lgkmcnt(0)" ::: "memory");
  __builtin_amdgcn_s_barrier();
}
// global -> LDS direct copy, 16B per lane. LDS dest must be wave-uniform
// base + lane*16 (contract of global_load_lds).
__device__ __forceinline__ void gload16(const ushort_t* g, ushort_t* l) {
  __builtin_amdgcn_global_load_lds(
      (__attribute__((address_space(1))) void*)(uintptr_t)g,
      (__attribute__((address_space(3))) void*)(uintptr_t)l, 16, 0, 0);
}
// ---- fragment-tiled (FT) layout --------------------------------------------
// Matrix X[R][K] (bf16) stored as 1024B blocks of (16 r x 32 k); lane
// = ((k>>3)&3)*16 + (r&15) holds 8 consecutive k-elements = EXACTLY the
// mfma_f32_16x16x32_bf16 A/B fragment order.
__device__ __forceinline__ size_t ft512(int r, int c) {  // K = 512 (KT = 16)
  return (((size_t)(r >> 4) * 16 + (c >> 5)) << 9) + (((c >> 3) & 3) << 7) +
         ((r & 15) << 3) + (c & 7);
}

// ---- fused prep: all 4 layers' weight transposes + build w/pos ------------
__global__ __launch_bounds__(256) void k_prep(
    const float* __restrict__ Wqkv, const float* __restrict__ Wr,
    const float* __restrict__ Wo, const float* __restrict__ W1,
    const float* __restrict__ W2, ushort_t* __restrict__ dstAll,
    const float* __restrict__ we, const float* __restrict__ mem,
    float* __restrict__ w, ushort_t* __restrict__ wbft,
    ushort_t* __restrict__ posft) {
  const int tid = threadIdx.x;
  if (blockIdx.x >= 13312) {  // ---- build ----
    int idx = (blockIdx.x - 13312) * 256 + tid;
    if (idx >= TT * DM) return;
    int t = idx >> 9, d = idx & 511;
    float v;
    if (t < NMTOK) v = mem[t * DM + d];
    else if (t < NMTOK + 2048) v = we[(t - NMTOK) * DM + d];
    else v = mem[(t - (NMTOK + 2048)) * DM + d];
    w[idx] = v;
    wbft[ft512(t, d)] = f2bf(v);
    float p = (float)(TT - 1 - t);
    int i2 = d & 255;
    float freq = __expf(-0.035977892f * (float)i2);
    float ang = p * freq;
    posft[ft512(t, d)] = f2bf((d < 256) ? __sinf(ang) : __cosf(ang));
    return;
  }
  // ---- transpose+cast, layer l ----
  __shared__ float tl[32][33];
  const int l = blockIdx.x / 3328;
  int idx = blockIdx.x % 3328;
  const float* src;
  ushort_t* dst = dstAll + (size_t)l * WT_STRIDE;
  int K, N, local;
  bool isFT = true;
  if (idx < 768)       { src = Wqkv + (size_t)l * 512 * 1536; K = 512;  N = 1536; local = idx; }
  else if (idx < 1024) { src = Wr   + (size_t)l * 512 * 512;  dst += 786432;  K = 512;  N = 512;  local = idx - 768; }
  else if (idx < 1280) { src = Wo   + (size_t)l * 512 * 512;  dst += 1048576; K = 512;  N = 512;  local = idx - 1024; isFT = false; }
  else if (idx < 2304) { src = W1   + (size_t)l * 512 * 2048; dst += 1310720; K = 512;  N = 2048; local = idx - 1280; }
  else                 { src = W2   + (size_t)l * 2048 * 512; dst += 2359296; K = 2048; N = 512;  local = idx - 2304; }
  const int ntiles = N / 32;
  const int n0 = (local % ntiles) * 32, k0 = (local / ntiles) * 32;
#pragma unroll
  for (int p = 0; p < 4; ++p) {
    int row = (tid >> 5) + 8 * p, col = tid & 31;
    tl[row][col] = src[(size_t)(k0 + row) * N + n0 + col];  // tl[k][n]
  }
  __syncthreads();
  if (isFT) {
    if (tid < 128) {
      int b = tid >> 6, l2 = tid & 63;
      int nn = b * 16 + (l2 & 15);
      int kq = (l2 >> 4) * 8;
      ushort_t t8[8];
#pragma unroll
      for (int e = 0; e < 8; ++e) t8[e] = f2bf(tl[kq + e][nn]);
      size_t ad = (((size_t)((n0 >> 4) + b) * (K >> 5) + (k0 >> 5)) << 9) +
                  ((size_t)l2 << 3);
      *(uint4*)&dst[ad] = *(uint4*)t8;
    }
  } else {
#pragma unroll
    for (int p = 0; p < 4; ++p) {
      int n = (tid >> 5) + 8 * p, k = tid & 31;
      dst[(size_t)(n0 + n) * K + k0 + k] = f2bf(tl[k][n]);
    }
  }
}

// -------- bf16 MFMA GEMM body, 32x64 tile, register prefetch (Wo only) ----
__device__ __forceinline__ void gemm32x64_body(const ushort_t* __restrict__ A,
                                               const ushort_t* __restrict__ Bt,
                                               const float* __restrict__ bias,
                                               float* __restrict__ C,
                                               ushort_t* __restrict__ Cb,
                                               int N, int K, int flags,
                                               int m0, int n0) {
  __shared__ short As[32][72];
  __shared__ short Bs[64][72];
  const int tid = threadIdx.x;
  const int lane = tid & 63, wv = tid >> 6;
  const int wm = (wv >> 1) * 16, wn = (wv & 1) * 32;
  const int lm = lane & 15, quad = lane >> 4;
  const int sr = tid >> 3, sc8 = (tid & 7) * 8;

  f32x4 acc[2];
  acc[0] = (f32x4)(0.f); acc[1] = (f32x4)(0.f);

  auto loadA = [&](int k0) -> uint4 {
    return *(const uint4*)&A[(size_t)(m0 + sr) * K + k0 + sc8];
  };
  auto loadB = [&](int row, int k0) -> uint4 {
    return *(const uint4*)&Bt[(size_t)(n0 + row) * K + k0 + sc8];
  };

  uint4 aC = loadA(0), b0C = loadB(sr, 0), b1C = loadB(sr + 32, 0);

  for (int k0 = 0; k0 < K; k0 += 64) {
    const int kn = (k0 + 64 < K) ? k0 + 64 : k0;  // clamped tail reload
    uint4 aN = loadA(kn), b0N = loadB(sr, kn), b1N = loadB(sr + 32, kn);
    barrier_lds();  // prev ds_reads done; vm prefetches stay in flight
    *(uint4*)&As[sr][sc8] = aC;
    *(uint4*)&Bs[sr][sc8] = b0C;
    *(uint4*)&Bs[sr + 32][sc8] = b1C;
    barrier_lds();
#pragma unroll
    for (int kk = 0; kk < 64; kk += 32) {
      bf16x8 a = *(const bf16x8*)&As[wm + lm][kk + quad * 8];
      bf16x8 b0 = *(const bf16x8*)&Bs[wn + lm][kk + quad * 8];
      bf16x8 b1 = *(const bf16x8*)&Bs[wn + 16 + lm][kk + quad * 8];
      acc[0] = __builtin_amdgcn_mfma_f32_16x16x32_bf16(a, b0, acc[0], 0, 0, 0);
      acc[1] = __builtin_amdgcn_mfma_f32_16x16x32_bf16(a, b1, acc[1], 0, 0, 0);
    }
    aC = aN; b0C = b0N; b1C = b1N;
  }
#pragma unroll
  for (int nt = 0; nt < 2; ++nt) {
    int col = n0 + wn + nt * 16 + lm;
    float bv = (flags & 1) ? bias[col] : 0.f;
#pragma unroll
    for (int t = 0; t < 4; ++t) {
      int row = m0 + wm + quad * 4 + t;
      float v = acc[nt][t] + bv;
      if (flags & 2) v = fmaxf(v, 0.f);
      if (flags & 4) Cb[(size_t)row * N + col] = f2bf(v);
      else C[(size_t)row * N + col] = v;
    }
  }
}

__global__ __launch_bounds__(256) void k_gemm_mfma(const ushort_t* __restrict__ A,
                                                   const ushort_t* __restrict__ Bt,
                                                   const float* __restrict__ bias,
                                                   float* __restrict__ C,
                                                   ushort_t* __restrict__ Cb,
                                                   int N, int K, int flags) {
  gemm32x64_body(A, Bt, bias, C, Cb, N, K, flags, blockIdx.y * 32, blockIdx.x * 64);
}

// -------- FT GEMM: 64x128 tile, 4 waves x (32x64), global_load_lds staging,
// conflict-free fragment ds_reads, double-buffered (2 x 24KB LDS).
// flags: 1=+bias, 2=relu. omode: 0=fp32 rm, 1=bf16 rm, 2=FT(cftKT),
// 3=q(qwft=v+rwb FT; aux=qrft=v+rrb FT), 4=k(kft FT, col-512),
// 5=v(vtft V^T FT), 6=r(rsft FT shifted +1 row; aux=r16 rm for row<16).
__device__ __forceinline__ void gemm_ft_body(
    ushort_t* smem, const ushort_t* __restrict__ A, const ushort_t* __restrict__ Bt,
    const float* __restrict__ bias, int N, int K, int kBeg, int kEnd,
    int m0, int n0, int flags, int omode,
    float* __restrict__ Cf, ushort_t* __restrict__ Cb, int cftKT,
    ushort_t* __restrict__ aux, const float* __restrict__ rwb,
    const float* __restrict__ rrb) {
  const int tid = threadIdx.x;
  const int lane = tid & 63, wv = tid >> 6;
  const int wm = (wv >> 1) * 32, wn = (wv & 1) * 64;
  const int lm = lane & 15, quad = lane >> 4;
  const int AKT = K >> 5;                 // global k-tiles per 16-row block
  const int mt0 = m0 >> 4, nt0 = n0 >> 4;
  const int kt0 = kBeg >> 5;

  f32x4 acc[2][4];
#pragma unroll
  for (int i = 0; i < 2; ++i)
#pragma unroll
    for (int j = 0; j < 4; ++j) acc[i][j] = (f32x4)(0.f);

  auto stage = [&](ushort_t* dA, int ktg) {
    ushort_t* dB = dA + 4096;
#pragma unroll
    for (int it = 0; it < 6; ++it) {
      const int c = (it << 8) + tid;
      if (it < 2) {  // A chunks: c in [0,512)
        const int blk = c >> 6, ln = c & 63;
        gload16(A + (((size_t)(mt0 + (blk >> 1)) * AKT + ktg + (blk & 1)) << 9) + (ln << 3),
                dA + (c << 3));
      } else {       // B chunks: cB in [0,1024)
        const int cB = c - 512;
        const int blk = cB >> 6, ln = cB & 63;
        gload16(Bt + (((size_t)(nt0 + (blk >> 1)) * AKT + ktg + (blk & 1)) << 9) + (ln << 3),
                dB + (cB << 3));
      }
    }
  };
  auto compute = [&](const ushort_t* dA) {
    const ushort_t* dB = dA + 4096;
#pragma unroll
    for (int kk = 0; kk < 2; ++kk) {
      bf16x8 a[2], b[4];
#pragma unroll
      for (int i = 0; i < 2; ++i)
        a[i] = *(const bf16x8*)&dA[((((wm >> 4) + i) << 1) + kk) * 512 + (lane << 3)];
#pragma unroll
      for (int j = 0; j < 4; ++j)
        b[j] = *(const bf16x8*)&dB[((((wn >> 4) + j) << 1) + kk) * 512 + (lane << 3)];
#pragma unroll
      for (int i = 0; i < 2; ++i)
#pragma unroll
        for (int j = 0; j < 4; ++j)
          acc[i][j] = __builtin_amdgcn_mfma_f32_16x16x32_bf16(a[i], b[j], acc[i][j], 0, 0, 0);
    }
  };

  const int nIter = (kEnd - kBeg) >> 6;  // always even (8) here
  stage(smem, kt0);
  __syncthreads();
  for (int t = 0; t < nIter; t += 2) {
    if (t + 1 < nIter) stage(smem + 12288, kt0 + (t + 1) * 2);
    compute(smem);
    __syncthreads();
    if (t + 2 < nIter) stage(smem, kt0 + (t + 2) * 2);
    compute(smem + 12288);
    __syncthreads();
  }

#pragma unroll
  for (int i = 0; i < 2; ++i) {
    const int rowb = m0 + wm + i * 16 + quad * 4;
#pragma unroll
    for (int j = 0; j < 4; ++j) {
      const int col = n0 + wn + j * 16 + lm;
      const float bv = (flags & 1) ? bias[col] : 0.f;
#pragma unroll
      for (int t2 = 0; t2 < 4; ++t2) {
        const int row = rowb + t2;
        float v = acc[i][j][t2] + bv;
        if (flags & 2) v = fmaxf(v, 0.f);
        if (omode == 0) {
          Cf[(size_t)row * N + col] = v;
        } else if (omode == 1) {
          Cb[(size_t)row * N + col] = f2bf(v);
        } else if (omode == 2) {
          Cb[(((size_t)(row >> 4) * cftKT + (col >> 5)) << 9) +
             (((col >> 3) & 3) << 7) + ((row & 15) << 3) + (col & 7)] = f2bf(v);
        } else if (omode == 3) {
          Cb[ft512(row, col)] = f2bf(v + rwb[col]);
          aux[ft512(row, col)] = f2bf(v + rrb[col]);
        } else if (omode == 4) {
          Cb[ft512(row, col - 512)] = f2bf(v);
        } else if (omode == 5) {  // V^T FT, r = v-dim, c = token
          const int dv = col - 1024;
          Cb[((size_t)(dv >> 4) * 65 + (row >> 5)) * 512 +
             (((row >> 3) & 3) << 7) + ((dv & 15) << 3) + (row & 7)] = f2bf(v);
        } else {  // omode 6: shifted r (rsft[k] = r[k-1]) + r16 head rows
          Cb[ft512(row + 1, col)] = f2bf(v);
          if (row < 16) aux[(size_t)row * 512 + col] = f2bf(v);
        }
      }
    }
  }
}

// merged QKV + Wr GEMMs (FT); q -> qwft(+rwb) & qrft(+rrb); k -> kft;
// v -> vtft (V^T FT); Wr -> rsft (shifted FT) + r16
__global__ __launch_bounds__(256) void k_gemm_qkvwr_ft(
    const ushort_t* __restrict__ wbft, const ushort_t* __restrict__ posft,
    const ushort_t* __restrict__ qkvT, const ushort_t* __restrict__ wrT,
    ushort_t* __restrict__ qwft, ushort_t* __restrict__ kft,
    ushort_t* __restrict__ vtft, ushort_t* __restrict__ rsft,
    ushort_t* __restrict__ r16, ushort_t* __restrict__ qrft,
    const float* __restrict__ rwb, const float* __restrict__ rrb) {
  __shared__ ushort_t smem[24576];
  int m0 = blockIdx.y * 64;
  if (m0 + 64 > TT) m0 = TT - 64;  // overlapped last tile (dup writes benign)
  const int bx = blockIdx.x;
  if (bx < 12) {
    const int om = (bx < 4) ? 3 : (bx < 8 ? 4 : 5);
    ushort_t* dst = (om == 3) ? qwft : (om == 4) ? kft : vtft;
    gemm_ft_body(smem, wbft, qkvT, nullptr, QKV_N, DM, 0, DM, m0, bx * 128,
                 0, om, nullptr, dst, 0, (om == 3) ? qrft : nullptr, rwb, rrb);
  } else {
    gemm_ft_body(smem, posft, wrT, nullptr, DM, DM, 0, DM, m0, (bx - 12) * 128,
                 0, 6, nullptr, rsft, 0, r16, nullptr, nullptr);
  }
}

// FFN1: wbft x w1T -> ff1ft (FT, K_out = DI), bias+relu
__global__ __launch_bounds__(256) void k_ffn1_ft(const ushort_t* __restrict__ wbft,
                                                 const ushort_t* __restrict__ w1T,
                                                 const float* __restrict__ b1l,
                                                 ushort_t* __restrict__ ff1ft) {
  __shared__ ushort_t smem[24576];
  int m0 = blockIdx.y * 64;
  if (m0 + 64 > TT) m0 = TT - 64;
  gemm_ft_body(smem, wbft, w1T, b1l, DI, DM, 0, DM, m0, blockIdx.x * 128,
               1 | 2, 2, nullptr, ff1ft, DI >> 5, nullptr, nullptr, nullptr);
}

// FFN2: ff1ft x w2T -> fp32 partials (split-K=4); bias folded into split 0
__global__ __launch_bounds__(256) void k_ffn2_ft(const ushort_t* __restrict__ ff1ft,
                                                 const ushort_t* __restrict__ w2T,
                                                 const float* __restrict__ b2l,
                                                 float* __restrict__ ff2p) {
  __shared__ ushort_t smem[24576];
  int m0 = blockIdx.y * 64;
  if (m0 + 64 > TT) m0 = TT - 64;
  const int s = blockIdx.z;
  gemm_ft_body(smem, ff1ft, w2T, b2l, DM, DI, s * 512, s * 512 + 512, m0,
               blockIdx.x * 128, (s == 0) ? 1 : 0, 0,
               ff2p + (size_t)s * TT * DM, nullptr, 0, nullptr, nullptr, nullptr);
}

// ---- wrap values: wrapv[h][row][w<16] = qr_row(h) . r_w(h) ---------------
// 1D grid, h = bid & 7 -> head h lands on XCD h (L2 affinity).
__global__ __launch_bounds__(256) void k_wrap(const ushort_t* __restrict__ qrft,
                                              const ushort_t* __restrict__ r16,
                                              ushort_t* __restrict__ wrapv) {
  const int bid = blockIdx.x;
  const int h = bid & 7;
  const int row = (bid >> 3) * 32 + (threadIdx.x >> 3);
  const int w = threadIdx.x & 7;
  float a0 = 0.f, a1 = 0.f;
#pragma unroll
  for (int d8 = 0; d8 < 64; d8 += 8) {
    bf16x8 qv = *(const bf16x8*)&qrft[ft512(row, h * DH + d8)];
    bf16x8 r0 = *(const bf16x8*)&r16[(size_t)w * 512 + h * DH + d8];
    bf16x8 r1 = *(const bf16x8*)&r16[(size_t)(w + 8) * 512 + h * DH + d8];
#pragma unroll
    for (int e = 0; e < 8; ++e) {
      float q = bf2f((ushort_t)qv[e]);
      a0 += q * bf2f((ushort_t)r0[e]);
      a1 += q * bf2f((ushort_t)r1[e]);
    }
  }
  const size_t b = (size_t)h * TT * 16 + (size_t)row * 16;
  wrapv[b + w] = f2bf(a0);
  wrapv[b + w + 8] = f2bf(a1);
}

// ------- MFMA flash attention, KVBLK=32, split-j, FT-staged Q/K/V^T -------
// Round-11 structure + two occupancy/latency fixes:
//  (a) qwl aliased onto vtl[1] (Q read once in prologue, fenced by an extra
//      barrier before vtl[1]'s first write) -> LDS 27.6KB -> 22.6KB.
//  (b) counted vmcnt(4) at iteration end: retires the 2 stage gloads (oldest)
//      while the 4 rs prefetch loads (younger, needed next iter) stay in
//      flight. Order pinned: stageKV builtins -> sched_barrier(0) -> rs loads;
//      "memory"-clobbered waits keep loads from crossing barriers. The
//      diagonal (wrap-reading) iteration is always last => no stage pending.
__global__ __launch_bounds__(256) void k_attn(const ushort_t* __restrict__ qwft,
                                              const ushort_t* __restrict__ qrft,
                                              const ushort_t* __restrict__ kft,
                                              const ushort_t* __restrict__ vtft,
                                              const ushort_t* __restrict__ rsft,
                                              const ushort_t* __restrict__ wrapv,
                                              float* __restrict__ mlP,
                                              ushort_t* __restrict__ opP) {
  const int bid = blockIdx.x;
  const int h = bid & 7;            // head == XCD (bid % 8 round-robin)
  const int rest = bid >> 3;
  const int qt = 64 - rest % 65;    // heavy q-tiles dispatch first
  const int c = rest / 65;
  if (c > qt) return;  // empty chunk
  const int i0 = qt * 32;
  const int tid = threadIdx.x;
  const int lane = tid & 63, wv = tid >> 6;
  const int lm = lane & 15, quad = lane >> 4;

  __shared__ ushort_t kl[2][2048];   // K dbuf, 4 FT blocks [jt][kt]
  __shared__ ushort_t vtl[2][2048];  // V^T dbuf, 4 FT blocks [dt]
  __shared__ ushort_t pbl[1024];     // P bf16, 2 FT blocks [it]
  __shared__ float st[32][34];       // AC+BD fp32 [i][j] (+2 pad)
  __shared__ float m_s[32], l_s[32], alpha_s[32];
  ushort_t* qwl = vtl[1];  // alias: read only in prologue, before first write

  const int ii = tid >> 3, g = tid & 7, jjb = g * 4;
  const int i = i0 + ii;
  const size_t hwr = (size_t)h * TT * 16;

  const int sblk = tid >> 6, sln = tid & 63;
  auto stageKV = [&](int j0, int buf) {
    gload16(kft + (((size_t)((j0 >> 4) + (sblk >> 1)) * 16) + h * 2 + (sblk & 1)) * 512 +
                (sln << 3),
            kl[buf] + (tid << 3));
    gload16(vtft + (((size_t)(h * 4 + sblk)) * 65 + (j0 >> 5)) * 512 + (sln << 3),
            vtl[buf] + (tid << 3));
  };

  // per-wave quadrant + its banded-QR column pair
  const int acit = wv >> 1, acjt = wv & 1;
  const int cqlo = 1 + acjt - acit;  // needed QRb col-blocks {cqlo, cqlo+1}
  auto loadRS = [&](int jt2, bf16x8 (&rs)[2][2]) {
    const int wbp4 = 128 - 2 * (qt - jt2);  // rS window base block
#pragma unroll
    for (int f = 0; f < 2; ++f)
#pragma unroll
      for (int kt = 0; kt < 2; ++kt)
        rs[f][kt] = *(const bf16x8*)&rsft[(((size_t)(wbp4 + cqlo + f) * 16) +
                                          h * 2 + kt) * 512 + (lane << 3)];
  };

  // prologue: Q tile (into aliased qwl) + first K/V tile; first rS to VGPR
  gload16(qwft + (((size_t)((i0 >> 4) + (sblk >> 1)) * 16) + h * 2 + (sblk & 1)) * 512 +
              (sln << 3),
          qwl + (tid << 3));
  stageKV(c * 32, 0);
  bf16x8 rsc[2][2];
  loadRS(c, rsc);
  if (tid < 32) { m_s[tid] = -INFINITY; l_s[tid] = 0.f; }
  barrier_all();

  // loop-invariant A fragments: q+rwb (from aliased LDS) and q+rrb (global)
  bf16x8 aQ[2], aQR[2];
#pragma unroll
  for (int kt = 0; kt < 2; ++kt) {
    aQ[kt] = *(const bf16x8*)&qwl[(acit * 2 + kt) * 512 + (lane << 3)];
    aQR[kt] = *(const bf16x8*)&qrft[(((size_t)((i0 >> 4) + acit) * 16) +
                                    h * 2 + kt) * 512 + (lane << 3)];
  }
  barrier_lds();  // all waves' qwl reads retired before vtl[1] is overwritten

  f32x4 oA = (f32x4)(0.f);  // O^T accum, d-tile=wv, i = i0+lm
  f32x4 oB = (f32x4)(0.f);  // i = i0+16+lm

  int cur = 0;
  for (int jt = c; jt <= qt; jt += SPLIT) {
    const int j0 = jt * 32;
    const bool hasNext = (jt + SPLIT <= qt);
    if (hasNext) stageKV((jt + SPLIT) * 32, cur ^ 1);
    __builtin_amdgcn_sched_barrier(0);  // pin: stage gloads precede rs loads
    const int jn = hasNext ? jt + SPLIT : jt;
    bf16x8 rsn[2][2];
    loadRS(jn, rsn);

    {  // ---- phase B: AC + banded-QR MFMAs -> st = AC + BD ----
      f32x4 ac = (f32x4)(0.f), qa = (f32x4)(0.f), qb = (f32x4)(0.f);
#pragma unroll
      for (int kt = 0; kt < 2; ++kt) {
        bf16x8 b = *(const bf16x8*)&kl[cur][(acjt * 2 + kt) * 512 + (lane << 3)];
        ac = __builtin_amdgcn_mfma_f32_16x16x32_bf16(aQ[kt], b, ac, 0, 0, 0);
        qa = __builtin_amdgcn_mfma_f32_16x16x32_bf16(aQR[kt], rsc[0][kt], qa, 0, 0, 0);
        qb = __builtin_amdgcn_mfma_f32_16x16x32_bf16(aQR[kt], rsc[1][kt], qb, 0, 0, 0);
      }
      const bool diag = (jt == qt);
      const int thr = 16 * (1 + acit - acjt);
#pragma unroll
      for (int t = 0; t < 4; ++t) {
        // element (row quad*4+t, col lm) needs band index cw = col-row+32;
        // within this wave's pair: idx = cw - cqlo*16 = lm - (quad*4+t) + 16
        const int idx = lm - (quad * 4 + t) + 16;
        const int src = quad * 16 + (idx & 15);
        const float av = __shfl(qa[t], src);
        const float bv2 = __shfl(qb[t], src);
        float bd = (idx < 16) ? av : bv2;
        if (diag && idx > thr) bd = 0.f;  // j > i: BD replaced by mask/wrap
        st[acit * 16 + quad * 4 + t][acjt * 16 + lm] = ac[t] + bd;
      }
    }
    barrier_lds();

    {  // ---- phase C: score masking + online softmax ----
      float sreg[4];
      if (jt < qt) {  // fast path: all-causal tile, BD already in st
#pragma unroll
        for (int u = 0; u < 4; ++u) sreg[u] = st[ii][jjb + u] * ATT_SCALE;
      } else {  // diagonal tile: mask + mem-corner + wrap handling
#pragma unroll
        for (int u = 0; u < 4; ++u) {
          int j = j0 + jjb + u;
          float stv = st[ii][jjb + u];
          float s;
          if (j <= i) {
            s = stv * ATT_SCALE;
          } else {
            bool inmem = (i < NMTOK && j < NMTOK) ||
                         (i >= TT - NMTOK && j >= TT - NMTOK);
            if (!inmem) s = -1e30f;
            else if (j == i + 1) s = stv * ATT_SCALE;  // rel_shift zero-pad
            else s = (stv + bf2f(wrapv[hwr + (size_t)(i + 1) * 16 + (j - i - 2)])) *
                     ATT_SCALE;
          }
          sreg[u] = s;
        }
      }
      float tmax = fmaxf(fmaxf(sreg[0], sreg[1]), fmaxf(sreg[2], sreg[3]));
#pragma unroll
      for (int off = 1; off < 8; off <<= 1) tmax = fmaxf(tmax, __shfl_xor(tmax, off));
      const float mold = m_s[ii];
      const float mnew = fmaxf(mold, tmax);
      const float alpha = __expf(mold - mnew);
      float p[4], psum = 0.f;
#pragma unroll
      for (int u = 0; u < 4; ++u) { p[u] = __expf(sreg[u] - mnew); psum += p[u]; }
#pragma unroll
      for (int off = 1; off < 8; off <<= 1) psum += __shfl_xor(psum, off);
      uint2 pk;
      pk.x = pack2(f2bf(p[0]), f2bf(p[1]));
      pk.y = pack2(f2bf(p[2]), f2bf(p[3]));
      *(uint2*)&pbl[(size_t)(ii >> 4) * 512 + (g >> 1) * 128 + (ii & 15) * 8 +
                    (g & 1) * 4] = pk;
      if (g == 0) {
        m_s[ii] = mnew;
        l_s[ii] = l_s[ii] * alpha + psum;
        alpha_s[ii] = alpha;
      }
    }
    barrier_lds();

    {  // ---- phase D: O^T = O^T*alpha + V^T P^T ----
      float a0 = alpha_s[lm], a1 = alpha_s[16 + lm];
      bf16x8 av = *(const bf16x8*)&vtl[cur][wv * 512 + (lane << 3)];
      bf16x8 p0 = *(const bf16x8*)&pbl[(lane << 3)];
      bf16x8 p1 = *(const bf16x8*)&pbl[512 + (lane << 3)];
#pragma unroll
      for (int t = 0; t < 4; ++t) { oA[t] *= a0; oB[t] *= a1; }
      oA = __builtin_amdgcn_mfma_f32_16x16x32_bf16(av, p0, oA, 0, 0, 0);
      oB = __builtin_amdgcn_mfma_f32_16x16x32_bf16(av, p1, oB, 0, 0, 0);
    }
    barrier_vm4();  // retire stage gloads (oldest 2); rs loads stay in flight
    cur ^= 1;
#pragma unroll
    for (int f = 0; f < 2; ++f)
#pragma unroll
      for (int kt = 0; kt < 2; ++kt) rsc[f][kt] = rsn[f][kt];
  }

  {  // write partials: m, l (fp32) and un-normalized O (bf16, [i][d] layout)
    const int pidx = (qt * NH + h) * SPLIT + c;
    if (tid < 32) {
      mlP[(size_t)pidx * 64 + tid] = m_s[tid];
      mlP[(size_t)pidx * 64 + 32 + tid] = l_s[tid];
    }
    ushort_t o0[4], o1[4];
#pragma unroll
    for (int t = 0; t < 4; ++t) { o0[t] = f2bf(oA[t]); o1[t] = f2bf(oB[t]); }
    size_t ob = (size_t)pidx * 2048;
    *(uint2*)&opP[ob + (size_t)lm * 64 + wv * 16 + quad * 4] = *(uint2*)o0;
    *(uint2*)&opP[ob + (size_t)(16 + lm) * 64 + wv * 16 + quad * 4] = *(uint2*)o1;
  }
}

// -------- combine <=SPLIT chunk partials -> normalized attn output --------
// 1D grid with h = bid & 7: partials are read on the XCD that wrote them.
__global__ __launch_bounds__(256) void k_attn_combine(const float* __restrict__ mlP,
                                                      const ushort_t* __restrict__ opP,
                                                      ushort_t* __restrict__ attnb) {
  const int bid = blockIdx.x;
  const int h = bid & 7, qt = bid >> 3;
  const int nc = (qt + 1 < SPLIT) ? qt + 1 : SPLIT;
  const int tid = threadIdx.x;
  const int i = tid >> 3, d8 = (tid & 7) * 8;
  const size_t base = (size_t)(qt * NH + h) * SPLIT;
  float m[SPLIT], l[SPLIT], wgt[SPLIT];
  float M = -INFINITY;
  for (int cc = 0; cc < nc; ++cc) {
    m[cc] = mlP[(base + cc) * 64 + i];
    l[cc] = mlP[(base + cc) * 64 + 32 + i];
    M = fmaxf(M, m[cc]);
  }
  float L = 0.f;
  for (int cc = 0; cc < nc; ++cc) { wgt[cc] = __expf(m[cc] - M); L += l[cc] * wgt[cc]; }
  float acc[8] = {0, 0, 0, 0, 0, 0, 0, 0};
  for (int cc = 0; cc < nc; ++cc) {
    uint4 v = *(const uint4*)&opP[(base + cc) * 2048 + (size_t)i * 64 + d8];
    float f[8]; unpack8(v, f);
#pragma unroll
    for (int k = 0; k < 8; ++k) acc[k] += wgt[cc] * f[k];
  }
  const float inv = 1.f / L;
  ushort_t o8[8];
#pragma unroll
  for (int k = 0; k < 8; ++k) o8[k] = f2bf(acc[k] * inv);
  *(uint4*)&attnb[(size_t)(qt * 32 + i) * DM + h * DH + d8] = *(uint4*)o8;
}

// -------- w' = LayerNorm(w + sum(delta parts)) * g + b ---------------------
__global__ __launch_bounds__(256) void k_addln(const float* __restrict__ w,
                                               float* __restrict__ wout,
                                               ushort_t* __restrict__ wbft,
                                               const float* __restrict__ delta,
                                               int nparts,
                                               const float* __restrict__ gamma,
                                               const float* __restrict__ beta) {
  const int row = blockIdx.x;
  const int tid = threadIdx.x;
  __shared__ float red[4], red2[4];
  __shared__ float sm[512];
  size_t base = (size_t)row * DM;
  float x0 = w[base + tid];
  float x1 = w[base + tid + 256];
  for (int p = 0; p < nparts; ++p) {
    x0 += delta[(size_t)p * TT * DM + base + tid];
    x1 += delta[(size_t)p * TT * DM + base + tid + 256];
  }
  float s = x0 + x1;
#pragma unroll
  for (int off = 1; off < 64; off <<= 1) s += __shfl_xor(s, off);
  if ((tid & 63) == 0) red[tid >> 6] = s;
  __syncthreads();
  float mu = (red[0] + red[1] + red[2] + red[3]) * (1.f / 512.f);
  float d0 = x0 - mu, d1 = x1 - mu;
  float v = d0 * d0 + d1 * d1;
#pragma unroll
  for (int off = 1; off < 64; off <<= 1) v += __shfl_xor(v, off);
  if ((tid & 63) == 0) red2[tid >> 6] = v;
  __syncthreads();
  float var = (red2[0] + red2[1] + red2[2] + red2[3]) * (1.f / 512.f);
  float rstd = rsqrtf(var + 1e-5f);
  float o0 = d0 * rstd * gamma[tid] + beta[tid];
  float o1 = d1 * rstd * gamma[tid + 256] + beta[tid + 256];
  wout[base + tid] = o0;
  wout[base + tid + 256] = o1;
  sm[tid] = o0; sm[tid + 256] = o1;
  __syncthreads();
  if (tid < 64) {
    const int d8 = tid << 3;
    ushort_t t8[8];
#pragma unroll
    for (int e = 0; e < 8; ++e) t8[e] = f2bf(sm[d8 + e]);
    *(uint4*)&wbft[ft512(row, d8)] = *(uint4*)t8;
  }
}

extern "C" void kernel_launch(void* const* d_in, const int* in_sizes, int n_in,
                              void* d_out, int out_size, void* d_ws, size_t ws_size,
                              hipStream_t stream) {
  const float* we   = (const float*)d_in[0];
  const float* mem  = (const float*)d_in[1];
  const float* Wqkv = (const float*)d_in[2];
  const float* Wr   = (const float*)d_in[3];
  const float* Wo   = (const float*)d_in[4];
  const float* ln1s = (const float*)d_in[5];
  const float* ln1b = (const float*)d_in[6];
  const float* W1   = (const float*)d_in[7];
  const float* b1   = (const float*)d_in[8];
  const float* W2   = (const float*)d_in[9];
  const float* b2   = (const float*)d_in[10];
  const float* ln2s = (const float*)d_in[11];
  const float* ln2b = (const float*)d_in[12];
  const float* rwb  = (const float*)d_in[13];
  const float* rrb  = (const float*)d_in[14];

  // ---- workspace layout ----
  float* w     = (float*)d_ws;                        // TT*DM fp32
  float* proj  = w + (size_t)TT * DM;                 // TT*DM fp32 (Wo out)
  ushort_t* wbft  = (ushort_t*)(proj + (size_t)TT * DM);  // TT*DM bf16 (FT)
  ushort_t* posft = wbft + (size_t)TT * DM;           // TT*DM bf16 (FT)
  ushort_t* attnb = posft + (size_t)TT * DM;          // TT*DM bf16 (rm)
  ushort_t* qkvB  = attnb + (size_t)TT * DM;          // q/k/v FT region
  ushort_t* qwft  = qkvB;                             // TT*DM (Q+rwb, FT)
  ushort_t* kft   = qkvB + (size_t)TT * DM;           // TT*DM (K, FT)
  ushort_t* vtft  = qkvB + (size_t)2 * TT * DM;       // DM*TT (V^T, FT)
  // + TT*DM reserved gap (ff1ft overlay tail)
  ushort_t* WtAll = qkvB + (size_t)TT * QKV_N + (size_t)TT * DM;
  ushort_t* opP   = WtAll + (size_t)NLAYER * WT_STRIDE;  // 65*8*SPLIT*2048
  float* mlP   = (float*)(opP + (size_t)65 * 8 * SPLIT * 2048);  // 65*8*SPLIT*64 f32
  ushort_t* qrft  = (ushort_t*)(mlP + (size_t)65 * 8 * SPLIT * 64);  // TT*DM (FT)
  ushort_t* rsft  = qrft + (size_t)TT * DM;           // RSFT_ROWS/16 * 16*512 shorts
  ushort_t* wrapv = rsft + (size_t)(RSFT_ROWS / 16) * 16 * 512;  // NH*TT*16
  ushort_t* r16   = wrapv + (size_t)NH * TT * 16;     // 16*512
  // overlays (time-shared, stream-ordered):
  ushort_t* ff1ft = qkvB;            // FT TT*DI bf16 spans qkv region + gap
  float* ff2p  = (float*)opP;        // 4 split-K partials, 4*TT*DM f32
  const size_t OFF_QKVT = 0, OFF_WRT = 786432, OFF_WOT = 1048576,
               OFF_W1T = 1310720, OFF_W2T = 2359296;

  // all-layer weight transpose(+FT pack) + build in one dispatch
  k_prep<<<13312 + 4160, 256, 0, stream>>>(Wqkv, Wr, Wo, W1, W2, WtAll,
                                           we, mem, w, wbft, posft);

  dim3 gQW(16, 33);          // merged QKV (12 n-tiles) + Wr (4 n-tiles), 64x128
  dim3 gW1(16, 33);          // FFN1 64x128
  dim3 gW2(4, 33, 4);        // FFN2 64x128, split-K=4
  dim3 gDM32(DM / 64, 65);   // Wo (old 32x64 kernel)

  for (int l = 0; l < NLAYER; ++l) {
    const ushort_t* Wt = WtAll + (size_t)l * WT_STRIDE;
    k_gemm_qkvwr_ft<<<gQW, 256, 0, stream>>>(wbft, posft, Wt + OFF_QKVT,
                                             Wt + OFF_WRT, qwft, kft, vtft,
                                             rsft, r16, qrft, rwb, rrb);
    k_wrap<<<65 * NH, 256, 0, stream>>>(qrft, r16, wrapv);
    k_attn<<<65 * NH * SPLIT, 256, 0, stream>>>(qwft, qrft, kft, vtft, rsft,
                                                wrapv, mlP, opP);
    k_attn_combine<<<65 * NH, 256, 0, stream>>>(mlP, opP, attnb);
    k_gemm_mfma<<<gDM32, 256, 0, stream>>>(attnb, Wt + OFF_WOT, nullptr, proj, nullptr,
                                           DM, DM, 0);
    k_addln<<<TT, 256, 0, stream>>>(w, w, wbft, proj, 1,
                                    ln1s + (size_t)l * DM, ln1b + (size_t)l * DM);
    k_ffn1_ft<<<gW1, 256, 0, stream>>>(wbft, Wt + OFF_W1T, b1 + (size_t)l * DI, ff1ft);
    k_ffn2_ft<<<gW2, 256, 0, stream>>>(ff1ft, Wt + OFF_W2T, b2 + (size_t)l * DM, ff2p);
    float* wout = (l == NLAYER - 1) ? (float*)d_out : w;
    k_addln<<<TT, 256, 0, stream>>>(w, wout, wbft, ff2p, 4,
                                    ln2s + (size_t)l * DM, ln2b + (size_t)l * DM);
  }
}

// Round 13
// 576.455 us; speedup vs baseline: 1.1730x; 1.0367x over previous
//
#include <hip/hip_runtime.h>
#include <hip/hip_bf16.h>
#include <math.h>
#include <stdint.h>

#define TT 2080
#define DM 512
#define DI 2048
#define NH 8
#define DH 64
#define NMTOK 16
#define NLAYER 4
#define QKV_N 1536
#define ATT_SCALE 0.125f
#define SPLIT 8
#define WT_STRIDE 3407872   // shorts per layer's transposed-weight block
#define RSFT_ROWS 2112      // shifted-r FT rows (132 blocks of 16)

typedef short bf16x8 __attribute__((ext_vector_type(8)));
typedef float f32x4 __attribute__((ext_vector_type(4)));
typedef unsigned short ushort_t;

__device__ __forceinline__ ushort_t f2bf(float f) {
  __hip_bfloat16 h = __float2bfloat16(f);
  return *reinterpret_cast<ushort_t*>(&h);
}
__device__ __forceinline__ float bfbits2f(unsigned int hi_bits) {
  return __uint_as_float(hi_bits);
}
__device__ __forceinline__ float bf2f(ushort_t u) {
  return bfbits2f(((unsigned int)u) << 16);
}
__device__ __forceinline__ void unpack8(uint4 v, float* f) {
  f[0] = bfbits2f(v.x << 16); f[1] = bfbits2f(v.x & 0xffff0000u);
  f[2] = bfbits2f(v.y << 16); f[3] = bfbits2f(v.y & 0xffff0000u);
  f[4] = bfbits2f(v.z << 16); f[5] = bfbits2f(v.z & 0xffff0000u);
  f[6] = bfbits2f(v.w << 16); f[7] = bfbits2f(v.w & 0xffff0000u);
}
__device__ __forceinline__ unsigned int pack2(ushort_t lo, ushort_t hi) {
  return (unsigned int)lo | ((unsigned int)hi << 16);
}
// Barrier draining LDS ops only — leaves global (vmcnt) loads in flight.
__device__ __forceinline__ void barrier_lds() {
  asm volatile("s_waitcnt lgkmcnt(0)" ::: "memory");
  __builtin_amdgcn_s_barrier();
}
// Barrier draining everything (used to retire global_load_lds prefetches).
__device__ __forceinline__ void barrier_all() {
  asm volatile("s_waitcnt vmcnt(0) lgkmcnt(0)" ::: "memory");
  __builtin_amdgcn_s_barrier();
}
// Counted drain: waits the OLDEST outstanding vmem ops down to 4 — retires
// the 2 stageKV gload_lds (issued first in the iteration) while leaving the
// 4 rs prefetch loads (issued after, needed only next iteration) in flight.
__device__ __forceinline__ void barrier_vm4() {
  asm volatile("s_waitcnt vmcnt(4) lgkmcnt(0)" ::: "memory");
  __builtin_amdgcn_s_barrier();
}
// global -> LDS direct copy, 16B per lane. LDS dest must be wave-uniform
// base + lane*16 (contract of global_load_lds).
__device__ __forceinline__ void gload16(const ushort_t* g, ushort_t* l) {
  __builtin_amdgcn_global_load_lds(
      (__attribute__((address_space(1))) void*)(uintptr_t)g,
      (__attribute__((address_space(3))) void*)(uintptr_t)l, 16, 0, 0);
}
// ---- fragment-tiled (FT) layout --------------------------------------------
// Matrix X[R][K] (bf16) stored as 1024B blocks of (16 r x 32 k); lane
// = ((k>>3)&3)*16 + (r&15) holds 8 consecutive k-elements = EXACTLY the
// mfma_f32_16x16x32_bf16 A/B fragment order.
__device__ __forceinline__ size_t ft512(int r, int c) {  // K = 512 (KT = 16)
  return (((size_t)(r >> 4) * 16 + (c >> 5)) << 9) + (((c >> 3) & 3) << 7) +
         ((r & 15) << 3) + (c & 7);
}

// ---- fused prep: all 4 layers' weight transposes + build w/pos ------------
__global__ __launch_bounds__(256) void k_prep(
    const float* __restrict__ Wqkv, const float* __restrict__ Wr,
    const float* __restrict__ Wo, const float* __restrict__ W1,
    const float* __restrict__ W2, ushort_t* __restrict__ dstAll,
    const float* __restrict__ we, const float* __restrict__ mem,
    float* __restrict__ w, ushort_t* __restrict__ wbft,
    ushort_t* __restrict__ posft) {
  const int tid = threadIdx.x;
  if (blockIdx.x >= 13312) {  // ---- build ----
    int idx = (blockIdx.x - 13312) * 256 + tid;
    if (idx >= TT * DM) return;
    int t = idx >> 9, d = idx & 511;
    float v;
    if (t < NMTOK) v = mem[t * DM + d];
    else if (t < NMTOK + 2048) v = we[(t - NMTOK) * DM + d];
    else v = mem[(t - (NMTOK + 2048)) * DM + d];
    w[idx] = v;
    wbft[ft512(t, d)] = f2bf(v);
    float p = (float)(TT - 1 - t);
    int i2 = d & 255;
    float freq = __expf(-0.035977892f * (float)i2);
    float ang = p * freq;
    posft[ft512(t, d)] = f2bf((d < 256) ? __sinf(ang) : __cosf(ang));
    return;
  }
  // ---- transpose+cast, layer l ----
  __shared__ float tl[32][33];
  const int l = blockIdx.x / 3328;
  int idx = blockIdx.x % 3328;
  const float* src;
  ushort_t* dst = dstAll + (size_t)l * WT_STRIDE;
  int K, N, local;
  bool isFT = true;
  if (idx < 768)       { src = Wqkv + (size_t)l * 512 * 1536; K = 512;  N = 1536; local = idx; }
  else if (idx < 1024) { src = Wr   + (size_t)l * 512 * 512;  dst += 786432;  K = 512;  N = 512;  local = idx - 768; }
  else if (idx < 1280) { src = Wo   + (size_t)l * 512 * 512;  dst += 1048576; K = 512;  N = 512;  local = idx - 1024; isFT = false; }
  else if (idx < 2304) { src = W1   + (size_t)l * 512 * 2048; dst += 1310720; K = 512;  N = 2048; local = idx - 1280; }
  else                 { src = W2   + (size_t)l * 2048 * 512; dst += 2359296; K = 2048; N = 512;  local = idx - 2304; }
  const int ntiles = N / 32;
  const int n0 = (local % ntiles) * 32, k0 = (local / ntiles) * 32;
#pragma unroll
  for (int p = 0; p < 4; ++p) {
    int row = (tid >> 5) + 8 * p, col = tid & 31;
    tl[row][col] = src[(size_t)(k0 + row) * N + n0 + col];  // tl[k][n]
  }
  __syncthreads();
  if (isFT) {
    if (tid < 128) {
      int b = tid >> 6, l2 = tid & 63;
      int nn = b * 16 + (l2 & 15);
      int kq = (l2 >> 4) * 8;
      ushort_t t8[8];
#pragma unroll
      for (int e = 0; e < 8; ++e) t8[e] = f2bf(tl[kq + e][nn]);
      size_t ad = (((size_t)((n0 >> 4) + b) * (K >> 5) + (k0 >> 5)) << 9) +
                  ((size_t)l2 << 3);
      *(uint4*)&dst[ad] = *(uint4*)t8;
    }
  } else {
#pragma unroll
    for (int p = 0; p < 4; ++p) {
      int n = (tid >> 5) + 8 * p, k = tid & 31;
      dst[(size_t)(n0 + n) * K + k0 + k] = f2bf(tl[k][n]);
    }
  }
}

// -------- bf16 MFMA GEMM body, 32x64 tile, register prefetch (Wo only) ----
__device__ __forceinline__ void gemm32x64_body(const ushort_t* __restrict__ A,
                                               const ushort_t* __restrict__ Bt,
                                               const float* __restrict__ bias,
                                               float* __restrict__ C,
                                               ushort_t* __restrict__ Cb,
                                               int N, int K, int flags,
                                               int m0, int n0) {
  __shared__ short As[32][72];
  __shared__ short Bs[64][72];
  const int tid = threadIdx.x;
  const int lane = tid & 63, wv = tid >> 6;
  const int wm = (wv >> 1) * 16, wn = (wv & 1) * 32;
  const int lm = lane & 15, quad = lane >> 4;
  const int sr = tid >> 3, sc8 = (tid & 7) * 8;

  f32x4 acc[2];
  acc[0] = (f32x4)(0.f); acc[1] = (f32x4)(0.f);

  auto loadA = [&](int k0) -> uint4 {
    return *(const uint4*)&A[(size_t)(m0 + sr) * K + k0 + sc8];
  };
  auto loadB = [&](int row, int k0) -> uint4 {
    return *(const uint4*)&Bt[(size_t)(n0 + row) * K + k0 + sc8];
  };

  uint4 aC = loadA(0), b0C = loadB(sr, 0), b1C = loadB(sr + 32, 0);

  for (int k0 = 0; k0 < K; k0 += 64) {
    const int kn = (k0 + 64 < K) ? k0 + 64 : k0;  // clamped tail reload
    uint4 aN = loadA(kn), b0N = loadB(sr, kn), b1N = loadB(sr + 32, kn);
    barrier_lds();  // prev ds_reads done; vm prefetches stay in flight
    *(uint4*)&As[sr][sc8] = aC;
    *(uint4*)&Bs[sr][sc8] = b0C;
    *(uint4*)&Bs[sr + 32][sc8] = b1C;
    barrier_lds();
#pragma unroll
    for (int kk = 0; kk < 64; kk += 32) {
      bf16x8 a = *(const bf16x8*)&As[wm + lm][kk + quad * 8];
      bf16x8 b0 = *(const bf16x8*)&Bs[wn + lm][kk + quad * 8];
      bf16x8 b1 = *(const bf16x8*)&Bs[wn + 16 + lm][kk + quad * 8];
      acc[0] = __builtin_amdgcn_mfma_f32_16x16x32_bf16(a, b0, acc[0], 0, 0, 0);
      acc[1] = __builtin_amdgcn_mfma_f32_16x16x32_bf16(a, b1, acc[1], 0, 0, 0);
    }
    aC = aN; b0C = b0N; b1C = b1N;
  }
#pragma unroll
  for (int nt = 0; nt < 2; ++nt) {
    int col = n0 + wn + nt * 16 + lm;
    float bv = (flags & 1) ? bias[col] : 0.f;
#pragma unroll
    for (int t = 0; t < 4; ++t) {
      int row = m0 + wm + quad * 4 + t;
      float v = acc[nt][t] + bv;
      if (flags & 2) v = fmaxf(v, 0.f);
      if (flags & 4) Cb[(size_t)row * N + col] = f2bf(v);
      else C[(size_t)row * N + col] = v;
    }
  }
}

__global__ __launch_bounds__(256) void k_gemm_mfma(const ushort_t* __restrict__ A,
                                                   const ushort_t* __restrict__ Bt,
                                                   const float* __restrict__ bias,
                                                   float* __restrict__ C,
                                                   ushort_t* __restrict__ Cb,
                                                   int N, int K, int flags) {
  gemm32x64_body(A, Bt, bias, C, Cb, N, K, flags, blockIdx.y * 32, blockIdx.x * 64);
}

// -------- FT GEMM: 64x128 tile, 4 waves x (32x64), global_load_lds staging,
// conflict-free fragment ds_reads, double-buffered (2 x 24KB LDS).
// flags: 1=+bias, 2=relu. omode: 0=fp32 rm, 1=bf16 rm, 2=FT(cftKT),
// 3=q(qwft=v+rwb FT; aux=qrft=v+rrb FT), 4=k(kft FT, col-512),
// 5=v(vtft V^T FT), 6=r(rsft FT shifted +1 row; aux=r16 rm for row<16).
__device__ __forceinline__ void gemm_ft_body(
    ushort_t* smem, const ushort_t* __restrict__ A, const ushort_t* __restrict__ Bt,
    const float* __restrict__ bias, int N, int K, int kBeg, int kEnd,
    int m0, int n0, int flags, int omode,
    float* __restrict__ Cf, ushort_t* __restrict__ Cb, int cftKT,
    ushort_t* __restrict__ aux, const float* __restrict__ rwb,
    const float* __restrict__ rrb) {
  const int tid = threadIdx.x;
  const int lane = tid & 63, wv = tid >> 6;
  const int wm = (wv >> 1) * 32, wn = (wv & 1) * 64;
  const int lm = lane & 15, quad = lane >> 4;
  const int AKT = K >> 5;                 // global k-tiles per 16-row block
  const int mt0 = m0 >> 4, nt0 = n0 >> 4;
  const int kt0 = kBeg >> 5;

  f32x4 acc[2][4];
#pragma unroll
  for (int i = 0; i < 2; ++i)
#pragma unroll
    for (int j = 0; j < 4; ++j) acc[i][j] = (f32x4)(0.f);

  auto stage = [&](ushort_t* dA, int ktg) {
    ushort_t* dB = dA + 4096;
#pragma unroll
    for (int it = 0; it < 6; ++it) {
      const int c = (it << 8) + tid;
      if (it < 2) {  // A chunks: c in [0,512)
        const int blk = c >> 6, ln = c & 63;
        gload16(A + (((size_t)(mt0 + (blk >> 1)) * AKT + ktg + (blk & 1)) << 9) + (ln << 3),
                dA + (c << 3));
      } else {       // B chunks: cB in [0,1024)
        const int cB = c - 512;
        const int blk = cB >> 6, ln = cB & 63;
        gload16(Bt + (((size_t)(nt0 + (blk >> 1)) * AKT + ktg + (blk & 1)) << 9) + (ln << 3),
                dB + (cB << 3));
      }
    }
  };
  auto compute = [&](const ushort_t* dA) {
    const ushort_t* dB = dA + 4096;
#pragma unroll
    for (int kk = 0; kk < 2; ++kk) {
      bf16x8 a[2], b[4];
#pragma unroll
      for (int i = 0; i < 2; ++i)
        a[i] = *(const bf16x8*)&dA[((((wm >> 4) + i) << 1) + kk) * 512 + (lane << 3)];
#pragma unroll
      for (int j = 0; j < 4; ++j)
        b[j] = *(const bf16x8*)&dB[((((wn >> 4) + j) << 1) + kk) * 512 + (lane << 3)];
#pragma unroll
      for (int i = 0; i < 2; ++i)
#pragma unroll
        for (int j = 0; j < 4; ++j)
          acc[i][j] = __builtin_amdgcn_mfma_f32_16x16x32_bf16(a[i], b[j], acc[i][j], 0, 0, 0);
    }
  };

  const int nIter = (kEnd - kBeg) >> 6;  // always even (8) here
  stage(smem, kt0);
  __syncthreads();
  for (int t = 0; t < nIter; t += 2) {
    if (t + 1 < nIter) stage(smem + 12288, kt0 + (t + 1) * 2);
    compute(smem);
    __syncthreads();
    if (t + 2 < nIter) stage(smem, kt0 + (t + 2) * 2);
    compute(smem + 12288);
    __syncthreads();
  }

#pragma unroll
  for (int i = 0; i < 2; ++i) {
    const int rowb = m0 + wm + i * 16 + quad * 4;
#pragma unroll
    for (int j = 0; j < 4; ++j) {
      const int col = n0 + wn + j * 16 + lm;
      const float bv = (flags & 1) ? bias[col] : 0.f;
#pragma unroll
      for (int t2 = 0; t2 < 4; ++t2) {
        const int row = rowb + t2;
        float v = acc[i][j][t2] + bv;
        if (flags & 2) v = fmaxf(v, 0.f);
        if (omode == 0) {
          Cf[(size_t)row * N + col] = v;
        } else if (omode == 1) {
          Cb[(size_t)row * N + col] = f2bf(v);
        } else if (omode == 2) {
          Cb[(((size_t)(row >> 4) * cftKT + (col >> 5)) << 9) +
             (((col >> 3) & 3) << 7) + ((row & 15) << 3) + (col & 7)] = f2bf(v);
        } else if (omode == 3) {
          Cb[ft512(row, col)] = f2bf(v + rwb[col]);
          aux[ft512(row, col)] = f2bf(v + rrb[col]);
        } else if (omode == 4) {
          Cb[ft512(row, col - 512)] = f2bf(v);
        } else if (omode == 5) {  // V^T FT, r = v-dim, c = token
          const int dv = col - 1024;
          Cb[((size_t)(dv >> 4) * 65 + (row >> 5)) * 512 +
             (((row >> 3) & 3) << 7) + ((dv & 15) << 3) + (row & 7)] = f2bf(v);
        } else {  // omode 6: shifted r (rsft[k] = r[k-1]) + r16 head rows
          Cb[ft512(row + 1, col)] = f2bf(v);
          if (row < 16) aux[(size_t)row * 512 + col] = f2bf(v);
        }
      }
    }
  }
}

// merged QKV + Wr GEMMs (FT); q -> qwft(+rwb) & qrft(+rrb); k -> kft;
// v -> vtft (V^T FT); Wr -> rsft (shifted FT) + r16
__global__ __launch_bounds__(256) void k_gemm_qkvwr_ft(
    const ushort_t* __restrict__ wbft, const ushort_t* __restrict__ posft,
    const ushort_t* __restrict__ qkvT, const ushort_t* __restrict__ wrT,
    ushort_t* __restrict__ qwft, ushort_t* __restrict__ kft,
    ushort_t* __restrict__ vtft, ushort_t* __restrict__ rsft,
    ushort_t* __restrict__ r16, ushort_t* __restrict__ qrft,
    const float* __restrict__ rwb, const float* __restrict__ rrb) {
  __shared__ ushort_t smem[24576];
  int m0 = blockIdx.y * 64;
  if (m0 + 64 > TT) m0 = TT - 64;  // overlapped last tile (dup writes benign)
  const int bx = blockIdx.x;
  if (bx < 12) {
    const int om = (bx < 4) ? 3 : (bx < 8 ? 4 : 5);
    ushort_t* dst = (om == 3) ? qwft : (om == 4) ? kft : vtft;
    gemm_ft_body(smem, wbft, qkvT, nullptr, QKV_N, DM, 0, DM, m0, bx * 128,
                 0, om, nullptr, dst, 0, (om == 3) ? qrft : nullptr, rwb, rrb);
  } else {
    gemm_ft_body(smem, posft, wrT, nullptr, DM, DM, 0, DM, m0, (bx - 12) * 128,
                 0, 6, nullptr, rsft, 0, r16, nullptr, nullptr);
  }
}

// FFN1: wbft x w1T -> ff1ft (FT, K_out = DI), bias+relu
__global__ __launch_bounds__(256) void k_ffn1_ft(const ushort_t* __restrict__ wbft,
                                                 const ushort_t* __restrict__ w1T,
                                                 const float* __restrict__ b1l,
                                                 ushort_t* __restrict__ ff1ft) {
  __shared__ ushort_t smem[24576];
  int m0 = blockIdx.y * 64;
  if (m0 + 64 > TT) m0 = TT - 64;
  gemm_ft_body(smem, wbft, w1T, b1l, DI, DM, 0, DM, m0, blockIdx.x * 128,
               1 | 2, 2, nullptr, ff1ft, DI >> 5, nullptr, nullptr, nullptr);
}

// FFN2: ff1ft x w2T -> fp32 partials (split-K=4); bias folded into split 0
__global__ __launch_bounds__(256) void k_ffn2_ft(const ushort_t* __restrict__ ff1ft,
                                                 const ushort_t* __restrict__ w2T,
                                                 const float* __restrict__ b2l,
                                                 float* __restrict__ ff2p) {
  __shared__ ushort_t smem[24576];
  int m0 = blockIdx.y * 64;
  if (m0 + 64 > TT) m0 = TT - 64;
  const int s = blockIdx.z;
  gemm_ft_body(smem, ff1ft, w2T, b2l, DM, DI, s * 512, s * 512 + 512, m0,
               blockIdx.x * 128, (s == 0) ? 1 : 0, 0,
               ff2p + (size_t)s * TT * DM, nullptr, 0, nullptr, nullptr, nullptr);
}

// ---- wrap values: wrapv[h][row][w<16] = qr_row(h) . r_w(h) ---------------
// Read ONLY on diagonal-tile mem corners => rows 1..16 and 2064..2079.
// Grid = 16 blocks (8 heads x 2 corners); h = bid & 7 keeps XCD affinity.
__global__ __launch_bounds__(256) void k_wrap(const ushort_t* __restrict__ qrft,
                                              const ushort_t* __restrict__ r16,
                                              ushort_t* __restrict__ wrapv) {
  const int h = blockIdx.x & 7;
  const int base = (blockIdx.x >> 3) ? 2064 : 1;
  const int row = base + (threadIdx.x >> 4);
  const int w = threadIdx.x & 15;
  float a = 0.f;
#pragma unroll
  for (int d8 = 0; d8 < 64; d8 += 8) {
    bf16x8 qv = *(const bf16x8*)&qrft[ft512(row, h * DH + d8)];
    bf16x8 rv = *(const bf16x8*)&r16[(size_t)w * 512 + h * DH + d8];
#pragma unroll
    for (int e = 0; e < 8; ++e)
      a += bf2f((ushort_t)qv[e]) * bf2f((ushort_t)rv[e]);
  }
  wrapv[(size_t)h * TT * 16 + (size_t)row * 16 + w] = f2bf(a);
}

// ------- MFMA flash attention, KVBLK=32, split-j, FT-staged Q/K/V^T -------
// Round-12 structure + (a) T5 setprio around MFMA clusters (independent
// blocks at different phases per CU -> scheduler favors MFMA waves),
// (b) corner-aware diagonal path (inmem only possible at qt==0 or qt==64;
// the other 63 diagonal tiles reduce to a branch-free mask).
__global__ __launch_bounds__(256) void k_attn(const ushort_t* __restrict__ qwft,
                                              const ushort_t* __restrict__ qrft,
                                              const ushort_t* __restrict__ kft,
                                              const ushort_t* __restrict__ vtft,
                                              const ushort_t* __restrict__ rsft,
                                              const ushort_t* __restrict__ wrapv,
                                              float* __restrict__ mlP,
                                              ushort_t* __restrict__ opP) {
  const int bid = blockIdx.x;
  const int h = bid & 7;            // head == XCD (bid % 8 round-robin)
  const int rest = bid >> 3;
  const int qt = 64 - rest % 65;    // heavy q-tiles dispatch first
  const int c = rest / 65;
  if (c > qt) return;  // empty chunk
  const int i0 = qt * 32;
  const int tid = threadIdx.x;
  const int lane = tid & 63, wv = tid >> 6;
  const int lm = lane & 15, quad = lane >> 4;
  const bool corner = (qt == 0) || (qt == 64);  // only qt where inmem possible

  __shared__ ushort_t kl[2][2048];   // K dbuf, 4 FT blocks [jt][kt]
  __shared__ ushort_t vtl[2][2048];  // V^T dbuf, 4 FT blocks [dt]
  __shared__ ushort_t pbl[1024];     // P bf16, 2 FT blocks [it]
  __shared__ float st[32][34];       // AC+BD fp32 [i][j] (+2 pad)
  __shared__ float m_s[32], l_s[32], alpha_s[32];
  ushort_t* qwl = vtl[1];  // alias: read only in prologue, before first write

  const int ii = tid >> 3, g = tid & 7, jjb = g * 4;
  const int i = i0 + ii;
  const size_t hwr = (size_t)h * TT * 16;

  const int sblk = tid >> 6, sln = tid & 63;
  auto stageKV = [&](int j0, int buf) {
    gload16(kft + (((size_t)((j0 >> 4) + (sblk >> 1)) * 16) + h * 2 + (sblk & 1)) * 512 +
                (sln << 3),
            kl[buf] + (tid << 3));
    gload16(vtft + (((size_t)(h * 4 + sblk)) * 65 + (j0 >> 5)) * 512 + (sln << 3),
            vtl[buf] + (tid << 3));
  };

  // per-wave quadrant + its banded-QR column pair
  const int acit = wv >> 1, acjt = wv & 1;
  const int cqlo = 1 + acjt - acit;  // needed QRb col-blocks {cqlo, cqlo+1}
  auto loadRS = [&](int jt2, bf16x8 (&rs)[2][2]) {
    const int wbp4 = 128 - 2 * (qt - jt2);  // rS window base block
#pragma unroll
    for (int f = 0; f < 2; ++f)
#pragma unroll
      for (int kt = 0; kt < 2; ++kt)
        rs[f][kt] = *(const bf16x8*)&rsft[(((size_t)(wbp4 + cqlo + f) * 16) +
                                          h * 2 + kt) * 512 + (lane << 3)];
  };

  // prologue: Q tile (into aliased qwl) + first K/V tile; first rS to VGPR
  gload16(qwft + (((size_t)((i0 >> 4) + (sblk >> 1)) * 16) + h * 2 + (sblk & 1)) * 512 +
              (sln << 3),
          qwl + (tid << 3));
  stageKV(c * 32, 0);
  bf16x8 rsc[2][2];
  loadRS(c, rsc);
  if (tid < 32) { m_s[tid] = -INFINITY; l_s[tid] = 0.f; }
  barrier_all();

  // loop-invariant A fragments: q+rwb (from aliased LDS) and q+rrb (global)
  bf16x8 aQ[2], aQR[2];
#pragma unroll
  for (int kt = 0; kt < 2; ++kt) {
    aQ[kt] = *(const bf16x8*)&qwl[(acit * 2 + kt) * 512 + (lane << 3)];
    aQR[kt] = *(const bf16x8*)&qrft[(((size_t)((i0 >> 4) + acit) * 16) +
                                    h * 2 + kt) * 512 + (lane << 3)];
  }
  barrier_lds();  // all waves' qwl reads retired before vtl[1] is overwritten

  f32x4 oA = (f32x4)(0.f);  // O^T accum, d-tile=wv, i = i0+lm
  f32x4 oB = (f32x4)(0.f);  // i = i0+16+lm

  int cur = 0;
  for (int jt = c; jt <= qt; jt += SPLIT) {
    const int j0 = jt * 32;
    const bool hasNext = (jt + SPLIT <= qt);
    if (hasNext) stageKV((jt + SPLIT) * 32, cur ^ 1);
    __builtin_amdgcn_sched_barrier(0);  // pin: stage gloads precede rs loads
    const int jn = hasNext ? jt + SPLIT : jt;
    bf16x8 rsn[2][2];
    loadRS(jn, rsn);

    {  // ---- phase B: AC + banded-QR MFMAs -> st = AC + BD ----
      f32x4 ac = (f32x4)(0.f), qa = (f32x4)(0.f), qb = (f32x4)(0.f);
      __builtin_amdgcn_s_setprio(1);
#pragma unroll
      for (int kt = 0; kt < 2; ++kt) {
        bf16x8 b = *(const bf16x8*)&kl[cur][(acjt * 2 + kt) * 512 + (lane << 3)];
        ac = __builtin_amdgcn_mfma_f32_16x16x32_bf16(aQ[kt], b, ac, 0, 0, 0);
        qa = __builtin_amdgcn_mfma_f32_16x16x32_bf16(aQR[kt], rsc[0][kt], qa, 0, 0, 0);
        qb = __builtin_amdgcn_mfma_f32_16x16x32_bf16(aQR[kt], rsc[1][kt], qb, 0, 0, 0);
      }
      __builtin_amdgcn_s_setprio(0);
      const bool diag = (jt == qt);
      const int thr = 16 * (1 + acit - acjt);
#pragma unroll
      for (int t = 0; t < 4; ++t) {
        // element (row quad*4+t, col lm) needs band index cw = col-row+32;
        // within this wave's pair: idx = cw - cqlo*16 = lm - (quad*4+t) + 16
        const int idx = lm - (quad * 4 + t) + 16;
        const int src = quad * 16 + (idx & 15);
        const float av = __shfl(qa[t], src);
        const float bv2 = __shfl(qb[t], src);
        float bd = (idx < 16) ? av : bv2;
        if (diag && idx > thr) bd = 0.f;  // j > i: BD replaced by mask/wrap
        st[acit * 16 + quad * 4 + t][acjt * 16 + lm] = ac[t] + bd;
      }
    }
    barrier_lds();

    {  // ---- phase C: score masking + online softmax ----
      float sreg[4];
      if (jt < qt) {  // fast path: all-causal tile, BD already in st
#pragma unroll
        for (int u = 0; u < 4; ++u) sreg[u] = st[ii][jjb + u] * ATT_SCALE;
      } else if (!corner) {  // diagonal, no mem corner: pure causal mask
#pragma unroll
        for (int u = 0; u < 4; ++u) {
          int j = j0 + jjb + u;
          sreg[u] = (j <= i) ? st[ii][jjb + u] * ATT_SCALE : -1e30f;
        }
      } else {  // corner diagonal tile: mask + mem-corner + wrap handling
#pragma unroll
        for (int u = 0; u < 4; ++u) {
          int j = j0 + jjb + u;
          float stv = st[ii][jjb + u];
          float s;
          if (j <= i) {
            s = stv * ATT_SCALE;
          } else {
            bool inmem = (i < NMTOK && j < NMTOK) ||
                         (i >= TT - NMTOK && j >= TT - NMTOK);
            if (!inmem) s = -1e30f;
            else if (j == i + 1) s = stv * ATT_SCALE;  // rel_shift zero-pad
            else s = (stv + bf2f(wrapv[hwr + (size_t)(i + 1) * 16 + (j - i - 2)])) *
                     ATT_SCALE;
          }
          sreg[u] = s;
        }
      }
      float tmax = fmaxf(fmaxf(sreg[0], sreg[1]), fmaxf(sreg[2], sreg[3]));
#pragma unroll
      for (int off = 1; off < 8; off <<= 1) tmax = fmaxf(tmax, __shfl_xor(tmax, off));
      const float mold = m_s[ii];
      const float mnew = fmaxf(mold, tmax);
      const float alpha = __expf(mold - mnew);
      float p[4], psum = 0.f;
#pragma unroll
      for (int u = 0; u < 4; ++u) { p[u] = __expf(sreg[u] - mnew); psum += p[u]; }
#pragma unroll
      for (int off = 1; off < 8; off <<= 1) psum += __shfl_xor(psum, off);
      uint2 pk;
      pk.x = pack2(f2bf(p[0]), f2bf(p[1]));
      pk.y = pack2(f2bf(p[2]), f2bf(p[3]));
      *(uint2*)&pbl[(size_t)(ii >> 4) * 512 + (g >> 1) * 128 + (ii & 15) * 8 +
                    (g & 1) * 4] = pk;
      if (g == 0) {
        m_s[ii] = mnew;
        l_s[ii] = l_s[ii] * alpha + psum;
        alpha_s[ii] = alpha;
      }
    }
    barrier_lds();

    {  // ---- phase D: O^T = O^T*alpha + V^T P^T ----
      float a0 = alpha_s[lm], a1 = alpha_s[16 + lm];
      bf16x8 av = *(const bf16x8*)&vtl[cur][wv * 512 + (lane << 3)];
      bf16x8 p0 = *(const bf16x8*)&pbl[(lane << 3)];
      bf16x8 p1 = *(const bf16x8*)&pbl[512 + (lane << 3)];
#pragma unroll
      for (int t = 0; t < 4; ++t) { oA[t] *= a0; oB[t] *= a1; }
      __builtin_amdgcn_s_setprio(1);
      oA = __builtin_amdgcn_mfma_f32_16x16x32_bf16(av, p0, oA, 0, 0, 0);
      oB = __builtin_amdgcn_mfma_f32_16x16x32_bf16(av, p1, oB, 0, 0, 0);
      __builtin_amdgcn_s_setprio(0);
    }
    barrier_vm4();  // retire stage gloads (oldest 2); rs loads stay in flight
    cur ^= 1;
#pragma unroll
    for (int f = 0; f < 2; ++f)
#pragma unroll
      for (int kt = 0; kt < 2; ++kt) rsc[f][kt] = rsn[f][kt];
  }

  {  // write partials: m, l (fp32) and un-normalized O (bf16, [i][d] layout)
    const int pidx = (qt * NH + h) * SPLIT + c;
    if (tid < 32) {
      mlP[(size_t)pidx * 64 + tid] = m_s[tid];
      mlP[(size_t)pidx * 64 + 32 + tid] = l_s[tid];
    }
    ushort_t o0[4], o1[4];
#pragma unroll
    for (int t = 0; t < 4; ++t) { o0[t] = f2bf(oA[t]); o1[t] = f2bf(oB[t]); }
    size_t ob = (size_t)pidx * 2048;
    *(uint2*)&opP[ob + (size_t)lm * 64 + wv * 16 + quad * 4] = *(uint2*)o0;
    *(uint2*)&opP[ob + (size_t)(16 + lm) * 64 + wv * 16 + quad * 4] = *(uint2*)o1;
  }
}

// -------- combine <=SPLIT chunk partials -> normalized attn output --------
// 1D grid with h = bid & 7: partials are read on the XCD that wrote them.
__global__ __launch_bounds__(256) void k_attn_combine(const float* __restrict__ mlP,
                                                      const ushort_t* __restrict__ opP,
                                                      ushort_t* __restrict__ attnb) {
  const int bid = blockIdx.x;
  const int h = bid & 7, qt = bid >> 3;
  const int nc = (qt + 1 < SPLIT) ? qt + 1 : SPLIT;
  const int tid = threadIdx.x;
  const int i = tid >> 3, d8 = (tid & 7) * 8;
  const size_t base = (size_t)(qt * NH + h) * SPLIT;
  float m[SPLIT], l[SPLIT], wgt[SPLIT];
  float M = -INFINITY;
  for (int cc = 0; cc < nc; ++cc) {
    m[cc] = mlP[(base + cc) * 64 + i];
    l[cc] = mlP[(base + cc) * 64 + 32 + i];
    M = fmaxf(M, m[cc]);
  }
  float L = 0.f;
  for (int cc = 0; cc < nc; ++cc) { wgt[cc] = __expf(m[cc] - M); L += l[cc] * wgt[cc]; }
  float acc[8] = {0, 0, 0, 0, 0, 0, 0, 0};
  for (int cc = 0; cc < nc; ++cc) {
    uint4 v = *(const uint4*)&opP[(base + cc) * 2048 + (size_t)i * 64 + d8];
    float f[8]; unpack8(v, f);
#pragma unroll
    for (int k = 0; k < 8; ++k) acc[k] += wgt[cc] * f[k];
  }
  const float inv = 1.f / L;
  ushort_t o8[8];
#pragma unroll
  for (int k = 0; k < 8; ++k) o8[k] = f2bf(acc[k] * inv);
  *(uint4*)&attnb[(size_t)(qt * 32 + i) * DM + h * DH + d8] = *(uint4*)o8;
}

// -------- w' = LayerNorm(w + sum(delta parts)) * g + b ---------------------
__global__ __launch_bounds__(256) void k_addln(const float* __restrict__ w,
                                               float* __restrict__ wout,
                                               ushort_t* __restrict__ wbft,
                                               const float* __restrict__ delta,
                                               int nparts,
                                               const float* __restrict__ gamma,
                                               const float* __restrict__ beta) {
  const int row = blockIdx.x;
  const int tid = threadIdx.x;
  __shared__ float red[4], red2[4];
  __shared__ float sm[512];
  size_t base = (size_t)row * DM;
  float x0 = w[base + tid];
  float x1 = w[base + tid + 256];
  for (int p = 0; p < nparts; ++p) {
    x0 += delta[(size_t)p * TT * DM + base + tid];
    x1 += delta[(size_t)p * TT * DM + base + tid + 256];
  }
  float s = x0 + x1;
#pragma unroll
  for (int off = 1; off < 64; off <<= 1) s += __shfl_xor(s, off);
  if ((tid & 63) == 0) red[tid >> 6] = s;
  __syncthreads();
  float mu = (red[0] + red[1] + red[2] + red[3]) * (1.f / 512.f);
  float d0 = x0 - mu, d1 = x1 - mu;
  float v = d0 * d0 + d1 * d1;
#pragma unroll
  for (int off = 1; off < 64; off <<= 1) v += __shfl_xor(v, off);
  if ((tid & 63) == 0) red2[tid >> 6] = v;
  __syncthreads();
  float var = (red2[0] + red2[1] + red2[2] + red2[3]) * (1.f / 512.f);
  float rstd = rsqrtf(var + 1e-5f);
  float o0 = d0 * rstd * gamma[tid] + beta[tid];
  float o1 = d1 * rstd * gamma[tid + 256] + beta[tid + 256];
  wout[base + tid] = o0;
  wout[base + tid + 256] = o1;
  sm[tid] = o0; sm[tid + 256] = o1;
  __syncthreads();
  if (tid < 64) {
    const int d8 = tid << 3;
    ushort_t t8[8];
#pragma unroll
    for (int e = 0; e < 8; ++e) t8[e] = f2bf(sm[d8 + e]);
    *(uint4*)&wbft[ft512(row, d8)] = *(uint4*)t8;
  }
}

extern "C" void kernel_launch(void* const* d_in, const int* in_sizes, int n_in,
                              void* d_out, int out_size, void* d_ws, size_t ws_size,
                              hipStream_t stream) {
  const float* we   = (const float*)d_in[0];
  const float* mem  = (const float*)d_in[1];
  const float* Wqkv = (const float*)d_in[2];
  const float* Wr   = (const float*)d_in[3];
  const float* Wo   = (const float*)d_in[4];
  const float* ln1s = (const float*)d_in[5];
  const float* ln1b = (const float*)d_in[6];
  const float* W1   = (const float*)d_in[7];
  const float* b1   = (const float*)d_in[8];
  const float* W2   = (const float*)d_in[9];
  const float* b2   = (const float*)d_in[10];
  const float* ln2s = (const float*)d_in[11];
  const float* ln2b = (const float*)d_in[12];
  const float* rwb  = (const float*)d_in[13];
  const float* rrb  = (const float*)d_in[14];

  // ---- workspace layout ----
  float* w     = (float*)d_ws;                        // TT*DM fp32
  float* proj  = w + (size_t)TT * DM;                 // TT*DM fp32 (Wo out)
  ushort_t* wbft  = (ushort_t*)(proj + (size_t)TT * DM);  // TT*DM bf16 (FT)
  ushort_t* posft = wbft + (size_t)TT * DM;           // TT*DM bf16 (FT)
  ushort_t* attnb = posft + (size_t)TT * DM;          // TT*DM bf16 (rm)
  ushort_t* qkvB  = attnb + (size_t)TT * DM;          // q/k/v FT region
  ushort_t* qwft  = qkvB;                             // TT*DM (Q+rwb, FT)
  ushort_t* kft   = qkvB + (size_t)TT * DM;           // TT*DM (K, FT)
  ushort_t* vtft  = qkvB + (size_t)2 * TT * DM;       // DM*TT (V^T, FT)
  // + TT*DM reserved gap (ff1ft overlay tail)
  ushort_t* WtAll = qkvB + (size_t)TT * QKV_N + (size_t)TT * DM;
  ushort_t* opP   = WtAll + (size_t)NLAYER * WT_STRIDE;  // 65*8*SPLIT*2048
  float* mlP   = (float*)(opP + (size_t)65 * 8 * SPLIT * 2048);  // 65*8*SPLIT*64 f32
  ushort_t* qrft  = (ushort_t*)(mlP + (size_t)65 * 8 * SPLIT * 64);  // TT*DM (FT)
  ushort_t* rsft  = qrft + (size_t)TT * DM;           // RSFT_ROWS/16 * 16*512 shorts
  ushort_t* wrapv = rsft + (size_t)(RSFT_ROWS / 16) * 16 * 512;  // NH*TT*16
  ushort_t* r16   = wrapv + (size_t)NH * TT * 16;     // 16*512
  // overlays (time-shared, stream-ordered):
  ushort_t* ff1ft = qkvB;            // FT TT*DI bf16 spans qkv region + gap
  float* ff2p  = (float*)opP;        // 4 split-K partials, 4*TT*DM f32
  const size_t OFF_QKVT = 0, OFF_WRT = 786432, OFF_WOT = 1048576,
               OFF_W1T = 1310720, OFF_W2T = 2359296;

  // all-layer weight transpose(+FT pack) + build in one dispatch
  k_prep<<<13312 + 4160, 256, 0, stream>>>(Wqkv, Wr, Wo, W1, W2, WtAll,
                                           we, mem, w, wbft, posft);

  dim3 gQW(16, 33);          // merged QKV (12 n-tiles) + Wr (4 n-tiles), 64x128
  dim3 gW1(16, 33);          // FFN1 64x128
  dim3 gW2(4, 33, 4);        // FFN2 64x128, split-K=4
  dim3 gDM32(DM / 64, 65);   // Wo (old 32x64 kernel)

  for (int l = 0; l < NLAYER; ++l) {
    const ushort_t* Wt = WtAll + (size_t)l * WT_STRIDE;
    k_gemm_qkvwr_ft<<<gQW, 256, 0, stream>>>(wbft, posft, Wt + OFF_QKVT,
                                             Wt + OFF_WRT, qwft, kft, vtft,
                                             rsft, r16, qrft, rwb, rrb);
    k_wrap<<<16, 256, 0, stream>>>(qrft, r16, wrapv);
    k_attn<<<65 * NH * SPLIT, 256, 0, stream>>>(qwft, qrft, kft, vtft, rsft,
                                                wrapv, mlP, opP);
    k_attn_combine<<<65 * NH, 256, 0, stream>>>(mlP, opP, attnb);
    k_gemm_mfma<<<gDM32, 256, 0, stream>>>(attnb, Wt + OFF_WOT, nullptr, proj, nullptr,
                                           DM, DM, 0);
    k_addln<<<TT, 256, 0, stream>>>(w, w, wbft, proj, 1,
                                    ln1s + (size_t)l * DM, ln1b + (size_t)l * DM);
    k_ffn1_ft<<<gW1, 256, 0, stream>>>(wbft, Wt + OFF_W1T, b1 + (size_t)l * DI, ff1ft);
    k_ffn2_ft<<<gW2, 256, 0, stream>>>(ff1ft, Wt + OFF_W2T, b2 + (size_t)l * DM, ff2p);
    float* wout = (l == NLAYER - 1) ? (float*)d_out : w;
    k_addln<<<TT, 256, 0, stream>>>(w, wout, wbft, ff2p, 4,
                                    ln2s + (size_t)l * DM, ln2b + (size_t)l * DM);
  }
}